// Round 3
// baseline (968.746 us; speedup 1.0000x reference)
//
#include <hip/hip_runtime.h>

// ---------------------------------------------------------------------------
// CrossDecoderLayer on MI355X (gfx950). External I/O fp32; internal bf16
// MFMA, fp32 accumulate. B=8, W=1024, V=512, D=1024, H=8, DK=128.
// R7: XOR-swizzle on attn_self Ks/Vs/Ps and gate2 Ks/Pt (conflicts 15.2M->4.2M).
// R9: attn_self T14 async-STAGE split (prefetch tile t+1 K/V into regs during
//     compute of tile t; double-buffered named reg sets, static indexing) +
//     T5 s_setprio(1) around both MFMA clusters. LDS caps occupancy at
//     2 blocks/CU so the +64 transient VGPRs are free.
// ---------------------------------------------------------------------------

typedef __bf16 bf16;
typedef bf16  bf16x4 __attribute__((ext_vector_type(4)));
typedef bf16  bf16x8 __attribute__((ext_vector_type(8)));
typedef float f32x4  __attribute__((ext_vector_type(4)));

#define SCALE 0.08838834764831845f  // 1/sqrt(128)

__device__ __forceinline__ f32x4 mfma16(bf16x8 a, bf16x8 b, f32x4 c) {
  return __builtin_amdgcn_mfma_f32_16x16x32_bf16(a, b, c, 0, 0, 0);
}

__device__ __forceinline__ void gll16(const bf16* g, bf16* l) {
  __builtin_amdgcn_global_load_lds(
      (__attribute__((address_space(1))) void*)(void*)g,
      (__attribute__((address_space(3))) void*)(void*)l, 16, 0, 0);
}

// ---------------------------------------------------------------------------
// GEMM: C = epi(A[M,K] @ Bt[N,K]^T + bias [+residF]), 128x128 tile, BK=32,
// 4 waves x (64x64), global_load_lds staging (m97 structure).
// ---------------------------------------------------------------------------
__global__ __launch_bounds__(256) void gemm_bt(
    const bf16* __restrict__ A, const bf16* __restrict__ Bt,
    const float* __restrict__ bias,
    const bf16* __restrict__ residB, const float* __restrict__ residF,
    bf16* __restrict__ Cb, float* __restrict__ Cf,
    int M, int N, int K, int relu)
{
  __shared__ alignas(16) bf16 As[128 * 32];
  __shared__ alignas(16) bf16 Bs[128 * 32];
  const int tid  = threadIdx.x;
  const int wid  = tid >> 6;
  const int lane = tid & 63;
  const int l15  = lane & 15;
  const int quad = lane >> 4;
  const int bm = blockIdx.y * 128, bn = blockIdx.x * 128;
  const int wm = (wid & 1) * 64,  wn = (wid >> 1) * 64;

  f32x4 acc[4][4] = {};

  const int srow = tid >> 2;
  const int scol = (tid & 3) * 8;
  const bf16* ag0 = A  + (long)(bm + srow) * K + scol;
  const bf16* ag1 = ag0 + (long)64 * K;
  const bf16* bg0 = Bt + (long)(bn + srow) * K + scol;
  const bf16* bg1 = bg0 + (long)64 * K;
  bf16* lA0 = As + wid * 512;
  bf16* lA1 = As + 2048 + wid * 512;
  bf16* lB0 = Bs + wid * 512;
  bf16* lB1 = Bs + 2048 + wid * 512;

  for (int k0 = 0; k0 < K; k0 += 32) {
    gll16(ag0 + k0, lA0);
    gll16(ag1 + k0, lA1);
    gll16(bg0 + k0, lB0);
    gll16(bg1 + k0, lB1);
    __syncthreads();
    bf16x8 af[4], bfr[4];
#pragma unroll
    for (int i = 0; i < 4; ++i)
      af[i] = *(const bf16x8*)(As + (wm + i * 16 + l15) * 32 + quad * 8);
#pragma unroll
    for (int i = 0; i < 4; ++i)
      bfr[i] = *(const bf16x8*)(Bs + (wn + i * 16 + l15) * 32 + quad * 8);
#pragma unroll
    for (int mt = 0; mt < 4; ++mt)
#pragma unroll
      for (int nt = 0; nt < 4; ++nt)
        acc[mt][nt] = mfma16(af[mt], bfr[nt], acc[mt][nt]);
    __syncthreads();
  }

#pragma unroll
  for (int nt = 0; nt < 4; ++nt) {
    const int col = bn + wn + nt * 16 + l15;
    const float bv = bias ? bias[col] : 0.f;
#pragma unroll
    for (int mt = 0; mt < 4; ++mt) {
      const int row0 = bm + wm + mt * 16 + quad * 4;
#pragma unroll
      for (int r = 0; r < 4; ++r) {
        const long idx = (long)(row0 + r) * N + col;
        float v = acc[mt][nt][r] + bv;
        if (relu) v = fmaxf(v, 0.f);
        if (residB) v += (float)residB[idx];
        if (residF) v += residF[idx];
        if (Cb) Cb[idx] = (bf16)v;
        if (Cf) Cf[idx] = v;
      }
    }
  }
}

// ---------------------------------------------------------------------------
// Flash-style self-attention. R7 swizzle + R9 async-STAGE split + setprio.
// Per tile: barrier -> write prefetched regs to LDS -> barrier -> issue next
// tile's global loads (hide under compute) -> QK^T -> softmax -> PV.
// ---------------------------------------------------------------------------
__global__ __launch_bounds__(256, 2) void attn_self(
    const bf16* __restrict__ Q, const bf16* __restrict__ Km,
    const bf16* __restrict__ Vt, bf16* __restrict__ O)
{
  __shared__ alignas(16) bf16 Ks[16384];
  __shared__ alignas(16) bf16 Vs[16384];
  __shared__ alignas(16) bf16 Ps[8192];
  const int tid  = threadIdx.x;
  const int wid  = tid >> 6;
  const int lane = tid & 63;
  const int l15  = lane & 15;
  const int quad = lane >> 4;
  const int b = blockIdx.y >> 3, h = blockIdx.y & 7;
  const int q0 = blockIdx.x * 64;

  // swizzled read offset within a [rows][32] chunk: row=l15, slot=quad^((l15>>1)&3)
  const int rdoff = l15 * 32 + (((quad ^ ((l15 >> 1) & 3))) << 3);

  const long qb = ((long)(b * 1024 + q0 + wid * 16 + l15)) * 1024 + h * 128 + quad * 8;
  bf16x8 qf[4];
#pragma unroll
  for (int ks = 0; ks < 4; ++ks) qf[ks] = *(const bf16x8*)(Q + qb + ks * 32);

  f32x4 oacc[8] = {};
  float mrow[4], lrow[4];
#pragma unroll
  for (int r = 0; r < 4; ++r) { mrow[r] = -3.0e38f; lrow[r] = 0.f; }

  const long kbase = (long)(b * 1024) * 1024 + h * 128;
  const long vbase = (long)(b * 8 + h) * 128 * 1024;

  const int srow = tid >> 3;
  const int sc8  = (tid & 7) * 8;

  bf16* pw = Ps + wid * 2048;

  bf16x8 kra[8], vra[8], krb[8], vrb[8];

  auto loadkv = [&](bf16x8 (&kr)[8], bf16x8 (&vr)[8], const int kv0) {
#pragma unroll
    for (int dh = 0; dh < 2; ++dh)
#pragma unroll
      for (int kq = 0; kq < 4; ++kq)
        kr[dh * 4 + kq] = *(const bf16x8*)(
            Km + kbase + (long)(kv0 + kq * 32 + srow) * 1024 + dh * 64 + sc8);
#pragma unroll
    for (int kh = 0; kh < 2; ++kh)
#pragma unroll
      for (int dq = 0; dq < 4; ++dq)
        vr[kh * 4 + dq] = *(const bf16x8*)(
            Vt + vbase + (long)(dq * 32 + srow) * 1024 + kv0 + kh * 64 + sc8);
  };

  auto writekv = [&](bf16x8 (&kr)[8], bf16x8 (&vr)[8]) {
#pragma unroll
    for (int dh = 0; dh < 2; ++dh)
#pragma unroll
      for (int kq = 0; kq < 4; ++kq) {
        const int kv = kq * 32 + srow;
        const int d  = dh * 64 + sc8;
        *(bf16x8*)(Ks + (d >> 5) * 4096 + kv * 32 +
                   ((((d & 31) >> 3) ^ ((kv >> 1) & 3)) << 3)) = kr[dh * 4 + kq];
      }
#pragma unroll
    for (int kh = 0; kh < 2; ++kh)
#pragma unroll
      for (int dq = 0; dq < 4; ++dq) {
        const int d  = dq * 32 + srow;
        const int kv = kh * 64 + sc8;
        *(bf16x8*)(Vs + (kv >> 5) * 4096 + d * 32 +
                   ((((kv & 31) >> 3) ^ ((d >> 1) & 3)) << 3)) = vr[kh * 4 + dq];
      }
  };

  auto compute_tile = [&]() {
    f32x4 sacc[8] = {};
    __builtin_amdgcn_s_setprio(1);
#pragma unroll
    for (int nt = 0; nt < 8; ++nt)
#pragma unroll
      for (int ks = 0; ks < 4; ++ks)
        sacc[nt] = mfma16(qf[ks],
            *(const bf16x8*)(Ks + ks * 4096 + nt * 512 + rdoff),
            sacc[nt]);
    __builtin_amdgcn_s_setprio(0);

    float tm[4];
#pragma unroll
    for (int r = 0; r < 4; ++r) {
      float m = -3.0e38f;
#pragma unroll
      for (int nt = 0; nt < 8; ++nt) m = fmaxf(m, sacc[nt][r]);
      tm[r] = m * SCALE;
    }
#pragma unroll
    for (int off = 8; off; off >>= 1)
#pragma unroll
      for (int r = 0; r < 4; ++r) tm[r] = fmaxf(tm[r], __shfl_xor(tm[r], off));
    float alpha[4], psum[4];
#pragma unroll
    for (int r = 0; r < 4; ++r) {
      const float mnew = fmaxf(mrow[r], tm[r]);
      alpha[r] = __expf(mrow[r] - mnew);
      mrow[r] = mnew;
      psum[r] = 0.f;
    }
#pragma unroll
    for (int nt = 0; nt < 8; ++nt)
#pragma unroll
      for (int r = 0; r < 4; ++r) {
        const float p = __expf(sacc[nt][r] * SCALE - mrow[r]);
        psum[r] += p;
        // row=quad*4+r, col=(nt&1)*16+l15 -> slot=((nt&1)*2+(l15>>3)) ^ ((row>>1)&3)
        const int prow = quad * 4 + r;
        pw[(nt >> 1) * 512 + prow * 32 +
           (((((nt & 1) * 2 + (l15 >> 3)) ^ ((prow >> 1) & 3))) << 3) + (l15 & 7)] =
            (bf16)p;
      }
#pragma unroll
    for (int off = 8; off; off >>= 1)
#pragma unroll
      for (int r = 0; r < 4; ++r) psum[r] += __shfl_xor(psum[r], off);
#pragma unroll
    for (int r = 0; r < 4; ++r) lrow[r] = lrow[r] * alpha[r] + psum[r];
#pragma unroll
    for (int nt = 0; nt < 8; ++nt)
#pragma unroll
      for (int r = 0; r < 4; ++r) oacc[nt][r] *= alpha[r];
    __syncthreads();

    __builtin_amdgcn_s_setprio(1);
#pragma unroll
    for (int ks = 0; ks < 4; ++ks) {
      const bf16x8 pa = *(const bf16x8*)(pw + ks * 512 + rdoff);
#pragma unroll
      for (int nt = 0; nt < 8; ++nt)
        oacc[nt] = mfma16(pa,
            *(const bf16x8*)(Vs + ks * 4096 + nt * 512 + rdoff),
            oacc[nt]);
    }
    __builtin_amdgcn_s_setprio(0);
  };

  loadkv(kra, vra, 0);
  for (int tt = 0; tt < 4; ++tt) {
    // even tile 2*tt: consume A, prefetch into B
    __syncthreads();                 // prev tile PV reads done
    writekv(kra, vra);
    __syncthreads();
    loadkv(krb, vrb, (tt * 2 + 1) * 128);   // in flight under compute
    compute_tile();
    // odd tile 2*tt+1: consume B, prefetch into A
    __syncthreads();
    writekv(krb, vrb);
    __syncthreads();
    if (tt < 3) loadkv(kra, vra, (tt * 2 + 2) * 128);
    compute_tile();
  }

  float linv[4];
#pragma unroll
  for (int r = 0; r < 4; ++r) linv[r] = 1.f / lrow[r];
#pragma unroll
  for (int nt = 0; nt < 8; ++nt)
#pragma unroll
    for (int r = 0; r < 4; ++r) {
      const int row = q0 + wid * 16 + quad * 4 + r;
      O[((long)(b * 1024 + row)) * 1024 + h * 128 + nt * 16 + l15] =
          (bf16)(oacc[nt][r] * linv[r]);
    }
}

// ---------------------------------------------------------------------------
// gate2: G[z=(b,h)][w][v] = sigmoid(SCALE * CQ.CK^T). Grid (32 wtiles, 64 z).
// R7: Ks and Pt swizzled like attn_self.
// ---------------------------------------------------------------------------
__global__ __launch_bounds__(256) void gate2(
    const bf16* __restrict__ CQ, const bf16* __restrict__ CK,
    bf16* __restrict__ gA, bf16* __restrict__ gB)
{
  __shared__ alignas(16) bf16 Ks[16384];      // 4 dchunks x 128 v x 32 d
  __shared__ alignas(16) bf16 Pt[4][1024];    // per-wave 16w x 64v transpose
  const int tid  = threadIdx.x;
  const int wid  = tid >> 6;
  const int lane = tid & 63;
  const int l15  = lane & 15;
  const int quad = lane >> 4;
  const int z = blockIdx.y, b = z >> 3, h = z & 7;
  const int w0 = blockIdx.x * 32;
  const int rsel = wid & 1, vsel = wid >> 1;

  const int rdoff = l15 * 32 + (((quad ^ ((l15 >> 1) & 3))) << 3);

  bf16* Gz = (z < 32) ? (gA + (long)z * 524288) : (gB + (long)(z - 32) * 524288);

  const long qb = ((long)(b * 1024 + w0 + rsel * 16 + l15)) * 1024 + h * 128 + quad * 8;
  bf16x8 qf[4];
#pragma unroll
  for (int ks = 0; ks < 4; ++ks) qf[ks] = *(const bf16x8*)(CQ + qb + ks * 32);

  const int srow = tid >> 3;        // 0..31
  const int sc8  = (tid & 7) * 8;   // 0..56

  for (int vt = 0; vt < 4; ++vt) {
    const int v0 = vt * 128;
    __syncthreads();
#pragma unroll
    for (int i = 0; i < 4; ++i) {
      const int v = i * 32 + srow;
#pragma unroll
      for (int dh = 0; dh < 2; ++dh) {
        const int d = dh * 64 + sc8;
        bf16x8 val = *(const bf16x8*)(CK + ((long)(b * 512 + v0 + v)) * 1024 + h * 128 + d);
        *(bf16x8*)(Ks + (d >> 5) * 4096 + v * 32 +
                   (((((d & 31) >> 3) ^ ((v >> 1) & 3))) << 3)) = val;
      }
    }
    __syncthreads();

    f32x4 sacc[4] = {};
#pragma unroll
    for (int nt = 0; nt < 4; ++nt)
#pragma unroll
      for (int ks = 0; ks < 4; ++ks)
        sacc[nt] = mfma16(qf[ks],
            *(const bf16x8*)(Ks + ks * 4096 + vsel * 2048 + nt * 512 + rdoff),
            sacc[nt]);

    // sigmoid + per-wave transpose to row-major 16x64 (swizzled 16B slots;
    // rows are 128B so slot g in 0..7, g ^= (row>>1)&3)
#pragma unroll
    for (int nt = 0; nt < 4; ++nt)
#pragma unroll
      for (int r = 0; r < 4; ++r) {
        const float g = 1.f / (1.f + __expf(-sacc[nt][r] * SCALE));
        const int prow = quad * 4 + r;
        const int g0 = nt * 2 + (l15 >> 3);
        Pt[wid][prow * 64 + ((g0 ^ ((prow >> 1) & 3)) << 3) + (l15 & 7)] = (bf16)g;
      }
    // coalesced store: 16B/lane, 128B contiguous per row (in-wave LDS order ok)
#pragma unroll
    for (int pass = 0; pass < 2; ++pass) {
      const int f = pass * 512 + lane * 8;
      const int row = f >> 6, col = f & 63;
      const int gl = (lane & 7) ^ ((row >> 1) & 3);
      bf16x8 vv = *(const bf16x8*)(&Pt[wid][row * 64 + gl * 8]);
      *(bf16x8*)(Gz + (long)(w0 + rsel * 16 + row) * 512 + v0 + vsel * 64 + col) = vv;
    }
  }
}

// ---------------------------------------------------------------------------
// reduce_h: attn_out[b,w,v] = mean over 8 heads of G. Fully coalesced.
// ---------------------------------------------------------------------------
__global__ __launch_bounds__(256) void reduce_h(
    const bf16* __restrict__ gA, const bf16* __restrict__ gB,
    float* __restrict__ AOUT)
{
  const int idx = blockIdx.x * 256 + threadIdx.x;  // 1,048,576 total
  const int v4 = idx & 127;
  const int w  = (idx >> 7) & 1023;
  const int b  = idx >> 17;
  float s0 = 0.f, s1 = 0.f, s2 = 0.f, s3 = 0.f;
#pragma unroll
  for (int h = 0; h < 8; ++h) {
    const int z = b * 8 + h;
    const bf16* base = (z < 32) ? (gA + (long)z * 524288) : (gB + (long)(z - 32) * 524288);
    bf16x4 g = *(const bf16x4*)(base + (long)w * 512 + v4 * 4);
    s0 += (float)g[0]; s1 += (float)g[1]; s2 += (float)g[2]; s3 += (float)g[3];
  }
  *(float4*)(AOUT + (long)idx * 4) =
      make_float4(s0 * 0.125f, s1 * 0.125f, s2 * 0.125f, s3 * 0.125f);
}

// ---------------------------------------------------------------------------
// gemm_res: res[b,w,h*128+d] = G[z] (1024x512) @ CVt[z] (128x512)^T (m97).
// ---------------------------------------------------------------------------
__global__ __launch_bounds__(256) void gemm_res(
    const bf16* __restrict__ gA, const bf16* __restrict__ gB,
    const bf16* __restrict__ CVt, bf16* __restrict__ RES)
{
  __shared__ alignas(16) bf16 As[128 * 32];
  __shared__ alignas(16) bf16 Bs[128 * 32];
  const int tid  = threadIdx.x;
  const int wid  = tid >> 6;
  const int lane = tid & 63;
  const int l15  = lane & 15;
  const int quad = lane >> 4;
  const int z = blockIdx.z, b = z >> 3, h = z & 7;
  const bf16* A  = (z < 32) ? (gA + (long)z * 524288) : (gB + (long)(z - 32) * 524288);
  const bf16* Bt = CVt + (long)z * 65536;
  const int bm = blockIdx.x * 128;
  const int wm = (wid & 1) * 64, wn = (wid >> 1) * 64;

  f32x4 acc[4][4] = {};

  const int srow = tid >> 2;
  const int scol = (tid & 3) * 8;
  const bf16* ag0 = A  + (long)(bm + srow) * 512 + scol;
  const bf16* ag1 = ag0 + (long)64 * 512;
  const bf16* bg0 = Bt + (long)srow * 512 + scol;
  const bf16* bg1 = bg0 + (long)64 * 512;
  bf16* lA0 = As + wid * 512;
  bf16* lA1 = As + 2048 + wid * 512;
  bf16* lB0 = Bs + wid * 512;
  bf16* lB1 = Bs + 2048 + wid * 512;

  for (int k0 = 0; k0 < 512; k0 += 32) {
    gll16(ag0 + k0, lA0);
    gll16(ag1 + k0, lA1);
    gll16(bg0 + k0, lB0);
    gll16(bg1 + k0, lB1);
    __syncthreads();
    bf16x8 af[4], bfr[4];
#pragma unroll
    for (int i = 0; i < 4; ++i)
      af[i] = *(const bf16x8*)(As + (wm + i * 16 + l15) * 32 + quad * 8);
#pragma unroll
    for (int i = 0; i < 4; ++i)
      bfr[i] = *(const bf16x8*)(Bs + (wn + i * 16 + l15) * 32 + quad * 8);
#pragma unroll
    for (int mt = 0; mt < 4; ++mt)
#pragma unroll
      for (int nt = 0; nt < 4; ++nt)
        acc[mt][nt] = mfma16(af[mt], bfr[nt], acc[mt][nt]);
    __syncthreads();
  }

#pragma unroll
  for (int nt = 0; nt < 4; ++nt) {
    const int col = h * 128 + wn + nt * 16 + l15;
#pragma unroll
    for (int mt = 0; mt < 4; ++mt) {
      const int row0 = bm + wm + mt * 16 + quad * 4;
#pragma unroll
      for (int r = 0; r < 4; ++r)
        RES[((long)(b * 1024 + row0 + r)) * 1024 + col] = (bf16)acc[mt][nt][r];
    }
  }
}

// ---------------------------------------------------------------------------
// Batched transpose through LDS: T in {float,bf16} -> bf16 out.
// ---------------------------------------------------------------------------
template <typename T>
__global__ __launch_bounds__(256) void transpose_k(
    const T* __restrict__ in, bf16* __restrict__ out,
    int sIR, int sOR, long inStrideB, long inStrideH, long outStrideZ, int H)
{
  __shared__ bf16 t[32][33];
  const int z = blockIdx.z;
  const T* ib = in + (long)(z / H) * inStrideB + (long)(z % H) * inStrideH;
  bf16* ob = out + (long)z * outStrideZ;
  const int r0 = blockIdx.x * 32, c0 = blockIdx.y * 32;
  const int tx = threadIdx.x & 31, ty = threadIdx.x >> 5;
#pragma unroll
  for (int i = 0; i < 32; i += 8)
    t[ty + i][tx] = (bf16)(float)ib[(long)(r0 + ty + i) * sIR + (c0 + tx)];
  __syncthreads();
#pragma unroll
  for (int i = 0; i < 32; i += 8)
    ob[(long)(c0 + ty + i) * sOR + (r0 + tx)] = t[tx][ty + i];
}

// ---------------------------------------------------------------------------
// LayerNorm over D=1024, 1 wave/row, 4 rows/block. TI in {float,bf16}.
// Optional second input: out = LN(X;G1,B1)+LN(X2;G2,B2). bf16 out.
// ---------------------------------------------------------------------------
__device__ __forceinline__ void load16v(float* d, const bf16* p) {
  bf16x8 a = *(const bf16x8*)p, b2 = *(const bf16x8*)(p + 8);
#pragma unroll
  for (int j = 0; j < 8; ++j) { d[j] = (float)a[j]; d[j + 8] = (float)b2[j]; }
}
__device__ __forceinline__ void load16v(float* d, const float* p) {
#pragma unroll
  for (int j = 0; j < 4; ++j) {
    float4 v = ((const float4*)p)[j];
    d[4*j] = v.x; d[4*j+1] = v.y; d[4*j+2] = v.z; d[4*j+3] = v.w;
  }
}

template <typename TI>
__global__ __launch_bounds__(256) void ln_k(
    const TI* __restrict__ X,  const float* __restrict__ G1, const float* __restrict__ B1,
    const TI* __restrict__ X2, const float* __restrict__ G2, const float* __restrict__ B2,
    bf16* __restrict__ out)
{
  const int tid  = threadIdx.x;
  const int wid  = tid >> 6;
  const int lane = tid & 63;
  const long row = (long)blockIdx.x * 4 + wid;
  const int c0 = lane * 16;
  const long base = row * 1024 + c0;

  float a[16], b[16] = {};
  load16v(a, X + base);
  float s = 0.f, ss = 0.f;
#pragma unroll
  for (int j = 0; j < 16; ++j) { s += a[j]; ss += a[j] * a[j]; }
  const bool two = (X2 != nullptr);
  float s2 = 0.f, ss2 = 0.f;
  if (two) {
    load16v(b, X2 + base);
#pragma unroll
    for (int j = 0; j < 16; ++j) { s2 += b[j]; ss2 += b[j] * b[j]; }
  }
#pragma unroll
  for (int off = 32; off; off >>= 1) { s += __shfl_xor(s, off); ss += __shfl_xor(ss, off); }
  if (two) {
#pragma unroll
    for (int off = 32; off; off >>= 1) { s2 += __shfl_xor(s2, off); ss2 += __shfl_xor(ss2, off); }
  }
  const float inv = 1.f / 1024.f;
  const float m1 = s * inv;
  const float r1 = rsqrtf(fmaxf(ss * inv - m1 * m1, 0.f) + 1e-5f);
  float m2 = 0.f, r2 = 0.f;
  if (two) { m2 = s2 * inv; r2 = rsqrtf(fmaxf(ss2 * inv - m2 * m2, 0.f) + 1e-5f); }

  bf16x8 o0, o1;
#pragma unroll
  for (int j = 0; j < 16; ++j) {
    float v = (a[j] - m1) * r1 * G1[c0 + j] + B1[c0 + j];
    if (two) v += (b[j] - m2) * r2 * G2[c0 + j] + B2[c0 + j];
    if (j < 8) o0[j] = (bf16)v; else o1[j - 8] = (bf16)v;
  }
  *(bf16x8*)(out + base) = o0;
  *(bf16x8*)(out + base + 8) = o1;
}

// ---------------------------------------------------------------------------
extern "C" void kernel_launch(void* const* d_in, const int* in_sizes, int n_in,
                              void* d_out, int out_size, void* d_ws, size_t ws_size,
                              hipStream_t stream) {
  (void)in_sizes; (void)n_in; (void)out_size; (void)ws_size;

  const float* x   = (const float*)d_in[0];
  const float* y   = (const float*)d_in[1];
  const float* r1g = (const float*)d_in[3];  const float* r1b = (const float*)d_in[4];
  const float* sa_wq = (const float*)d_in[5];  const float* sa_bq = (const float*)d_in[6];
  const float* sa_wk = (const float*)d_in[7];  const float* sa_bk = (const float*)d_in[8];
  const float* sa_wv = (const float*)d_in[9];  const float* sa_bv = (const float*)d_in[10];
  const float* sa_wo = (const float*)d_in[11]; const float* sa_bo = (const float*)d_in[12];
  const float* tn_g = (const float*)d_in[13];  const float* tn_b = (const float*)d_in[14];
  const float* an_g = (const float*)d_in[15];  const float* an_b = (const float*)d_in[16];
  const float* ca_wq = (const float*)d_in[17]; const float* ca_bq = (const float*)d_in[18];
  const float* ca_wk = (const float*)d_in[19]; const float* ca_bk = (const float*)d_in[20];
  const float* ca_wv = (const float*)d_in[21];
  const float* ca_bv = (const float*)d_in[22];
  const float* n1g = (const float*)d_in[23];   const float* n1b = (const float*)d_in[24];
  const float* n2g = (const float*)d_in[25];   const float* n2b = (const float*)d_in[26];
  const float* r2g = (const float*)d_in[27];   const float* r2b = (const float*)d_in[28];
  const float* fw1 = (const float*)d_in[29];   const float* fb1 = (const float*)d_in[30];
  const float* fw2 = (const float*)d_in[31];   const float* fb2 = (const float*)d_in[32];

  // ---- static 150MB lifetime-planned workspace ----
  char* wsb = (char*)d_ws;
  const size_t MBy = 1048576;
  bf16* fw1T = (bf16*)(wsb + 0 * MBy);
  bf16* fw2T = (bf16*)(wsb + 4 * MBy);
  bf16* wqT  = (bf16*)(wsb + 8 * MBy);
  bf16* wkT  = (bf16*)(wsb + 10 * MBy);
  bf16* wvT  = (bf16*)(wsb + 12 * MBy);
  bf16* woT  = (bf16*)(wsb + 14 * MBy);
  bf16* cwqT = (bf16*)(wsb + 16 * MBy);
  bf16* cwkT = (bf16*)(wsb + 18 * MBy);
  bf16* cwvT = (bf16*)(wsb + 20 * MBy);
  bf16* h_bf = (bf16*)(wsb + 22 * MBy);
  bf16* t_bf = h_bf;  bf16* h2_bf = h_bf;
  bf16* q_bf = (bf16*)(wsb + 38 * MBy);
  bf16* av_bf = q_bf;
  bf16* gA = (bf16*)(wsb + 22 * MBy);           // z 0..31 (h/t/q/av dead)
  bf16* k_bf = (bf16*)(wsb + 54 * MBy);
  bf16* cq_bf = k_bf;  bf16* res_b = k_bf;
  bf16* v_bf = (bf16*)(wsb + 70 * MBy);
  bf16* ck_bf = v_bf;
  bf16* cv_bf = (bf16*)(wsb + 78 * MBy);
  bf16* x2_b  = v_bf;
  bf16* vT  = (bf16*)(wsb + 86 * MBy);
  bf16* cvT = vT;
  bf16* o_bf = (bf16*)(wsb + 102 * MBy);
  bf16* x1_b = o_bf;
  bf16* gB  = (bf16*)(wsb + 118 * MBy);          // z 32..63
  bf16* ffh = gB;

  float* out_x    = (float*)d_out;
  float* out_attn = out_x + 8 * 1024 * 1024;

  const dim3 blk(256);

  transpose_k<float><<<dim3(32, 32, 1), blk, 0, stream>>>(sa_wq, wqT, 1024, 1024, 0, 0, 0, 1);
  transpose_k<float><<<dim3(32, 32, 1), blk, 0, stream>>>(sa_wk, wkT, 1024, 1024, 0, 0, 0, 1);
  transpose_k<float><<<dim3(32, 32, 1), blk, 0, stream>>>(sa_wv, wvT, 1024, 1024, 0, 0, 0, 1);
  transpose_k<float><<<dim3(32, 32, 1), blk, 0, stream>>>(sa_wo, woT, 1024, 1024, 0, 0, 0, 1);
  transpose_k<float><<<dim3(32, 32, 1), blk, 0, stream>>>(ca_wq, cwqT, 1024, 1024, 0, 0, 0, 1);
  transpose_k<float><<<dim3(32, 32, 1), blk, 0, stream>>>(ca_wk, cwkT, 1024, 1024, 0, 0, 0, 1);
  transpose_k<float><<<dim3(32, 32, 1), blk, 0, stream>>>(ca_wv, cwvT, 1024, 1024, 0, 0, 0, 1);
  transpose_k<float><<<dim3(32, 64, 1), blk, 0, stream>>>(fw1, fw1T, 2048, 1024, 0, 0, 0, 1);
  transpose_k<float><<<dim3(64, 32, 1), blk, 0, stream>>>(fw2, fw2T, 1024, 2048, 0, 0, 0, 1);

  ln_k<float><<<dim3(2048), blk, 0, stream>>>(x, r1g, r1b, nullptr, nullptr, nullptr, h_bf);

  gemm_bt<<<dim3(8, 64), blk, 0, stream>>>(h_bf, wqT, sa_bq, nullptr, nullptr, q_bf, nullptr, 8192, 1024, 1024, 0);
  gemm_bt<<<dim3(8, 64), blk, 0, stream>>>(h_bf, wkT, sa_bk, nullptr, nullptr, k_bf, nullptr, 8192, 1024, 1024, 0);
  gemm_bt<<<dim3(8, 64), blk, 0, stream>>>(h_bf, wvT, sa_bv, nullptr, nullptr, v_bf, nullptr, 8192, 1024, 1024, 0);

  transpose_k<bf16><<<dim3(32, 4, 64), blk, 0, stream>>>(v_bf, vT, 1024, 1024,
      (long)1024 * 1024, 128, (long)128 * 1024, 8);

  attn_self<<<dim3(16, 64), blk, 0, stream>>>(q_bf, k_bf, vT, o_bf);

  gemm_bt<<<dim3(8, 64), blk, 0, stream>>>(o_bf, woT, sa_bo, nullptr, x, x1_b, nullptr, 8192, 1024, 1024, 0);

  ln_k<bf16><<<dim3(2048), blk, 0, stream>>>(x1_b, tn_g, tn_b, nullptr, nullptr, nullptr, t_bf);
  ln_k<float><<<dim3(1024), blk, 0, stream>>>(y, an_g, an_b, nullptr, nullptr, nullptr, av_bf);

  gemm_bt<<<dim3(8, 64), blk, 0, stream>>>(t_bf, cwqT, ca_bq, nullptr, nullptr, cq_bf, nullptr, 8192, 1024, 1024, 0);
  gemm_bt<<<dim3(8, 32), blk, 0, stream>>>(av_bf, cwkT, ca_bk, nullptr, nullptr, ck_bf, nullptr, 4096, 1024, 1024, 0);
  gemm_bt<<<dim3(8, 32), blk, 0, stream>>>(av_bf, cwvT, ca_bv, nullptr, nullptr, cv_bf, nullptr, 4096, 1024, 1024, 0);

  transpose_k<bf16><<<dim3(16, 4, 64), blk, 0, stream>>>(cv_bf, cvT, 1024, 512,
      (long)512 * 1024, 128, (long)128 * 512, 8);

  // gate (per-head blocks) -> G; then attn_out mean; then res GEMM
  gate2<<<dim3(32, 64), blk, 0, stream>>>(cq_bf, ck_bf, gA, gB);
  reduce_h<<<dim3(4096), blk, 0, stream>>>(gA, gB, out_attn);
  gemm_res<<<dim3(8, 1, 64), blk, 0, stream>>>(gA, gB, cvT, res_b);

  ln_k<bf16><<<dim3(2048), blk, 0, stream>>>(x1_b, n1g, n1b, res_b, n2g, n2b, x2_b);
  ln_k<bf16><<<dim3(2048), blk, 0, stream>>>(x2_b, r2g, r2b, nullptr, nullptr, nullptr, h2_bf);

  gemm_bt<<<dim3(16, 64), blk, 0, stream>>>(h2_bf, fw1T, fb1, nullptr, nullptr, ffh, nullptr, 8192, 2048, 1024, 1);
  gemm_bt<<<dim3(8, 64), blk, 0, stream>>>(ffh, fw2T, fb2, x2_b, nullptr, nullptr, out_x, 8192, 1024, 2048, 0);
}

// Round 4
// 890.081 us; speedup vs baseline: 1.0884x; 1.0884x over previous
//
#include <hip/hip_runtime.h>

// ---------------------------------------------------------------------------
// CrossDecoderLayer on MI355X (gfx950). External I/O fp32; internal bf16
// MFMA, fp32 accumulate. B=8, W=1024, V=512, D=1024, H=8, DK=128.
// R7 : XOR-swizzle on attn_self Ks/Vs/Ps and gate2 Ks/Pt (conflicts 15M->4M).
// R9 : FAILED (reg-prefetch spilled: WRITE_SIZE 16->54MB). Reverted.
// R10: launch fusion — 7 weight transposes in one z-batched launch;
//      QKV projections in one gemm_bt_split (N=3072, split epilogue);
//      CK/CV in one gemm_bt_split (N=2048). 30 -> 21 dispatches.
// ---------------------------------------------------------------------------

typedef __bf16 bf16;
typedef bf16  bf16x4 __attribute__((ext_vector_type(4)));
typedef bf16  bf16x8 __attribute__((ext_vector_type(8)));
typedef float f32x4  __attribute__((ext_vector_type(4)));

#define SCALE 0.08838834764831845f  // 1/sqrt(128)

__device__ __forceinline__ f32x4 mfma16(bf16x8 a, bf16x8 b, f32x4 c) {
  return __builtin_amdgcn_mfma_f32_16x16x32_bf16(a, b, c, 0, 0, 0);
}

__device__ __forceinline__ void gll16(const bf16* g, bf16* l) {
  __builtin_amdgcn_global_load_lds(
      (__attribute__((address_space(1))) void*)(void*)g,
      (__attribute__((address_space(3))) void*)(void*)l, 16, 0, 0);
}

// ---------------------------------------------------------------------------
// GEMM: C = epi(A[M,K] @ Bt[N,K]^T + bias [+residF]), 128x128 tile, BK=32,
// 4 waves x (64x64), global_load_lds staging (m97 structure).
// ---------------------------------------------------------------------------
__global__ __launch_bounds__(256) void gemm_bt(
    const bf16* __restrict__ A, const bf16* __restrict__ Bt,
    const float* __restrict__ bias,
    const bf16* __restrict__ residB, const float* __restrict__ residF,
    bf16* __restrict__ Cb, float* __restrict__ Cf,
    int M, int N, int K, int relu)
{
  __shared__ alignas(16) bf16 As[128 * 32];
  __shared__ alignas(16) bf16 Bs[128 * 32];
  const int tid  = threadIdx.x;
  const int wid  = tid >> 6;
  const int lane = tid & 63;
  const int l15  = lane & 15;
  const int quad = lane >> 4;
  const int bm = blockIdx.y * 128, bn = blockIdx.x * 128;
  const int wm = (wid & 1) * 64,  wn = (wid >> 1) * 64;

  f32x4 acc[4][4] = {};

  const int srow = tid >> 2;
  const int scol = (tid & 3) * 8;
  const bf16* ag0 = A  + (long)(bm + srow) * K + scol;
  const bf16* ag1 = ag0 + (long)64 * K;
  const bf16* bg0 = Bt + (long)(bn + srow) * K + scol;
  const bf16* bg1 = bg0 + (long)64 * K;
  bf16* lA0 = As + wid * 512;
  bf16* lA1 = As + 2048 + wid * 512;
  bf16* lB0 = Bs + wid * 512;
  bf16* lB1 = Bs + 2048 + wid * 512;

  for (int k0 = 0; k0 < K; k0 += 32) {
    gll16(ag0 + k0, lA0);
    gll16(ag1 + k0, lA1);
    gll16(bg0 + k0, lB0);
    gll16(bg1 + k0, lB1);
    __syncthreads();
    bf16x8 af[4], bfr[4];
#pragma unroll
    for (int i = 0; i < 4; ++i)
      af[i] = *(const bf16x8*)(As + (wm + i * 16 + l15) * 32 + quad * 8);
#pragma unroll
    for (int i = 0; i < 4; ++i)
      bfr[i] = *(const bf16x8*)(Bs + (wn + i * 16 + l15) * 32 + quad * 8);
#pragma unroll
    for (int mt = 0; mt < 4; ++mt)
#pragma unroll
      for (int nt = 0; nt < 4; ++nt)
        acc[mt][nt] = mfma16(af[mt], bfr[nt], acc[mt][nt]);
    __syncthreads();
  }

#pragma unroll
  for (int nt = 0; nt < 4; ++nt) {
    const int col = bn + wn + nt * 16 + l15;
    const float bv = bias ? bias[col] : 0.f;
#pragma unroll
    for (int mt = 0; mt < 4; ++mt) {
      const int row0 = bm + wm + mt * 16 + quad * 4;
#pragma unroll
      for (int r = 0; r < 4; ++r) {
        const long idx = (long)(row0 + r) * N + col;
        float v = acc[mt][nt][r] + bv;
        if (relu) v = fmaxf(v, 0.f);
        if (residB) v += (float)residB[idx];
        if (residF) v += residF[idx];
        if (Cb) Cb[idx] = (bf16)v;
        if (Cf) Cf[idx] = v;
      }
    }
  }
}

// ---------------------------------------------------------------------------
// gemm_bt_split: same m97 GEMM over a packed Bt of Ntot columns, but the
// epilogue splits output into per-1024-column buffers (each [M][1024]).
// chunk id is block-uniform (128-col tile never spans a 1024 boundary).
// ---------------------------------------------------------------------------
struct Out3 {
  bf16* o0; bf16* o1; bf16* o2;
  const float* b0; const float* b1; const float* b2;
};

__global__ __launch_bounds__(256) void gemm_bt_split(
    const bf16* __restrict__ A, const bf16* __restrict__ Bt,
    Out3 so, int M, int Ntot, int K)
{
  __shared__ alignas(16) bf16 As[128 * 32];
  __shared__ alignas(16) bf16 Bs[128 * 32];
  const int tid  = threadIdx.x;
  const int wid  = tid >> 6;
  const int lane = tid & 63;
  const int l15  = lane & 15;
  const int quad = lane >> 4;
  const int bm = blockIdx.y * 128, bn = blockIdx.x * 128;
  const int wm = (wid & 1) * 64,  wn = (wid >> 1) * 64;

  const int ch = bn >> 10;
  bf16* C = (ch == 0) ? so.o0 : (ch == 1 ? so.o1 : so.o2);
  const float* bp = (ch == 0) ? so.b0 : (ch == 1 ? so.b1 : so.b2);

  f32x4 acc[4][4] = {};

  const int srow = tid >> 2;
  const int scol = (tid & 3) * 8;
  const bf16* ag0 = A  + (long)(bm + srow) * K + scol;
  const bf16* ag1 = ag0 + (long)64 * K;
  const bf16* bg0 = Bt + (long)(bn + srow) * K + scol;
  const bf16* bg1 = bg0 + (long)64 * K;
  bf16* lA0 = As + wid * 512;
  bf16* lA1 = As + 2048 + wid * 512;
  bf16* lB0 = Bs + wid * 512;
  bf16* lB1 = Bs + 2048 + wid * 512;

  for (int k0 = 0; k0 < K; k0 += 32) {
    gll16(ag0 + k0, lA0);
    gll16(ag1 + k0, lA1);
    gll16(bg0 + k0, lB0);
    gll16(bg1 + k0, lB1);
    __syncthreads();
    bf16x8 af[4], bfr[4];
#pragma unroll
    for (int i = 0; i < 4; ++i)
      af[i] = *(const bf16x8*)(As + (wm + i * 16 + l15) * 32 + quad * 8);
#pragma unroll
    for (int i = 0; i < 4; ++i)
      bfr[i] = *(const bf16x8*)(Bs + (wn + i * 16 + l15) * 32 + quad * 8);
#pragma unroll
    for (int mt = 0; mt < 4; ++mt)
#pragma unroll
      for (int nt = 0; nt < 4; ++nt)
        acc[mt][nt] = mfma16(af[mt], bfr[nt], acc[mt][nt]);
    __syncthreads();
  }

#pragma unroll
  for (int nt = 0; nt < 4; ++nt) {
    const int col = bn + wn + nt * 16 + l15;
    const int cc  = col & 1023;
    const float bv = bp[cc];
#pragma unroll
    for (int mt = 0; mt < 4; ++mt) {
      const int row0 = bm + wm + mt * 16 + quad * 4;
#pragma unroll
      for (int r = 0; r < 4; ++r)
        C[(long)(row0 + r) * 1024 + cc] = (bf16)(acc[mt][nt][r] + bv);
    }
  }
  (void)M; (void)Ntot;
}

// ---------------------------------------------------------------------------
// Flash-style self-attention (R7: swizzled Ks/Vs/Ps; reg-prefetch reverted).
// ---------------------------------------------------------------------------
__global__ __launch_bounds__(256) void attn_self(
    const bf16* __restrict__ Q, const bf16* __restrict__ Km,
    const bf16* __restrict__ Vt, bf16* __restrict__ O)
{
  __shared__ alignas(16) bf16 Ks[16384];
  __shared__ alignas(16) bf16 Vs[16384];
  __shared__ alignas(16) bf16 Ps[8192];
  const int tid  = threadIdx.x;
  const int wid  = tid >> 6;
  const int lane = tid & 63;
  const int l15  = lane & 15;
  const int quad = lane >> 4;
  const int b = blockIdx.y >> 3, h = blockIdx.y & 7;
  const int q0 = blockIdx.x * 64;

  // swizzled read offset within a [rows][32] chunk: row=l15, slot=quad^((l15>>1)&3)
  const int rdoff = l15 * 32 + (((quad ^ ((l15 >> 1) & 3))) << 3);

  const long qb = ((long)(b * 1024 + q0 + wid * 16 + l15)) * 1024 + h * 128 + quad * 8;
  bf16x8 qf[4];
#pragma unroll
  for (int ks = 0; ks < 4; ++ks) qf[ks] = *(const bf16x8*)(Q + qb + ks * 32);

  f32x4 oacc[8] = {};
  float mrow[4], lrow[4];
#pragma unroll
  for (int r = 0; r < 4; ++r) { mrow[r] = -3.0e38f; lrow[r] = 0.f; }

  const long kbase = (long)(b * 1024) * 1024 + h * 128;
  const long vbase = (long)(b * 8 + h) * 128 * 1024;

  const int srow = tid >> 3;
  const int sc8  = (tid & 7) * 8;

  for (int t = 0; t < 8; ++t) {
    const int kv0 = t * 128;
    __syncthreads();
#pragma unroll
    for (int dh = 0; dh < 2; ++dh)
#pragma unroll
      for (int kq = 0; kq < 4; ++kq) {
        const int kv = kq * 32 + srow;
        const int d  = dh * 64 + sc8;
        bf16x8 v = *(const bf16x8*)(Km + kbase + (long)(kv0 + kv) * 1024 + d);
        // row=kv, slot=((d&31)>>3) ^ ((kv>>1)&3)
        *(bf16x8*)(Ks + (d >> 5) * 4096 + kv * 32 +
                   (((((d & 31) >> 3) ^ ((kv >> 1) & 3))) << 3)) = v;
      }
#pragma unroll
    for (int kh = 0; kh < 2; ++kh)
#pragma unroll
      for (int dq = 0; dq < 4; ++dq) {
        const int d  = dq * 32 + srow;
        const int kv = kh * 64 + sc8;
        bf16x8 v = *(const bf16x8*)(Vt + vbase + (long)d * 1024 + kv0 + kv);
        // row=d, slot=((kv&31)>>3) ^ ((d>>1)&3)
        *(bf16x8*)(Vs + (kv >> 5) * 4096 + d * 32 +
                   (((((kv & 31) >> 3) ^ ((d >> 1) & 3))) << 3)) = v;
      }
    __syncthreads();

    f32x4 sacc[8] = {};
#pragma unroll
    for (int nt = 0; nt < 8; ++nt)
#pragma unroll
      for (int ks = 0; ks < 4; ++ks)
        sacc[nt] = mfma16(qf[ks],
            *(const bf16x8*)(Ks + ks * 4096 + nt * 512 + rdoff),
            sacc[nt]);

    float tm[4];
#pragma unroll
    for (int r = 0; r < 4; ++r) {
      float m = -3.0e38f;
#pragma unroll
      for (int nt = 0; nt < 8; ++nt) m = fmaxf(m, sacc[nt][r]);
      tm[r] = m * SCALE;
    }
#pragma unroll
    for (int off = 8; off; off >>= 1)
#pragma unroll
      for (int r = 0; r < 4; ++r) tm[r] = fmaxf(tm[r], __shfl_xor(tm[r], off));
    float alpha[4], psum[4];
#pragma unroll
    for (int r = 0; r < 4; ++r) {
      const float mnew = fmaxf(mrow[r], tm[r]);
      alpha[r] = __expf(mrow[r] - mnew);
      mrow[r] = mnew;
      psum[r] = 0.f;
    }
    bf16* pw = Ps + wid * 2048;
#pragma unroll
    for (int nt = 0; nt < 8; ++nt)
#pragma unroll
      for (int r = 0; r < 4; ++r) {
        const float p = __expf(sacc[nt][r] * SCALE - mrow[r]);
        psum[r] += p;
        // row=quad*4+r, col=(nt&1)*16+l15 -> slot=((nt&1)*2+(l15>>3)) ^ ((row>>1)&3)
        const int prow = quad * 4 + r;
        pw[(nt >> 1) * 512 + prow * 32 +
           (((((nt & 1) * 2 + (l15 >> 3)) ^ ((prow >> 1) & 3))) << 3) + (l15 & 7)] =
            (bf16)p;
      }
#pragma unroll
    for (int off = 8; off; off >>= 1)
#pragma unroll
      for (int r = 0; r < 4; ++r) psum[r] += __shfl_xor(psum[r], off);
#pragma unroll
    for (int r = 0; r < 4; ++r) lrow[r] = lrow[r] * alpha[r] + psum[r];
#pragma unroll
    for (int nt = 0; nt < 8; ++nt)
#pragma unroll
      for (int r = 0; r < 4; ++r) oacc[nt][r] *= alpha[r];
    __syncthreads();

#pragma unroll
    for (int ks = 0; ks < 4; ++ks) {
      const bf16x8 pa = *(const bf16x8*)(pw + ks * 512 + rdoff);
#pragma unroll
      for (int nt = 0; nt < 8; ++nt)
        oacc[nt] = mfma16(pa,
            *(const bf16x8*)(Vs + ks * 4096 + nt * 512 + rdoff),
            oacc[nt]);
    }
  }

  float linv[4];
#pragma unroll
  for (int r = 0; r < 4; ++r) linv[r] = 1.f / lrow[r];
#pragma unroll
  for (int nt = 0; nt < 8; ++nt)
#pragma unroll
    for (int r = 0; r < 4; ++r) {
      const int row = q0 + wid * 16 + quad * 4 + r;
      O[((long)(b * 1024 + row)) * 1024 + h * 128 + nt * 16 + l15] =
          (bf16)(oacc[nt][r] * linv[r]);
    }
}

// ---------------------------------------------------------------------------
// gate2: G[z=(b,h)][w][v] = sigmoid(SCALE * CQ.CK^T). Grid (32 wtiles, 64 z).
// R7: Ks and Pt swizzled like attn_self.
// ---------------------------------------------------------------------------
__global__ __launch_bounds__(256) void gate2(
    const bf16* __restrict__ CQ, const bf16* __restrict__ CK,
    bf16* __restrict__ gA, bf16* __restrict__ gB)
{
  __shared__ alignas(16) bf16 Ks[16384];      // 4 dchunks x 128 v x 32 d
  __shared__ alignas(16) bf16 Pt[4][1024];    // per-wave 16w x 64v transpose
  const int tid  = threadIdx.x;
  const int wid  = tid >> 6;
  const int lane = tid & 63;
  const int l15  = lane & 15;
  const int quad = lane >> 4;
  const int z = blockIdx.y, b = z >> 3, h = z & 7;
  const int w0 = blockIdx.x * 32;
  const int rsel = wid & 1, vsel = wid >> 1;

  const int rdoff = l15 * 32 + (((quad ^ ((l15 >> 1) & 3))) << 3);

  bf16* Gz = (z < 32) ? (gA + (long)z * 524288) : (gB + (long)(z - 32) * 524288);

  const long qb = ((long)(b * 1024 + w0 + rsel * 16 + l15)) * 1024 + h * 128 + quad * 8;
  bf16x8 qf[4];
#pragma unroll
  for (int ks = 0; ks < 4; ++ks) qf[ks] = *(const bf16x8*)(CQ + qb + ks * 32);

  const int srow = tid >> 3;        // 0..31
  const int sc8  = (tid & 7) * 8;   // 0..56

  for (int vt = 0; vt < 4; ++vt) {
    const int v0 = vt * 128;
    __syncthreads();
#pragma unroll
    for (int i = 0; i < 4; ++i) {
      const int v = i * 32 + srow;
#pragma unroll
      for (int dh = 0; dh < 2; ++dh) {
        const int d = dh * 64 + sc8;
        bf16x8 val = *(const bf16x8*)(CK + ((long)(b * 512 + v0 + v)) * 1024 + h * 128 + d);
        *(bf16x8*)(Ks + (d >> 5) * 4096 + v * 32 +
                   (((((d & 31) >> 3) ^ ((v >> 1) & 3))) << 3)) = val;
      }
    }
    __syncthreads();

    f32x4 sacc[4] = {};
#pragma unroll
    for (int nt = 0; nt < 4; ++nt)
#pragma unroll
      for (int ks = 0; ks < 4; ++ks)
        sacc[nt] = mfma16(qf[ks],
            *(const bf16x8*)(Ks + ks * 4096 + vsel * 2048 + nt * 512 + rdoff),
            sacc[nt]);

    // sigmoid + per-wave transpose to row-major 16x64 (swizzled 16B slots;
    // rows are 128B so slot g in 0..7, g ^= (row>>1)&3)
#pragma unroll
    for (int nt = 0; nt < 4; ++nt)
#pragma unroll
      for (int r = 0; r < 4; ++r) {
        const float g = 1.f / (1.f + __expf(-sacc[nt][r] * SCALE));
        const int prow = quad * 4 + r;
        const int g0 = nt * 2 + (l15 >> 3);
        Pt[wid][prow * 64 + ((g0 ^ ((prow >> 1) & 3)) << 3) + (l15 & 7)] = (bf16)g;
      }
    // coalesced store: 16B/lane, 128B contiguous per row (in-wave LDS order ok)
#pragma unroll
    for (int pass = 0; pass < 2; ++pass) {
      const int f = pass * 512 + lane * 8;
      const int row = f >> 6, col = f & 63;
      const int gl = (lane & 7) ^ ((row >> 1) & 3);
      bf16x8 vv = *(const bf16x8*)(&Pt[wid][row * 64 + gl * 8]);
      *(bf16x8*)(Gz + (long)(w0 + rsel * 16 + row) * 512 + v0 + vsel * 64 + col) = vv;
    }
  }
}

// ---------------------------------------------------------------------------
// reduce_h: attn_out[b,w,v] = mean over 8 heads of G. Fully coalesced.
// ---------------------------------------------------------------------------
__global__ __launch_bounds__(256) void reduce_h(
    const bf16* __restrict__ gA, const bf16* __restrict__ gB,
    float* __restrict__ AOUT)
{
  const int idx = blockIdx.x * 256 + threadIdx.x;  // 1,048,576 total
  const int v4 = idx & 127;
  const int w  = (idx >> 7) & 1023;
  const int b  = idx >> 17;
  float s0 = 0.f, s1 = 0.f, s2 = 0.f, s3 = 0.f;
#pragma unroll
  for (int h = 0; h < 8; ++h) {
    const int z = b * 8 + h;
    const bf16* base = (z < 32) ? (gA + (long)z * 524288) : (gB + (long)(z - 32) * 524288);
    bf16x4 g = *(const bf16x4*)(base + (long)w * 512 + v4 * 4);
    s0 += (float)g[0]; s1 += (float)g[1]; s2 += (float)g[2]; s3 += (float)g[3];
  }
  *(float4*)(AOUT + (long)idx * 4) =
      make_float4(s0 * 0.125f, s1 * 0.125f, s2 * 0.125f, s3 * 0.125f);
}

// ---------------------------------------------------------------------------
// gemm_res: res[b,w,h*128+d] = G[z] (1024x512) @ CVt[z] (128x512)^T (m97).
// ---------------------------------------------------------------------------
__global__ __launch_bounds__(256) void gemm_res(
    const bf16* __restrict__ gA, const bf16* __restrict__ gB,
    const bf16* __restrict__ CVt, bf16* __restrict__ RES)
{
  __shared__ alignas(16) bf16 As[128 * 32];
  __shared__ alignas(16) bf16 Bs[128 * 32];
  const int tid  = threadIdx.x;
  const int wid  = tid >> 6;
  const int lane = tid & 63;
  const int l15  = lane & 15;
  const int quad = lane >> 4;
  const int z = blockIdx.z, b = z >> 3, h = z & 7;
  const bf16* A  = (z < 32) ? (gA + (long)z * 524288) : (gB + (long)(z - 32) * 524288);
  const bf16* Bt = CVt + (long)z * 65536;
  const int bm = blockIdx.x * 128;
  const int wm = (wid & 1) * 64, wn = (wid >> 1) * 64;

  f32x4 acc[4][4] = {};

  const int srow = tid >> 2;
  const int scol = (tid & 3) * 8;
  const bf16* ag0 = A  + (long)(bm + srow) * 512 + scol;
  const bf16* ag1 = ag0 + (long)64 * 512;
  const bf16* bg0 = Bt + (long)srow * 512 + scol;
  const bf16* bg1 = bg0 + (long)64 * 512;
  bf16* lA0 = As + wid * 512;
  bf16* lA1 = As + 2048 + wid * 512;
  bf16* lB0 = Bs + wid * 512;
  bf16* lB1 = Bs + 2048 + wid * 512;

  for (int k0 = 0; k0 < 512; k0 += 32) {
    gll16(ag0 + k0, lA0);
    gll16(ag1 + k0, lA1);
    gll16(bg0 + k0, lB0);
    gll16(bg1 + k0, lB1);
    __syncthreads();
    bf16x8 af[4], bfr[4];
#pragma unroll
    for (int i = 0; i < 4; ++i)
      af[i] = *(const bf16x8*)(As + (wm + i * 16 + l15) * 32 + quad * 8);
#pragma unroll
    for (int i = 0; i < 4; ++i)
      bfr[i] = *(const bf16x8*)(Bs + (wn + i * 16 + l15) * 32 + quad * 8);
#pragma unroll
    for (int mt = 0; mt < 4; ++mt)
#pragma unroll
      for (int nt = 0; nt < 4; ++nt)
        acc[mt][nt] = mfma16(af[mt], bfr[nt], acc[mt][nt]);
    __syncthreads();
  }

#pragma unroll
  for (int nt = 0; nt < 4; ++nt) {
    const int col = h * 128 + wn + nt * 16 + l15;
#pragma unroll
    for (int mt = 0; mt < 4; ++mt) {
      const int row0 = bm + wm + mt * 16 + quad * 4;
#pragma unroll
      for (int r = 0; r < 4; ++r)
        RES[((long)(b * 1024 + row0 + r)) * 1024 + col] = (bf16)acc[mt][nt][r];
    }
  }
}

// ---------------------------------------------------------------------------
// Batched transpose through LDS: T in {float,bf16} -> bf16 out.
// ---------------------------------------------------------------------------
template <typename T>
__global__ __launch_bounds__(256) void transpose_k(
    const T* __restrict__ in, bf16* __restrict__ out,
    int sIR, int sOR, long inStrideB, long inStrideH, long outStrideZ, int H)
{
  __shared__ bf16 t[32][33];
  const int z = blockIdx.z;
  const T* ib = in + (long)(z / H) * inStrideB + (long)(z % H) * inStrideH;
  bf16* ob = out + (long)z * outStrideZ;
  const int r0 = blockIdx.x * 32, c0 = blockIdx.y * 32;
  const int tx = threadIdx.x & 31, ty = threadIdx.x >> 5;
#pragma unroll
  for (int i = 0; i < 32; i += 8)
    t[ty + i][tx] = (bf16)(float)ib[(long)(r0 + ty + i) * sIR + (c0 + tx)];
  __syncthreads();
#pragma unroll
  for (int i = 0; i < 32; i += 8)
    ob[(long)(c0 + ty + i) * sOR + (r0 + tx)] = t[tx][ty + i];
}

// ---------------------------------------------------------------------------
// transpose_w7: z-batched 1024x1024 fp32->bf16 transposes of the 7 square
// weight matrices, one launch (grid 32x32x7).
// ---------------------------------------------------------------------------
struct TP7 { const float* in[7]; bf16* out[7]; };

__global__ __launch_bounds__(256) void transpose_w7(TP7 p)
{
  __shared__ bf16 t[32][33];
  const int z = blockIdx.z;
  const float* ib = p.in[z];
  bf16* ob = p.out[z];
  const int r0 = blockIdx.x * 32, c0 = blockIdx.y * 32;
  const int tx = threadIdx.x & 31, ty = threadIdx.x >> 5;
#pragma unroll
  for (int i = 0; i < 32; i += 8)
    t[ty + i][tx] = (bf16)ib[(long)(r0 + ty + i) * 1024 + (c0 + tx)];
  __syncthreads();
#pragma unroll
  for (int i = 0; i < 32; i += 8)
    ob[(long)(c0 + ty + i) * 1024 + (r0 + tx)] = t[tx][ty + i];
}

// ---------------------------------------------------------------------------
// LayerNorm over D=1024, 1 wave/row, 4 rows/block. TI in {float,bf16}.
// Optional second input: out = LN(X;G1,B1)+LN(X2;G2,B2). bf16 out.
// ---------------------------------------------------------------------------
__device__ __forceinline__ void load16v(float* d, const bf16* p) {
  bf16x8 a = *(const bf16x8*)p, b2 = *(const bf16x8*)(p + 8);
#pragma unroll
  for (int j = 0; j < 8; ++j) { d[j] = (float)a[j]; d[j + 8] = (float)b2[j]; }
}
__device__ __forceinline__ void load16v(float* d, const float* p) {
#pragma unroll
  for (int j = 0; j < 4; ++j) {
    float4 v = ((const float4*)p)[j];
    d[4*j] = v.x; d[4*j+1] = v.y; d[4*j+2] = v.z; d[4*j+3] = v.w;
  }
}

template <typename TI>
__global__ __launch_bounds__(256) void ln_k(
    const TI* __restrict__ X,  const float* __restrict__ G1, const float* __restrict__ B1,
    const TI* __restrict__ X2, const float* __restrict__ G2, const float* __restrict__ B2,
    bf16* __restrict__ out)
{
  const int tid  = threadIdx.x;
  const int wid  = tid >> 6;
  const int lane = tid & 63;
  const long row = (long)blockIdx.x * 4 + wid;
  const int c0 = lane * 16;
  const long base = row * 1024 + c0;

  float a[16], b[16] = {};
  load16v(a, X + base);
  float s = 0.f, ss = 0.f;
#pragma unroll
  for (int j = 0; j < 16; ++j) { s += a[j]; ss += a[j] * a[j]; }
  const bool two = (X2 != nullptr);
  float s2 = 0.f, ss2 = 0.f;
  if (two) {
    load16v(b, X2 + base);
#pragma unroll
    for (int j = 0; j < 16; ++j) { s2 += b[j]; ss2 += b[j] * b[j]; }
  }
#pragma unroll
  for (int off = 32; off; off >>= 1) { s += __shfl_xor(s, off); ss += __shfl_xor(ss, off); }
  if (two) {
#pragma unroll
    for (int off = 32; off; off >>= 1) { s2 += __shfl_xor(s2, off); ss2 += __shfl_xor(ss2, off); }
  }
  const float inv = 1.f / 1024.f;
  const float m1 = s * inv;
  const float r1 = rsqrtf(fmaxf(ss * inv - m1 * m1, 0.f) + 1e-5f);
  float m2 = 0.f, r2 = 0.f;
  if (two) { m2 = s2 * inv; r2 = rsqrtf(fmaxf(ss2 * inv - m2 * m2, 0.f) + 1e-5f); }

  bf16x8 o0, o1;
#pragma unroll
  for (int j = 0; j < 16; ++j) {
    float v = (a[j] - m1) * r1 * G1[c0 + j] + B1[c0 + j];
    if (two) v += (b[j] - m2) * r2 * G2[c0 + j] + B2[c0 + j];
    if (j < 8) o0[j] = (bf16)v; else o1[j - 8] = (bf16)v;
  }
  *(bf16x8*)(out + base) = o0;
  *(bf16x8*)(out + base + 8) = o1;
}

// ---------------------------------------------------------------------------
extern "C" void kernel_launch(void* const* d_in, const int* in_sizes, int n_in,
                              void* d_out, int out_size, void* d_ws, size_t ws_size,
                              hipStream_t stream) {
  (void)in_sizes; (void)n_in; (void)out_size; (void)ws_size;

  const float* x   = (const float*)d_in[0];
  const float* y   = (const float*)d_in[1];
  const float* r1g = (const float*)d_in[3];  const float* r1b = (const float*)d_in[4];
  const float* sa_wq = (const float*)d_in[5];  const float* sa_bq = (const float*)d_in[6];
  const float* sa_wk = (const float*)d_in[7];  const float* sa_bk = (const float*)d_in[8];
  const float* sa_wv = (const float*)d_in[9];  const float* sa_bv = (const float*)d_in[10];
  const float* sa_wo = (const float*)d_in[11]; const float* sa_bo = (const float*)d_in[12];
  const float* tn_g = (const float*)d_in[13];  const float* tn_b = (const float*)d_in[14];
  const float* an_g = (const float*)d_in[15];  const float* an_b = (const float*)d_in[16];
  const float* ca_wq = (const float*)d_in[17]; const float* ca_bq = (const float*)d_in[18];
  const float* ca_wk = (const float*)d_in[19]; const float* ca_bk = (const float*)d_in[20];
  const float* ca_wv = (const float*)d_in[21];
  const float* ca_bv = (const float*)d_in[22];
  const float* n1g = (const float*)d_in[23];   const float* n1b = (const float*)d_in[24];
  const float* n2g = (const float*)d_in[25];   const float* n2b = (const float*)d_in[26];
  const float* r2g = (const float*)d_in[27];   const float* r2b = (const float*)d_in[28];
  const float* fw1 = (const float*)d_in[29];   const float* fb1 = (const float*)d_in[30];
  const float* fw2 = (const float*)d_in[31];   const float* fb2 = (const float*)d_in[32];

  // ---- static 150MB lifetime-planned workspace ----
  char* wsb = (char*)d_ws;
  const size_t MBy = 1048576;
  bf16* fw1T = (bf16*)(wsb + 0 * MBy);
  bf16* fw2T = (bf16*)(wsb + 4 * MBy);
  bf16* wqT  = (bf16*)(wsb + 8 * MBy);    // wq|wk|wv contiguous (3x2MB)
  bf16* wkT  = (bf16*)(wsb + 10 * MBy);
  bf16* wvT  = (bf16*)(wsb + 12 * MBy);
  bf16* woT  = (bf16*)(wsb + 14 * MBy);
  bf16* cwqT = (bf16*)(wsb + 16 * MBy);
  bf16* cwkT = (bf16*)(wsb + 18 * MBy);   // cwk|cwv contiguous (2x2MB)
  bf16* cwvT = (bf16*)(wsb + 20 * MBy);
  bf16* h_bf = (bf16*)(wsb + 22 * MBy);
  bf16* t_bf = h_bf;  bf16* h2_bf = h_bf;
  bf16* q_bf = (bf16*)(wsb + 38 * MBy);
  bf16* av_bf = q_bf;
  bf16* gA = (bf16*)(wsb + 22 * MBy);           // z 0..31 (h/t/q/av dead)
  bf16* k_bf = (bf16*)(wsb + 54 * MBy);
  bf16* cq_bf = k_bf;  bf16* res_b = k_bf;
  bf16* v_bf = (bf16*)(wsb + 70 * MBy);
  bf16* ck_bf = v_bf;
  bf16* cv_bf = (bf16*)(wsb + 78 * MBy);
  bf16* x2_b  = v_bf;
  bf16* vT  = (bf16*)(wsb + 86 * MBy);
  bf16* cvT = vT;
  bf16* o_bf = (bf16*)(wsb + 102 * MBy);
  bf16* x1_b = o_bf;
  bf16* gB  = (bf16*)(wsb + 118 * MBy);          // z 32..63
  bf16* ffh = gB;

  float* out_x    = (float*)d_out;
  float* out_attn = out_x + 8 * 1024 * 1024;

  const dim3 blk(256);

  TP7 tp;
  tp.in[0] = sa_wq; tp.out[0] = wqT;
  tp.in[1] = sa_wk; tp.out[1] = wkT;
  tp.in[2] = sa_wv; tp.out[2] = wvT;
  tp.in[3] = sa_wo; tp.out[3] = woT;
  tp.in[4] = ca_wq; tp.out[4] = cwqT;
  tp.in[5] = ca_wk; tp.out[5] = cwkT;
  tp.in[6] = ca_wv; tp.out[6] = cwvT;
  transpose_w7<<<dim3(32, 32, 7), blk, 0, stream>>>(tp);
  transpose_k<float><<<dim3(32, 64, 1), blk, 0, stream>>>(fw1, fw1T, 2048, 1024, 0, 0, 0, 1);
  transpose_k<float><<<dim3(64, 32, 1), blk, 0, stream>>>(fw2, fw2T, 1024, 2048, 0, 0, 0, 1);

  ln_k<float><<<dim3(2048), blk, 0, stream>>>(x, r1g, r1b, nullptr, nullptr, nullptr, h_bf);

  // fused QKV projection: packed weights wqT|wkT|wvT, split outputs
  Out3 oqkv = { q_bf, k_bf, v_bf, sa_bq, sa_bk, sa_bv };
  gemm_bt_split<<<dim3(24, 64), blk, 0, stream>>>(h_bf, wqT, oqkv, 8192, 3072, 1024);

  transpose_k<bf16><<<dim3(32, 4, 64), blk, 0, stream>>>(v_bf, vT, 1024, 1024,
      (long)1024 * 1024, 128, (long)128 * 1024, 8);

  attn_self<<<dim3(16, 64), blk, 0, stream>>>(q_bf, k_bf, vT, o_bf);

  gemm_bt<<<dim3(8, 64), blk, 0, stream>>>(o_bf, woT, sa_bo, nullptr, x, x1_b, nullptr, 8192, 1024, 1024, 0);

  ln_k<bf16><<<dim3(2048), blk, 0, stream>>>(x1_b, tn_g, tn_b, nullptr, nullptr, nullptr, t_bf);
  ln_k<float><<<dim3(1024), blk, 0, stream>>>(y, an_g, an_b, nullptr, nullptr, nullptr, av_bf);

  gemm_bt<<<dim3(8, 64), blk, 0, stream>>>(t_bf, cwqT, ca_bq, nullptr, nullptr, cq_bf, nullptr, 8192, 1024, 1024, 0);

  // fused CK/CV projection: packed weights cwkT|cwvT, split outputs
  Out3 ockv = { ck_bf, cv_bf, nullptr, ca_bk, ca_bv, nullptr };
  gemm_bt_split<<<dim3(16, 32), blk, 0, stream>>>(av_bf, cwkT, ockv, 4096, 2048, 1024);

  transpose_k<bf16><<<dim3(16, 4, 64), blk, 0, stream>>>(cv_bf, cvT, 1024, 512,
      (long)512 * 1024, 128, (long)128 * 512, 8);

  // gate (per-head blocks) -> G; then attn_out mean; then res GEMM
  gate2<<<dim3(32, 64), blk, 0, stream>>>(cq_bf, ck_bf, gA, gB);
  reduce_h<<<dim3(4096), blk, 0, stream>>>(gA, gB, out_attn);
  gemm_res<<<dim3(8, 1, 64), blk, 0, stream>>>(gA, gB, cvT, res_b);

  ln_k<bf16><<<dim3(2048), blk, 0, stream>>>(x1_b, n1g, n1b, res_b, n2g, n2b, x2_b);
  ln_k<bf16><<<dim3(2048), blk, 0, stream>>>(x2_b, r2g, r2b, nullptr, nullptr, nullptr, h2_bf);

  gemm_bt<<<dim3(16, 64), blk, 0, stream>>>(h2_bf, fw1T, fb1, nullptr, nullptr, ffh, nullptr, 8192, 2048, 1024, 1);
  gemm_bt<<<dim3(8, 64), blk, 0, stream>>>(ffh, fw2T, fb2, x2_b, nullptr, nullptr, out_x, 8192, 1024, 2048, 0);
}

// Round 5
// 716.642 us; speedup vs baseline: 1.3518x; 1.2420x over previous
//
#include <hip/hip_runtime.h>

// ---------------------------------------------------------------------------
// CrossDecoderLayer on MI355X (gfx950). External I/O fp32; internal bf16
// MFMA, fp32 accumulate. B=8, W=1024, V=512, D=1024, H=8, DK=128.
// R7 : XOR-swizzle on attn_self Ks/Vs/Ps and gate2 Ks/Pt (conflicts 15M->4M).
// R9 : FAILED (reg-prefetch spilled: WRITE_SIZE 16->54MB). Reverted.
// R10: launch fusion (30->21 dispatches): -78us. ~8us/dispatch overhead.
// R11: attn_self 512-thr / 128-q-row blocks (halves staging+barriers per
//      MFMA; P-scratch halved via 2-half PV so LDS stays 80KB = 2 blk/CU);
//      more fusion: 9-mat transpose batch, ln_pair, ln_fuse2 (16 dispatches).
// ---------------------------------------------------------------------------

typedef __bf16 bf16;
typedef bf16  bf16x4 __attribute__((ext_vector_type(4)));
typedef bf16  bf16x8 __attribute__((ext_vector_type(8)));
typedef float f32x4  __attribute__((ext_vector_type(4)));

#define SCALE 0.08838834764831845f  // 1/sqrt(128)

__device__ __forceinline__ f32x4 mfma16(bf16x8 a, bf16x8 b, f32x4 c) {
  return __builtin_amdgcn_mfma_f32_16x16x32_bf16(a, b, c, 0, 0, 0);
}

__device__ __forceinline__ void gll16(const bf16* g, bf16* l) {
  __builtin_amdgcn_global_load_lds(
      (__attribute__((address_space(1))) void*)(void*)g,
      (__attribute__((address_space(3))) void*)(void*)l, 16, 0, 0);
}

// ---------------------------------------------------------------------------
// GEMM: C = epi(A[M,K] @ Bt[N,K]^T + bias [+residF]), 128x128 tile, BK=32,
// 4 waves x (64x64), global_load_lds staging (m97 structure).
// ---------------------------------------------------------------------------
__global__ __launch_bounds__(256) void gemm_bt(
    const bf16* __restrict__ A, const bf16* __restrict__ Bt,
    const float* __restrict__ bias,
    const bf16* __restrict__ residB, const float* __restrict__ residF,
    bf16* __restrict__ Cb, float* __restrict__ Cf,
    int M, int N, int K, int relu)
{
  __shared__ alignas(16) bf16 As[128 * 32];
  __shared__ alignas(16) bf16 Bs[128 * 32];
  const int tid  = threadIdx.x;
  const int wid  = tid >> 6;
  const int lane = tid & 63;
  const int l15  = lane & 15;
  const int quad = lane >> 4;
  const int bm = blockIdx.y * 128, bn = blockIdx.x * 128;
  const int wm = (wid & 1) * 64,  wn = (wid >> 1) * 64;

  f32x4 acc[4][4] = {};

  const int srow = tid >> 2;
  const int scol = (tid & 3) * 8;
  const bf16* ag0 = A  + (long)(bm + srow) * K + scol;
  const bf16* ag1 = ag0 + (long)64 * K;
  const bf16* bg0 = Bt + (long)(bn + srow) * K + scol;
  const bf16* bg1 = bg0 + (long)64 * K;
  bf16* lA0 = As + wid * 512;
  bf16* lA1 = As + 2048 + wid * 512;
  bf16* lB0 = Bs + wid * 512;
  bf16* lB1 = Bs + 2048 + wid * 512;

  for (int k0 = 0; k0 < K; k0 += 32) {
    gll16(ag0 + k0, lA0);
    gll16(ag1 + k0, lA1);
    gll16(bg0 + k0, lB0);
    gll16(bg1 + k0, lB1);
    __syncthreads();
    bf16x8 af[4], bfr[4];
#pragma unroll
    for (int i = 0; i < 4; ++i)
      af[i] = *(const bf16x8*)(As + (wm + i * 16 + l15) * 32 + quad * 8);
#pragma unroll
    for (int i = 0; i < 4; ++i)
      bfr[i] = *(const bf16x8*)(Bs + (wn + i * 16 + l15) * 32 + quad * 8);
#pragma unroll
    for (int mt = 0; mt < 4; ++mt)
#pragma unroll
      for (int nt = 0; nt < 4; ++nt)
        acc[mt][nt] = mfma16(af[mt], bfr[nt], acc[mt][nt]);
    __syncthreads();
  }

#pragma unroll
  for (int nt = 0; nt < 4; ++nt) {
    const int col = bn + wn + nt * 16 + l15;
    const float bv = bias ? bias[col] : 0.f;
#pragma unroll
    for (int mt = 0; mt < 4; ++mt) {
      const int row0 = bm + wm + mt * 16 + quad * 4;
#pragma unroll
      for (int r = 0; r < 4; ++r) {
        const long idx = (long)(row0 + r) * N + col;
        float v = acc[mt][nt][r] + bv;
        if (relu) v = fmaxf(v, 0.f);
        if (residB) v += (float)residB[idx];
        if (residF) v += residF[idx];
        if (Cb) Cb[idx] = (bf16)v;
        if (Cf) Cf[idx] = v;
      }
    }
  }
}

// ---------------------------------------------------------------------------
// gemm_bt_split: same m97 GEMM over a packed Bt of Ntot columns, but the
// epilogue splits output into per-1024-column buffers (each [M][1024]).
// ---------------------------------------------------------------------------
struct Out3 {
  bf16* o0; bf16* o1; bf16* o2;
  const float* b0; const float* b1; const float* b2;
};

__global__ __launch_bounds__(256) void gemm_bt_split(
    const bf16* __restrict__ A, const bf16* __restrict__ Bt,
    Out3 so, int M, int Ntot, int K)
{
  __shared__ alignas(16) bf16 As[128 * 32];
  __shared__ alignas(16) bf16 Bs[128 * 32];
  const int tid  = threadIdx.x;
  const int wid  = tid >> 6;
  const int lane = tid & 63;
  const int l15  = lane & 15;
  const int quad = lane >> 4;
  const int bm = blockIdx.y * 128, bn = blockIdx.x * 128;
  const int wm = (wid & 1) * 64,  wn = (wid >> 1) * 64;

  const int ch = bn >> 10;
  bf16* C = (ch == 0) ? so.o0 : (ch == 1 ? so.o1 : so.o2);
  const float* bp = (ch == 0) ? so.b0 : (ch == 1 ? so.b1 : so.b2);

  f32x4 acc[4][4] = {};

  const int srow = tid >> 2;
  const int scol = (tid & 3) * 8;
  const bf16* ag0 = A  + (long)(bm + srow) * K + scol;
  const bf16* ag1 = ag0 + (long)64 * K;
  const bf16* bg0 = Bt + (long)(bn + srow) * K + scol;
  const bf16* bg1 = bg0 + (long)64 * K;
  bf16* lA0 = As + wid * 512;
  bf16* lA1 = As + 2048 + wid * 512;
  bf16* lB0 = Bs + wid * 512;
  bf16* lB1 = Bs + 2048 + wid * 512;

  for (int k0 = 0; k0 < K; k0 += 32) {
    gll16(ag0 + k0, lA0);
    gll16(ag1 + k0, lA1);
    gll16(bg0 + k0, lB0);
    gll16(bg1 + k0, lB1);
    __syncthreads();
    bf16x8 af[4], bfr[4];
#pragma unroll
    for (int i = 0; i < 4; ++i)
      af[i] = *(const bf16x8*)(As + (wm + i * 16 + l15) * 32 + quad * 8);
#pragma unroll
    for (int i = 0; i < 4; ++i)
      bfr[i] = *(const bf16x8*)(Bs + (wn + i * 16 + l15) * 32 + quad * 8);
#pragma unroll
    for (int mt = 0; mt < 4; ++mt)
#pragma unroll
      for (int nt = 0; nt < 4; ++nt)
        acc[mt][nt] = mfma16(af[mt], bfr[nt], acc[mt][nt]);
    __syncthreads();
  }

#pragma unroll
  for (int nt = 0; nt < 4; ++nt) {
    const int col = bn + wn + nt * 16 + l15;
    const int cc  = col & 1023;
    const float bv = bp[cc];
#pragma unroll
    for (int mt = 0; mt < 4; ++mt) {
      const int row0 = bm + wm + mt * 16 + quad * 4;
#pragma unroll
      for (int r = 0; r < 4; ++r)
        C[(long)(row0 + r) * 1024 + cc] = (bf16)(acc[mt][nt][r] + bv);
    }
  }
  (void)M; (void)Ntot;
}

// ---------------------------------------------------------------------------
// Flash-style self-attention. R11: 512 threads, 128 q-rows/block (8 waves x
// 16 rows). Same per-wave math as R7; K/V staged once per 2x the MFMA.
// P-scratch is 2 chunks/wave, reused across the two PV halves (same-wave DS
// ops are in-order, so the WAR on the chunk is safe). LDS = 32+32+16 = 80KB
// -> 2 blocks/CU; launch_bounds(512,4) pins VGPR<=128 for 4 waves/SIMD.
// ---------------------------------------------------------------------------
__global__ __launch_bounds__(512, 4) void attn_self(
    const bf16* __restrict__ Q, const bf16* __restrict__ Km,
    const bf16* __restrict__ Vt, bf16* __restrict__ O)
{
  __shared__ alignas(16) bf16 Ks[16384];
  __shared__ alignas(16) bf16 Vs[16384];
  __shared__ alignas(16) bf16 Ps[8192];      // 8 waves x (2 chunks x 512)
  const int tid  = threadIdx.x;
  const int wid  = tid >> 6;                  // 0..7
  const int lane = tid & 63;
  const int l15  = lane & 15;
  const int quad = lane >> 4;
  const int b = blockIdx.y >> 3, h = blockIdx.y & 7;
  const int q0 = blockIdx.x * 128;

  // swizzled read offset within a [rows][32] chunk: row=l15, slot=quad^((l15>>1)&3)
  const int rdoff = l15 * 32 + (((quad ^ ((l15 >> 1) & 3))) << 3);

  const long qb = ((long)(b * 1024 + q0 + wid * 16 + l15)) * 1024 + h * 128 + quad * 8;
  bf16x8 qf[4];
#pragma unroll
  for (int ks = 0; ks < 4; ++ks) qf[ks] = *(const bf16x8*)(Q + qb + ks * 32);

  f32x4 oacc[8] = {};
  float mrow[4], lrow[4];
#pragma unroll
  for (int r = 0; r < 4; ++r) { mrow[r] = -3.0e38f; lrow[r] = 0.f; }

  const long kbase = (long)(b * 1024) * 1024 + h * 128;
  const long vbase = (long)(b * 8 + h) * 128 * 1024;

  const int srow = tid >> 3;        // 0..63
  const int sc8  = (tid & 7) * 8;

  bf16* pw = Ps + wid * 1024;

  for (int t = 0; t < 8; ++t) {
    const int kv0 = t * 128;
    __syncthreads();
#pragma unroll
    for (int dh = 0; dh < 2; ++dh)
#pragma unroll
      for (int kq = 0; kq < 2; ++kq) {
        const int kv = kq * 64 + srow;
        const int d  = dh * 64 + sc8;
        bf16x8 v = *(const bf16x8*)(Km + kbase + (long)(kv0 + kv) * 1024 + d);
        *(bf16x8*)(Ks + (d >> 5) * 4096 + kv * 32 +
                   (((((d & 31) >> 3) ^ ((kv >> 1) & 3))) << 3)) = v;
      }
#pragma unroll
    for (int kh = 0; kh < 2; ++kh)
#pragma unroll
      for (int dq = 0; dq < 2; ++dq) {
        const int d  = dq * 64 + srow;
        const int kv = kh * 64 + sc8;
        bf16x8 v = *(const bf16x8*)(Vt + vbase + (long)d * 1024 + kv0 + kv);
        *(bf16x8*)(Vs + (kv >> 5) * 4096 + d * 32 +
                   (((((kv & 31) >> 3) ^ ((d >> 1) & 3))) << 3)) = v;
      }
    __syncthreads();

    f32x4 sacc[8] = {};
#pragma unroll
    for (int nt = 0; nt < 8; ++nt)
#pragma unroll
      for (int ks = 0; ks < 4; ++ks)
        sacc[nt] = mfma16(qf[ks],
            *(const bf16x8*)(Ks + ks * 4096 + nt * 512 + rdoff),
            sacc[nt]);

    float tm[4];
#pragma unroll
    for (int r = 0; r < 4; ++r) {
      float m = -3.0e38f;
#pragma unroll
      for (int nt = 0; nt < 8; ++nt) m = fmaxf(m, sacc[nt][r]);
      tm[r] = m * SCALE;
    }
#pragma unroll
    for (int off = 8; off; off >>= 1)
#pragma unroll
      for (int r = 0; r < 4; ++r) tm[r] = fmaxf(tm[r], __shfl_xor(tm[r], off));
    float alpha[4], psum[4];
#pragma unroll
    for (int r = 0; r < 4; ++r) {
      const float mnew = fmaxf(mrow[r], tm[r]);
      alpha[r] = __expf(mrow[r] - mnew);
      mrow[r] = mnew;
      psum[r] = 0.f;
    }
#pragma unroll
    for (int nt = 0; nt < 8; ++nt)
#pragma unroll
      for (int r = 0; r < 4; ++r) oacc[nt][r] *= alpha[r];

    // two PV halves, reusing the 2-chunk per-wave P buffer
#pragma unroll
    for (int hs = 0; hs < 2; ++hs) {
#pragma unroll
      for (int n2 = 0; n2 < 4; ++n2) {
        const int nt = hs * 4 + n2;
#pragma unroll
        for (int r = 0; r < 4; ++r) {
          const float p = __expf(sacc[nt][r] * SCALE - mrow[r]);
          psum[r] += p;
          const int prow = quad * 4 + r;
          pw[((nt >> 1) & 1) * 512 + prow * 32 +
             (((((nt & 1) * 2 + (l15 >> 3)) ^ ((prow >> 1) & 3))) << 3) + (l15 & 7)] =
              (bf16)p;
        }
      }
#pragma unroll
      for (int ks2 = 0; ks2 < 2; ++ks2) {
        const bf16x8 pa = *(const bf16x8*)(pw + ks2 * 512 + rdoff);
        const int ksx = hs * 2 + ks2;
#pragma unroll
        for (int nt = 0; nt < 8; ++nt)
          oacc[nt] = mfma16(pa,
              *(const bf16x8*)(Vs + ksx * 4096 + nt * 512 + rdoff),
              oacc[nt]);
      }
    }

#pragma unroll
    for (int off = 8; off; off >>= 1)
#pragma unroll
      for (int r = 0; r < 4; ++r) psum[r] += __shfl_xor(psum[r], off);
#pragma unroll
    for (int r = 0; r < 4; ++r) lrow[r] = lrow[r] * alpha[r] + psum[r];
  }

  float linv[4];
#pragma unroll
  for (int r = 0; r < 4; ++r) linv[r] = 1.f / lrow[r];
#pragma unroll
  for (int nt = 0; nt < 8; ++nt)
#pragma unroll
    for (int r = 0; r < 4; ++r) {
      const int row = q0 + wid * 16 + quad * 4 + r;
      O[((long)(b * 1024 + row)) * 1024 + h * 128 + nt * 16 + l15] =
          (bf16)(oacc[nt][r] * linv[r]);
    }
}

// ---------------------------------------------------------------------------
// gate2: G[z=(b,h)][w][v] = sigmoid(SCALE * CQ.CK^T). Grid (32 wtiles, 64 z).
// ---------------------------------------------------------------------------
__global__ __launch_bounds__(256) void gate2(
    const bf16* __restrict__ CQ, const bf16* __restrict__ CK,
    bf16* __restrict__ gA, bf16* __restrict__ gB)
{
  __shared__ alignas(16) bf16 Ks[16384];      // 4 dchunks x 128 v x 32 d
  __shared__ alignas(16) bf16 Pt[4][1024];    // per-wave 16w x 64v transpose
  const int tid  = threadIdx.x;
  const int wid  = tid >> 6;
  const int lane = tid & 63;
  const int l15  = lane & 15;
  const int quad = lane >> 4;
  const int z = blockIdx.y, b = z >> 3, h = z & 7;
  const int w0 = blockIdx.x * 32;
  const int rsel = wid & 1, vsel = wid >> 1;

  const int rdoff = l15 * 32 + (((quad ^ ((l15 >> 1) & 3))) << 3);

  bf16* Gz = (z < 32) ? (gA + (long)z * 524288) : (gB + (long)(z - 32) * 524288);

  const long qb = ((long)(b * 1024 + w0 + rsel * 16 + l15)) * 1024 + h * 128 + quad * 8;
  bf16x8 qf[4];
#pragma unroll
  for (int ks = 0; ks < 4; ++ks) qf[ks] = *(const bf16x8*)(CQ + qb + ks * 32);

  const int srow = tid >> 3;        // 0..31
  const int sc8  = (tid & 7) * 8;   // 0..56

  for (int vt = 0; vt < 4; ++vt) {
    const int v0 = vt * 128;
    __syncthreads();
#pragma unroll
    for (int i = 0; i < 4; ++i) {
      const int v = i * 32 + srow;
#pragma unroll
      for (int dh = 0; dh < 2; ++dh) {
        const int d = dh * 64 + sc8;
        bf16x8 val = *(const bf16x8*)(CK + ((long)(b * 512 + v0 + v)) * 1024 + h * 128 + d);
        *(bf16x8*)(Ks + (d >> 5) * 4096 + v * 32 +
                   (((((d & 31) >> 3) ^ ((v >> 1) & 3))) << 3)) = val;
      }
    }
    __syncthreads();

    f32x4 sacc[4] = {};
#pragma unroll
    for (int nt = 0; nt < 4; ++nt)
#pragma unroll
      for (int ks = 0; ks < 4; ++ks)
        sacc[nt] = mfma16(qf[ks],
            *(const bf16x8*)(Ks + ks * 4096 + vsel * 2048 + nt * 512 + rdoff),
            sacc[nt]);

#pragma unroll
    for (int nt = 0; nt < 4; ++nt)
#pragma unroll
      for (int r = 0; r < 4; ++r) {
        const float g = 1.f / (1.f + __expf(-sacc[nt][r] * SCALE));
        const int prow = quad * 4 + r;
        const int g0 = nt * 2 + (l15 >> 3);
        Pt[wid][prow * 64 + ((g0 ^ ((prow >> 1) & 3)) << 3) + (l15 & 7)] = (bf16)g;
      }
#pragma unroll
    for (int pass = 0; pass < 2; ++pass) {
      const int f = pass * 512 + lane * 8;
      const int row = f >> 6, col = f & 63;
      const int gl = (lane & 7) ^ ((row >> 1) & 3);
      bf16x8 vv = *(const bf16x8*)(&Pt[wid][row * 64 + gl * 8]);
      *(bf16x8*)(Gz + (long)(w0 + rsel * 16 + row) * 512 + v0 + vsel * 64 + col) = vv;
    }
  }
}

// ---------------------------------------------------------------------------
// reduce_h: attn_out[b,w,v] = mean over 8 heads of G. Fully coalesced.
// ---------------------------------------------------------------------------
__global__ __launch_bounds__(256) void reduce_h(
    const bf16* __restrict__ gA, const bf16* __restrict__ gB,
    float* __restrict__ AOUT)
{
  const int idx = blockIdx.x * 256 + threadIdx.x;  // 1,048,576 total
  const int v4 = idx & 127;
  const int w  = (idx >> 7) & 1023;
  const int b  = idx >> 17;
  float s0 = 0.f, s1 = 0.f, s2 = 0.f, s3 = 0.f;
#pragma unroll
  for (int h = 0; h < 8; ++h) {
    const int z = b * 8 + h;
    const bf16* base = (z < 32) ? (gA + (long)z * 524288) : (gB + (long)(z - 32) * 524288);
    bf16x4 g = *(const bf16x4*)(base + (long)w * 512 + v4 * 4);
    s0 += (float)g[0]; s1 += (float)g[1]; s2 += (float)g[2]; s3 += (float)g[3];
  }
  *(float4*)(AOUT + (long)idx * 4) =
      make_float4(s0 * 0.125f, s1 * 0.125f, s2 * 0.125f, s3 * 0.125f);
}

// ---------------------------------------------------------------------------
// gemm_res: res[b,w,h*128+d] = G[z] (1024x512) @ CVt[z] (128x512)^T (m97).
// ---------------------------------------------------------------------------
__global__ __launch_bounds__(256) void gemm_res(
    const bf16* __restrict__ gA, const bf16* __restrict__ gB,
    const bf16* __restrict__ CVt, bf16* __restrict__ RES)
{
  __shared__ alignas(16) bf16 As[128 * 32];
  __shared__ alignas(16) bf16 Bs[128 * 32];
  const int tid  = threadIdx.x;
  const int wid  = tid >> 6;
  const int lane = tid & 63;
  const int l15  = lane & 15;
  const int quad = lane >> 4;
  const int z = blockIdx.z, b = z >> 3, h = z & 7;
  const bf16* A  = (z < 32) ? (gA + (long)z * 524288) : (gB + (long)(z - 32) * 524288);
  const bf16* Bt = CVt + (long)z * 65536;
  const int bm = blockIdx.x * 128;
  const int wm = (wid & 1) * 64, wn = (wid >> 1) * 64;

  f32x4 acc[4][4] = {};

  const int srow = tid >> 2;
  const int scol = (tid & 3) * 8;
  const bf16* ag0 = A  + (long)(bm + srow) * 512 + scol;
  const bf16* ag1 = ag0 + (long)64 * 512;
  const bf16* bg0 = Bt + (long)srow * 512 + scol;
  const bf16* bg1 = bg0 + (long)64 * 512;
  bf16* lA0 = As + wid * 512;
  bf16* lA1 = As + 2048 + wid * 512;
  bf16* lB0 = Bs + wid * 512;
  bf16* lB1 = Bs + 2048 + wid * 512;

  for (int k0 = 0; k0 < 512; k0 += 32) {
    gll16(ag0 + k0, lA0);
    gll16(ag1 + k0, lA1);
    gll16(bg0 + k0, lB0);
    gll16(bg1 + k0, lB1);
    __syncthreads();
    bf16x8 af[4], bfr[4];
#pragma unroll
    for (int i = 0; i < 4; ++i)
      af[i] = *(const bf16x8*)(As + (wm + i * 16 + l15) * 32 + quad * 8);
#pragma unroll
    for (int i = 0; i < 4; ++i)
      bfr[i] = *(const bf16x8*)(Bs + (wn + i * 16 + l15) * 32 + quad * 8);
#pragma unroll
    for (int mt = 0; mt < 4; ++mt)
#pragma unroll
      for (int nt = 0; nt < 4; ++nt)
        acc[mt][nt] = mfma16(af[mt], bfr[nt], acc[mt][nt]);
    __syncthreads();
  }

#pragma unroll
  for (int nt = 0; nt < 4; ++nt) {
    const int col = h * 128 + wn + nt * 16 + l15;
#pragma unroll
    for (int mt = 0; mt < 4; ++mt) {
      const int row0 = bm + wm + mt * 16 + quad * 4;
#pragma unroll
      for (int r = 0; r < 4; ++r)
        RES[((long)(b * 1024 + row0 + r)) * 1024 + col] = (bf16)acc[mt][nt][r];
    }
  }
}

// ---------------------------------------------------------------------------
// Batched transpose through LDS: T in {float,bf16} -> bf16 out.
// ---------------------------------------------------------------------------
template <typename T>
__global__ __launch_bounds__(256) void transpose_k(
    const T* __restrict__ in, bf16* __restrict__ out,
    int sIR, int sOR, long inStrideB, long inStrideH, long outStrideZ, int H)
{
  __shared__ bf16 t[32][33];
  const int z = blockIdx.z;
  const T* ib = in + (long)(z / H) * inStrideB + (long)(z % H) * inStrideH;
  bf16* ob = out + (long)z * outStrideZ;
  const int r0 = blockIdx.x * 32, c0 = blockIdx.y * 32;
  const int tx = threadIdx.x & 31, ty = threadIdx.x >> 5;
#pragma unroll
  for (int i = 0; i < 32; i += 8)
    t[ty + i][tx] = (bf16)(float)ib[(long)(r0 + ty + i) * sIR + (c0 + tx)];
  __syncthreads();
#pragma unroll
  for (int i = 0; i < 32; i += 8)
    ob[(long)(c0 + ty + i) * sOR + (r0 + tx)] = t[tx][ty + i];
}

// ---------------------------------------------------------------------------
// transpose_w9: z-batched fp32->bf16 transposes of all 9 weight matrices in
// one launch. z<7: 1024x1024. z=7: fw1 1024x2048. z=8: fw2 2048x1024.
// Grid (32, 64, 9); square mats early-return for by>=32.
// ---------------------------------------------------------------------------
struct TP9 { const float* in[9]; bf16* out[9]; };

__global__ __launch_bounds__(256) void transpose_w9(TP9 p)
{
  __shared__ bf16 t[32][33];
  const int z = blockIdx.z;
  int r0, c0, sIR, sOR;
  if (z < 7) {
    if (blockIdx.y >= 32) return;
    r0 = blockIdx.x * 32; c0 = blockIdx.y * 32; sIR = 1024; sOR = 1024;
  } else if (z == 7) {            // in 1024x2048 -> out 2048x1024
    r0 = blockIdx.x * 32; c0 = blockIdx.y * 32; sIR = 2048; sOR = 1024;
  } else {                        // in 2048x1024 -> out 1024x2048
    r0 = blockIdx.y * 32; c0 = blockIdx.x * 32; sIR = 1024; sOR = 2048;
  }
  const float* ib = p.in[z];
  bf16* ob = p.out[z];
  const int tx = threadIdx.x & 31, ty = threadIdx.x >> 5;
#pragma unroll
  for (int i = 0; i < 32; i += 8)
    t[ty + i][tx] = (bf16)ib[(long)(r0 + ty + i) * sIR + (c0 + tx)];
  __syncthreads();
#pragma unroll
  for (int i = 0; i < 32; i += 8)
    ob[(long)(c0 + ty + i) * sOR + (r0 + tx)] = t[tx][ty + i];
}

// ---------------------------------------------------------------------------
// LayerNorm over D=1024, 1 wave/row. Shared row body.
// ---------------------------------------------------------------------------
__device__ __forceinline__ void load16v(float* d, const bf16* p) {
  bf16x8 a = *(const bf16x8*)p, b2 = *(const bf16x8*)(p + 8);
#pragma unroll
  for (int j = 0; j < 8; ++j) { d[j] = (float)a[j]; d[j + 8] = (float)b2[j]; }
}
__device__ __forceinline__ void load16v(float* d, const float* p) {
#pragma unroll
  for (int j = 0; j < 4; ++j) {
    float4 v = ((const float4*)p)[j];
    d[4*j] = v.x; d[4*j+1] = v.y; d[4*j+2] = v.z; d[4*j+3] = v.w;
  }
}

template <typename TI>
__device__ __forceinline__ void ln_row_body(
    const TI* __restrict__ X, const float* __restrict__ G,
    const float* __restrict__ Bb, bf16* __restrict__ out, long row, int lane)
{
  const int c0 = lane * 16;
  const long base = row * 1024 + c0;
  float a[16];
  load16v(a, X + base);
  float s = 0.f, ss = 0.f;
#pragma unroll
  for (int j = 0; j < 16; ++j) { s += a[j]; ss += a[j] * a[j]; }
#pragma unroll
  for (int off = 32; off; off >>= 1) { s += __shfl_xor(s, off); ss += __shfl_xor(ss, off); }
  const float inv = 1.f / 1024.f;
  const float m = s * inv;
  const float rr = rsqrtf(fmaxf(ss * inv - m * m, 0.f) + 1e-5f);
  bf16x8 o0, o1;
#pragma unroll
  for (int j = 0; j < 16; ++j) {
    float v = (a[j] - m) * rr * G[c0 + j] + Bb[c0 + j];
    if (j < 8) o0[j] = (bf16)v; else o1[j - 8] = (bf16)v;
  }
  *(bf16x8*)(out + base) = o0;
  *(bf16x8*)(out + base + 8) = o1;
}

template <typename TI>
__global__ __launch_bounds__(256) void ln_k(
    const TI* __restrict__ X, const float* __restrict__ G1,
    const float* __restrict__ B1, bf16* __restrict__ out)
{
  const int wid = threadIdx.x >> 6, lane = threadIdx.x & 63;
  ln_row_body<TI>(X, G1, B1, out, (long)blockIdx.x * 4 + wid, lane);
}

// ln_pair: blocks [0,2048) LN 8192 bf16 rows; [2048,3072) LN 4096 f32 rows.
__global__ __launch_bounds__(256) void ln_pair(
    const bf16* __restrict__ Xa, const float* __restrict__ Ga,
    const float* __restrict__ Ba, bf16* __restrict__ outA,
    const float* __restrict__ Xb, const float* __restrict__ Gb,
    const float* __restrict__ Bb, bf16* __restrict__ outB)
{
  const int wid = threadIdx.x >> 6, lane = threadIdx.x & 63;
  const long row = (long)blockIdx.x * 4 + wid;
  if (blockIdx.x < 2048) ln_row_body<bf16>(Xa, Ga, Ba, outA, row, lane);
  else                   ln_row_body<float>(Xb, Gb, Bb, outB, row - 8192, lane);
}

// ln_fuse2: v = LN(X1;G1,B1)+LN(X2;G2,B2); outX = bf16(v); outH = LN(v;G3,B3).
__global__ __launch_bounds__(256) void ln_fuse2(
    const bf16* __restrict__ X1, const float* __restrict__ G1, const float* __restrict__ B1,
    const bf16* __restrict__ X2, const float* __restrict__ G2, const float* __restrict__ B2,
    const float* __restrict__ G3, const float* __restrict__ B3,
    bf16* __restrict__ outX, bf16* __restrict__ outH)
{
  const int wid = threadIdx.x >> 6, lane = threadIdx.x & 63;
  const long row = (long)blockIdx.x * 4 + wid;
  const int c0 = lane * 16;
  const long base = row * 1024 + c0;

  float a[16], b[16];
  load16v(a, X1 + base);
  load16v(b, X2 + base);
  float s1 = 0.f, ss1 = 0.f, s2 = 0.f, ss2 = 0.f;
#pragma unroll
  for (int j = 0; j < 16; ++j) {
    s1 += a[j]; ss1 += a[j] * a[j];
    s2 += b[j]; ss2 += b[j] * b[j];
  }
#pragma unroll
  for (int off = 32; off; off >>= 1) {
    s1 += __shfl_xor(s1, off); ss1 += __shfl_xor(ss1, off);
    s2 += __shfl_xor(s2, off); ss2 += __shfl_xor(ss2, off);
  }
  const float inv = 1.f / 1024.f;
  const float m1 = s1 * inv;
  const float r1 = rsqrtf(fmaxf(ss1 * inv - m1 * m1, 0.f) + 1e-5f);
  const float m2 = s2 * inv;
  const float r2 = rsqrtf(fmaxf(ss2 * inv - m2 * m2, 0.f) + 1e-5f);

  float v[16];
  float s3 = 0.f, ss3 = 0.f;
  bf16x8 o0, o1;
#pragma unroll
  for (int j = 0; j < 16; ++j) {
    v[j] = (a[j] - m1) * r1 * G1[c0 + j] + B1[c0 + j]
         + (b[j] - m2) * r2 * G2[c0 + j] + B2[c0 + j];
    s3 += v[j]; ss3 += v[j] * v[j];
    if (j < 8) o0[j] = (bf16)v[j]; else o1[j - 8] = (bf16)v[j];
  }
  *(bf16x8*)(outX + base) = o0;
  *(bf16x8*)(outX + base + 8) = o1;
#pragma unroll
  for (int off = 32; off; off >>= 1) {
    s3 += __shfl_xor(s3, off); ss3 += __shfl_xor(ss3, off);
  }
  const float m3 = s3 * inv;
  const float r3 = rsqrtf(fmaxf(ss3 * inv - m3 * m3, 0.f) + 1e-5f);
#pragma unroll
  for (int j = 0; j < 16; ++j) {
    float hh = (v[j] - m3) * r3 * G3[c0 + j] + B3[c0 + j];
    if (j < 8) o0[j] = (bf16)hh; else o1[j - 8] = (bf16)hh;
  }
  *(bf16x8*)(outH + base) = o0;
  *(bf16x8*)(outH + base + 8) = o1;
}

// ---------------------------------------------------------------------------
extern "C" void kernel_launch(void* const* d_in, const int* in_sizes, int n_in,
                              void* d_out, int out_size, void* d_ws, size_t ws_size,
                              hipStream_t stream) {
  (void)in_sizes; (void)n_in; (void)out_size; (void)ws_size;

  const float* x   = (const float*)d_in[0];
  const float* y   = (const float*)d_in[1];
  const float* r1g = (const float*)d_in[3];  const float* r1b = (const float*)d_in[4];
  const float* sa_wq = (const float*)d_in[5];  const float* sa_bq = (const float*)d_in[6];
  const float* sa_wk = (const float*)d_in[7];  const float* sa_bk = (const float*)d_in[8];
  const float* sa_wv = (const float*)d_in[9];  const float* sa_bv = (const float*)d_in[10];
  const float* sa_wo = (const float*)d_in[11]; const float* sa_bo = (const float*)d_in[12];
  const float* tn_g = (const float*)d_in[13];  const float* tn_b = (const float*)d_in[14];
  const float* an_g = (const float*)d_in[15];  const float* an_b = (const float*)d_in[16];
  const float* ca_wq = (const float*)d_in[17]; const float* ca_bq = (const float*)d_in[18];
  const float* ca_wk = (const float*)d_in[19]; const float* ca_bk = (const float*)d_in[20];
  const float* ca_wv = (const float*)d_in[21];
  const float* ca_bv = (const float*)d_in[22];
  const float* n1g = (const float*)d_in[23];   const float* n1b = (const float*)d_in[24];
  const float* n2g = (const float*)d_in[25];   const float* n2b = (const float*)d_in[26];
  const float* r2g = (const float*)d_in[27];   const float* r2b = (const float*)d_in[28];
  const float* fw1 = (const float*)d_in[29];   const float* fb1 = (const float*)d_in[30];
  const float* fw2 = (const float*)d_in[31];   const float* fb2 = (const float*)d_in[32];

  // ---- static 150MB lifetime-planned workspace ----
  char* wsb = (char*)d_ws;
  const size_t MBy = 1048576;
  bf16* fw1T = (bf16*)(wsb + 0 * MBy);
  bf16* fw2T = (bf16*)(wsb + 4 * MBy);
  bf16* wqT  = (bf16*)(wsb + 8 * MBy);    // wq|wk|wv contiguous (3x2MB)
  bf16* wkT  = (bf16*)(wsb + 10 * MBy);
  bf16* wvT  = (bf16*)(wsb + 12 * MBy);
  bf16* woT  = (bf16*)(wsb + 14 * MBy);
  bf16* cwqT = (bf16*)(wsb + 16 * MBy);
  bf16* cwkT = (bf16*)(wsb + 18 * MBy);   // cwk|cwv contiguous (2x2MB)
  bf16* cwvT = (bf16*)(wsb + 20 * MBy);
  bf16* h_bf = (bf16*)(wsb + 22 * MBy);
  bf16* t_bf = h_bf;  bf16* h2_bf = h_bf;
  bf16* q_bf = (bf16*)(wsb + 38 * MBy);
  bf16* av_bf = q_bf;
  bf16* gA = (bf16*)(wsb + 22 * MBy);           // z 0..31 (h/t/q/av dead)
  bf16* k_bf = (bf16*)(wsb + 54 * MBy);
  bf16* cq_bf = k_bf;  bf16* res_b = k_bf;
  bf16* v_bf = (bf16*)(wsb + 70 * MBy);
  bf16* ck_bf = v_bf;
  bf16* cv_bf = (bf16*)(wsb + 78 * MBy);
  bf16* x2_b  = v_bf;
  bf16* vT  = (bf16*)(wsb + 86 * MBy);
  bf16* cvT = vT;
  bf16* o_bf = (bf16*)(wsb + 102 * MBy);
  bf16* x1_b = o_bf;
  bf16* gB  = (bf16*)(wsb + 118 * MBy);          // z 32..63
  bf16* ffh = gB;

  float* out_x    = (float*)d_out;
  float* out_attn = out_x + 8 * 1024 * 1024;

  const dim3 blk(256);

  TP9 tp;
  tp.in[0] = sa_wq; tp.out[0] = wqT;
  tp.in[1] = sa_wk; tp.out[1] = wkT;
  tp.in[2] = sa_wv; tp.out[2] = wvT;
  tp.in[3] = sa_wo; tp.out[3] = woT;
  tp.in[4] = ca_wq; tp.out[4] = cwqT;
  tp.in[5] = ca_wk; tp.out[5] = cwkT;
  tp.in[6] = ca_wv; tp.out[6] = cwvT;
  tp.in[7] = fw1;   tp.out[7] = fw1T;
  tp.in[8] = fw2;   tp.out[8] = fw2T;
  transpose_w9<<<dim3(32, 64, 9), blk, 0, stream>>>(tp);

  ln_k<float><<<dim3(2048), blk, 0, stream>>>(x, r1g, r1b, h_bf);

  // fused QKV projection: packed weights wqT|wkT|wvT, split outputs
  Out3 oqkv = { q_bf, k_bf, v_bf, sa_bq, sa_bk, sa_bv };
  gemm_bt_split<<<dim3(24, 64), blk, 0, stream>>>(h_bf, wqT, oqkv, 8192, 3072, 1024);

  transpose_k<bf16><<<dim3(32, 4, 64), blk, 0, stream>>>(v_bf, vT, 1024, 1024,
      (long)1024 * 1024, 128, (long)128 * 1024, 8);

  attn_self<<<dim3(8, 64), dim3(512), 0, stream>>>(q_bf, k_bf, vT, o_bf);

  gemm_bt<<<dim3(8, 64), blk, 0, stream>>>(o_bf, woT, sa_bo, nullptr, x, x1_b, nullptr, 8192, 1024, 1024, 0);

  // t = LN(x1); av = LN(y) in one launch
  ln_pair<<<dim3(3072), blk, 0, stream>>>(x1_b, tn_g, tn_b, t_bf, y, an_g, an_b, av_bf);

  gemm_bt<<<dim3(8, 64), blk, 0, stream>>>(t_bf, cwqT, ca_bq, nullptr, nullptr, cq_bf, nullptr, 8192, 1024, 1024, 0);

  // fused CK/CV projection: packed weights cwkT|cwvT, split outputs
  Out3 ockv = { ck_bf, cv_bf, nullptr, ca_bk, ca_bv, nullptr };
  gemm_bt_split<<<dim3(16, 32), blk, 0, stream>>>(av_bf, cwkT, ockv, 4096, 2048, 1024);

  transpose_k<bf16><<<dim3(16, 4, 64), blk, 0, stream>>>(cv_bf, cvT, 1024, 512,
      (long)512 * 1024, 128, (long)128 * 512, 8);

  // gate (per-head blocks) -> G; then attn_out mean; then res GEMM
  gate2<<<dim3(32, 64), blk, 0, stream>>>(cq_bf, ck_bf, gA, gB);
  reduce_h<<<dim3(4096), blk, 0, stream>>>(gA, gB, out_attn);
  gemm_res<<<dim3(8, 1, 64), blk, 0, stream>>>(gA, gB, cvT, res_b);

  // x2 = LN(x1)+LN(res); h2 = LN(x2) in one launch
  ln_fuse2<<<dim3(2048), blk, 0, stream>>>(x1_b, n1g, n1b, res_b, n2g, n2b,
                                           r2g, r2b, x2_b, h2_bf);

  gemm_bt<<<dim3(16, 64), blk, 0, stream>>>(h2_bf, fw1T, fb1, nullptr, nullptr, ffh, nullptr, 8192, 2048, 1024, 1);
  gemm_bt<<<dim3(8, 64), blk, 0, stream>>>(ffh, fw2T, fb2, x2_b, nullptr, nullptr, out_x, 8192, 1024, 2048, 0);
}

// Round 6
// 699.378 us; speedup vs baseline: 1.3852x; 1.0247x over previous
//
#include <hip/hip_runtime.h>

// ---------------------------------------------------------------------------
// CrossDecoderLayer on MI355X (gfx950). External I/O fp32; internal bf16
// MFMA, fp32 accumulate. B=8, W=1024, V=512, D=1024, H=8, DK=128.
// R7 : XOR-swizzle on attn_self Ks/Vs/Ps and gate2 Ks/Pt (conflicts 15M->4M).
// R9 : FAILED (reg-prefetch spilled). Reverted.
// R10: launch fusion (30->21 dispatches): -78us.
// R11: 512-thr attn (128 q-rows/blk) + more fusion: 890->716us. BUT
//      __launch_bounds__(512,4) made hipcc cap VGPR=64 -> scratch spill
//      (WRITE 16->22.5MB, ord-0 178us outlier).
// R12: attn launch_bounds(512) only (LDS caps occupancy; ~116 VGPR, no
//      spill). T1 bijective XCD swizzle (row-major chunks) on gemm_bt /
//      gemm_bt_split: A row-panels stay on one XCD's L2 (FFN2 FETCH 153MB
//      vs 52 ideal was cross-XCD duplication).
// ---------------------------------------------------------------------------

typedef __bf16 bf16;
typedef bf16  bf16x4 __attribute__((ext_vector_type(4)));
typedef bf16  bf16x8 __attribute__((ext_vector_type(8)));
typedef float f32x4  __attribute__((ext_vector_type(4)));

#define SCALE 0.08838834764831845f  // 1/sqrt(128)

__device__ __forceinline__ f32x4 mfma16(bf16x8 a, bf16x8 b, f32x4 c) {
  return __builtin_amdgcn_mfma_f32_16x16x32_bf16(a, b, c, 0, 0, 0);
}

__device__ __forceinline__ void gll16(const bf16* g, bf16* l) {
  __builtin_amdgcn_global_load_lds(
      (__attribute__((address_space(1))) void*)(void*)g,
      (__attribute__((address_space(3))) void*)(void*)l, 16, 0, 0);
}

// XCD-aware bijective block swizzle (T1). Requires nwg % 8 == 0 (all our
// gemm grids: 512/1024/1536). Row-major chunking: each XCD gets contiguous
// (by,bx) row-panels so the A panel is fetched by exactly one XCD L2.
__device__ __forceinline__ void xcd_tile(int& bm, int& bn) {
  const int nx = gridDim.x;
  const int nwg = nx * gridDim.y;
  int bid = blockIdx.y * nx + blockIdx.x;
  const int cpx = nwg >> 3;
  bid = (bid & 7) * cpx + (bid >> 3);
  bn = (bid % nx) * 128;
  bm = (bid / nx) * 128;
}

// ---------------------------------------------------------------------------
// GEMM: C = epi(A[M,K] @ Bt[N,K]^T + bias [+residF]), 128x128 tile, BK=32,
// 4 waves x (64x64), global_load_lds staging (m97 structure).
// ---------------------------------------------------------------------------
__global__ __launch_bounds__(256) void gemm_bt(
    const bf16* __restrict__ A, const bf16* __restrict__ Bt,
    const float* __restrict__ bias,
    const bf16* __restrict__ residB, const float* __restrict__ residF,
    bf16* __restrict__ Cb, float* __restrict__ Cf,
    int M, int N, int K, int relu)
{
  __shared__ alignas(16) bf16 As[128 * 32];
  __shared__ alignas(16) bf16 Bs[128 * 32];
  const int tid  = threadIdx.x;
  const int wid  = tid >> 6;
  const int lane = tid & 63;
  const int l15  = lane & 15;
  const int quad = lane >> 4;
  int bm, bn;
  xcd_tile(bm, bn);
  const int wm = (wid & 1) * 64,  wn = (wid >> 1) * 64;

  f32x4 acc[4][4] = {};

  const int srow = tid >> 2;
  const int scol = (tid & 3) * 8;
  const bf16* ag0 = A  + (long)(bm + srow) * K + scol;
  const bf16* ag1 = ag0 + (long)64 * K;
  const bf16* bg0 = Bt + (long)(bn + srow) * K + scol;
  const bf16* bg1 = bg0 + (long)64 * K;
  bf16* lA0 = As + wid * 512;
  bf16* lA1 = As + 2048 + wid * 512;
  bf16* lB0 = Bs + wid * 512;
  bf16* lB1 = Bs + 2048 + wid * 512;

  for (int k0 = 0; k0 < K; k0 += 32) {
    gll16(ag0 + k0, lA0);
    gll16(ag1 + k0, lA1);
    gll16(bg0 + k0, lB0);
    gll16(bg1 + k0, lB1);
    __syncthreads();
    bf16x8 af[4], bfr[4];
#pragma unroll
    for (int i = 0; i < 4; ++i)
      af[i] = *(const bf16x8*)(As + (wm + i * 16 + l15) * 32 + quad * 8);
#pragma unroll
    for (int i = 0; i < 4; ++i)
      bfr[i] = *(const bf16x8*)(Bs + (wn + i * 16 + l15) * 32 + quad * 8);
#pragma unroll
    for (int mt = 0; mt < 4; ++mt)
#pragma unroll
      for (int nt = 0; nt < 4; ++nt)
        acc[mt][nt] = mfma16(af[mt], bfr[nt], acc[mt][nt]);
    __syncthreads();
  }

#pragma unroll
  for (int nt = 0; nt < 4; ++nt) {
    const int col = bn + wn + nt * 16 + l15;
    const float bv = bias ? bias[col] : 0.f;
#pragma unroll
    for (int mt = 0; mt < 4; ++mt) {
      const int row0 = bm + wm + mt * 16 + quad * 4;
#pragma unroll
      for (int r = 0; r < 4; ++r) {
        const long idx = (long)(row0 + r) * N + col;
        float v = acc[mt][nt][r] + bv;
        if (relu) v = fmaxf(v, 0.f);
        if (residB) v += (float)residB[idx];
        if (residF) v += residF[idx];
        if (Cb) Cb[idx] = (bf16)v;
        if (Cf) Cf[idx] = v;
      }
    }
  }
}

// ---------------------------------------------------------------------------
// gemm_bt_split: same m97 GEMM over a packed Bt of Ntot columns, but the
// epilogue splits output into per-1024-column buffers (each [M][1024]).
// ---------------------------------------------------------------------------
struct Out3 {
  bf16* o0; bf16* o1; bf16* o2;
  const float* b0; const float* b1; const float* b2;
};

__global__ __launch_bounds__(256) void gemm_bt_split(
    const bf16* __restrict__ A, const bf16* __restrict__ Bt,
    Out3 so, int M, int Ntot, int K)
{
  __shared__ alignas(16) bf16 As[128 * 32];
  __shared__ alignas(16) bf16 Bs[128 * 32];
  const int tid  = threadIdx.x;
  const int wid  = tid >> 6;
  const int lane = tid & 63;
  const int l15  = lane & 15;
  const int quad = lane >> 4;
  int bm, bn;
  xcd_tile(bm, bn);
  const int wm = (wid & 1) * 64,  wn = (wid >> 1) * 64;

  const int ch = bn >> 10;
  bf16* C = (ch == 0) ? so.o0 : (ch == 1 ? so.o1 : so.o2);
  const float* bp = (ch == 0) ? so.b0 : (ch == 1 ? so.b1 : so.b2);

  f32x4 acc[4][4] = {};

  const int srow = tid >> 2;
  const int scol = (tid & 3) * 8;
  const bf16* ag0 = A  + (long)(bm + srow) * K + scol;
  const bf16* ag1 = ag0 + (long)64 * K;
  const bf16* bg0 = Bt + (long)(bn + srow) * K + scol;
  const bf16* bg1 = bg0 + (long)64 * K;
  bf16* lA0 = As + wid * 512;
  bf16* lA1 = As + 2048 + wid * 512;
  bf16* lB0 = Bs + wid * 512;
  bf16* lB1 = Bs + 2048 + wid * 512;

  for (int k0 = 0; k0 < K; k0 += 32) {
    gll16(ag0 + k0, lA0);
    gll16(ag1 + k0, lA1);
    gll16(bg0 + k0, lB0);
    gll16(bg1 + k0, lB1);
    __syncthreads();
    bf16x8 af[4], bfr[4];
#pragma unroll
    for (int i = 0; i < 4; ++i)
      af[i] = *(const bf16x8*)(As + (wm + i * 16 + l15) * 32 + quad * 8);
#pragma unroll
    for (int i = 0; i < 4; ++i)
      bfr[i] = *(const bf16x8*)(Bs + (wn + i * 16 + l15) * 32 + quad * 8);
#pragma unroll
    for (int mt = 0; mt < 4; ++mt)
#pragma unroll
      for (int nt = 0; nt < 4; ++nt)
        acc[mt][nt] = mfma16(af[mt], bfr[nt], acc[mt][nt]);
    __syncthreads();
  }

#pragma unroll
  for (int nt = 0; nt < 4; ++nt) {
    const int col = bn + wn + nt * 16 + l15;
    const int cc  = col & 1023;
    const float bv = bp[cc];
#pragma unroll
    for (int mt = 0; mt < 4; ++mt) {
      const int row0 = bm + wm + mt * 16 + quad * 4;
#pragma unroll
      for (int r = 0; r < 4; ++r)
        C[(long)(row0 + r) * 1024 + cc] = (bf16)(acc[mt][nt][r] + bv);
    }
  }
  (void)M; (void)Ntot;
}

// ---------------------------------------------------------------------------
// Flash-style self-attention. R11 structure; R12: launch_bounds(512) only
// (R11's (512,4) forced VGPR=64 -> spill). LDS 80KB caps at 2 blocks/CU.
// ---------------------------------------------------------------------------
__global__ __launch_bounds__(512) void attn_self(
    const bf16* __restrict__ Q, const bf16* __restrict__ Km,
    const bf16* __restrict__ Vt, bf16* __restrict__ O)
{
  __shared__ alignas(16) bf16 Ks[16384];
  __shared__ alignas(16) bf16 Vs[16384];
  __shared__ alignas(16) bf16 Ps[8192];      // 8 waves x (2 chunks x 512)
  const int tid  = threadIdx.x;
  const int wid  = tid >> 6;                  // 0..7
  const int lane = tid & 63;
  const int l15  = lane & 15;
  const int quad = lane >> 4;
  const int b = blockIdx.y >> 3, h = blockIdx.y & 7;
  const int q0 = blockIdx.x * 128;

  // swizzled read offset within a [rows][32] chunk: row=l15, slot=quad^((l15>>1)&3)
  const int rdoff = l15 * 32 + (((quad ^ ((l15 >> 1) & 3))) << 3);

  const long qb = ((long)(b * 1024 + q0 + wid * 16 + l15)) * 1024 + h * 128 + quad * 8;
  bf16x8 qf[4];
#pragma unroll
  for (int ks = 0; ks < 4; ++ks) qf[ks] = *(const bf16x8*)(Q + qb + ks * 32);

  f32x4 oacc[8] = {};
  float mrow[4], lrow[4];
#pragma unroll
  for (int r = 0; r < 4; ++r) { mrow[r] = -3.0e38f; lrow[r] = 0.f; }

  const long kbase = (long)(b * 1024) * 1024 + h * 128;
  const long vbase = (long)(b * 8 + h) * 128 * 1024;

  const int srow = tid >> 3;        // 0..63
  const int sc8  = (tid & 7) * 8;

  bf16* pw = Ps + wid * 1024;

  for (int t = 0; t < 8; ++t) {
    const int kv0 = t * 128;
    __syncthreads();
#pragma unroll
    for (int dh = 0; dh < 2; ++dh)
#pragma unroll
      for (int kq = 0; kq < 2; ++kq) {
        const int kv = kq * 64 + srow;
        const int d  = dh * 64 + sc8;
        bf16x8 v = *(const bf16x8*)(Km + kbase + (long)(kv0 + kv) * 1024 + d);
        *(bf16x8*)(Ks + (d >> 5) * 4096 + kv * 32 +
                   (((((d & 31) >> 3) ^ ((kv >> 1) & 3))) << 3)) = v;
      }
#pragma unroll
    for (int kh = 0; kh < 2; ++kh)
#pragma unroll
      for (int dq = 0; dq < 2; ++dq) {
        const int d  = dq * 64 + srow;
        const int kv = kh * 64 + sc8;
        bf16x8 v = *(const bf16x8*)(Vt + vbase + (long)d * 1024 + kv0 + kv);
        *(bf16x8*)(Vs + (kv >> 5) * 4096 + d * 32 +
                   (((((kv & 31) >> 3) ^ ((d >> 1) & 3))) << 3)) = v;
      }
    __syncthreads();

    f32x4 sacc[8] = {};
#pragma unroll
    for (int nt = 0; nt < 8; ++nt)
#pragma unroll
      for (int ks = 0; ks < 4; ++ks)
        sacc[nt] = mfma16(qf[ks],
            *(const bf16x8*)(Ks + ks * 4096 + nt * 512 + rdoff),
            sacc[nt]);

    float tm[4];
#pragma unroll
    for (int r = 0; r < 4; ++r) {
      float m = -3.0e38f;
#pragma unroll
      for (int nt = 0; nt < 8; ++nt) m = fmaxf(m, sacc[nt][r]);
      tm[r] = m * SCALE;
    }
#pragma unroll
    for (int off = 8; off; off >>= 1)
#pragma unroll
      for (int r = 0; r < 4; ++r) tm[r] = fmaxf(tm[r], __shfl_xor(tm[r], off));
    float alpha[4], psum[4];
#pragma unroll
    for (int r = 0; r < 4; ++r) {
      const float mnew = fmaxf(mrow[r], tm[r]);
      alpha[r] = __expf(mrow[r] - mnew);
      mrow[r] = mnew;
      psum[r] = 0.f;
    }
#pragma unroll
    for (int nt = 0; nt < 8; ++nt)
#pragma unroll
      for (int r = 0; r < 4; ++r) oacc[nt][r] *= alpha[r];

    // two PV halves, reusing the 2-chunk per-wave P buffer
#pragma unroll
    for (int hs = 0; hs < 2; ++hs) {
#pragma unroll
      for (int n2 = 0; n2 < 4; ++n2) {
        const int nt = hs * 4 + n2;
#pragma unroll
        for (int r = 0; r < 4; ++r) {
          const float p = __expf(sacc[nt][r] * SCALE - mrow[r]);
          psum[r] += p;
          const int prow = quad * 4 + r;
          pw[((nt >> 1) & 1) * 512 + prow * 32 +
             (((((nt & 1) * 2 + (l15 >> 3)) ^ ((prow >> 1) & 3))) << 3) + (l15 & 7)] =
              (bf16)p;
        }
      }
#pragma unroll
      for (int ks2 = 0; ks2 < 2; ++ks2) {
        const bf16x8 pa = *(const bf16x8*)(pw + ks2 * 512 + rdoff);
        const int ksx = hs * 2 + ks2;
#pragma unroll
        for (int nt = 0; nt < 8; ++nt)
          oacc[nt] = mfma16(pa,
              *(const bf16x8*)(Vs + ksx * 4096 + nt * 512 + rdoff),
              oacc[nt]);
      }
    }

#pragma unroll
    for (int off = 8; off; off >>= 1)
#pragma unroll
      for (int r = 0; r < 4; ++r) psum[r] += __shfl_xor(psum[r], off);
#pragma unroll
    for (int r = 0; r < 4; ++r) lrow[r] = lrow[r] * alpha[r] + psum[r];
  }

  float linv[4];
#pragma unroll
  for (int r = 0; r < 4; ++r) linv[r] = 1.f / lrow[r];
#pragma unroll
  for (int nt = 0; nt < 8; ++nt)
#pragma unroll
    for (int r = 0; r < 4; ++r) {
      const int row = q0 + wid * 16 + quad * 4 + r;
      O[((long)(b * 1024 + row)) * 1024 + h * 128 + nt * 16 + l15] =
          (bf16)(oacc[nt][r] * linv[r]);
    }
}

// ---------------------------------------------------------------------------
// gate2: G[z=(b,h)][w][v] = sigmoid(SCALE * CQ.CK^T). Grid (32 wtiles, 64 z).
// ---------------------------------------------------------------------------
__global__ __launch_bounds__(256) void gate2(
    const bf16* __restrict__ CQ, const bf16* __restrict__ CK,
    bf16* __restrict__ gA, bf16* __restrict__ gB)
{
  __shared__ alignas(16) bf16 Ks[16384];      // 4 dchunks x 128 v x 32 d
  __shared__ alignas(16) bf16 Pt[4][1024];    // per-wave 16w x 64v transpose
  const int tid  = threadIdx.x;
  const int wid  = tid >> 6;
  const int lane = tid & 63;
  const int l15  = lane & 15;
  const int quad = lane >> 4;
  const int z = blockIdx.y, b = z >> 3, h = z & 7;
  const int w0 = blockIdx.x * 32;
  const int rsel = wid & 1, vsel = wid >> 1;

  const int rdoff = l15 * 32 + (((quad ^ ((l15 >> 1) & 3))) << 3);

  bf16* Gz = (z < 32) ? (gA + (long)z * 524288) : (gB + (long)(z - 32) * 524288);

  const long qb = ((long)(b * 1024 + w0 + rsel * 16 + l15)) * 1024 + h * 128 + quad * 8;
  bf16x8 qf[4];
#pragma unroll
  for (int ks = 0; ks < 4; ++ks) qf[ks] = *(const bf16x8*)(CQ + qb + ks * 32);

  const int srow = tid >> 3;        // 0..31
  const int sc8  = (tid & 7) * 8;   // 0..56

  for (int vt = 0; vt < 4; ++vt) {
    const int v0 = vt * 128;
    __syncthreads();
#pragma unroll
    for (int i = 0; i < 4; ++i) {
      const int v = i * 32 + srow;
#pragma unroll
      for (int dh = 0; dh < 2; ++dh) {
        const int d = dh * 64 + sc8;
        bf16x8 val = *(const bf16x8*)(CK + ((long)(b * 512 + v0 + v)) * 1024 + h * 128 + d);
        *(bf16x8*)(Ks + (d >> 5) * 4096 + v * 32 +
                   (((((d & 31) >> 3) ^ ((v >> 1) & 3))) << 3)) = val;
      }
    }
    __syncthreads();

    f32x4 sacc[4] = {};
#pragma unroll
    for (int nt = 0; nt < 4; ++nt)
#pragma unroll
      for (int ks = 0; ks < 4; ++ks)
        sacc[nt] = mfma16(qf[ks],
            *(const bf16x8*)(Ks + ks * 4096 + vsel * 2048 + nt * 512 + rdoff),
            sacc[nt]);

#pragma unroll
    for (int nt = 0; nt < 4; ++nt)
#pragma unroll
      for (int r = 0; r < 4; ++r) {
        const float g = 1.f / (1.f + __expf(-sacc[nt][r] * SCALE));
        const int prow = quad * 4 + r;
        const int g0 = nt * 2 + (l15 >> 3);
        Pt[wid][prow * 64 + ((g0 ^ ((prow >> 1) & 3)) << 3) + (l15 & 7)] = (bf16)g;
      }
#pragma unroll
    for (int pass = 0; pass < 2; ++pass) {
      const int f = pass * 512 + lane * 8;
      const int row = f >> 6, col = f & 63;
      const int gl = (lane & 7) ^ ((row >> 1) & 3);
      bf16x8 vv = *(const bf16x8*)(&Pt[wid][row * 64 + gl * 8]);
      *(bf16x8*)(Gz + (long)(w0 + rsel * 16 + row) * 512 + v0 + vsel * 64 + col) = vv;
    }
  }
}

// ---------------------------------------------------------------------------
// reduce_h: attn_out[b,w,v] = mean over 8 heads of G. Fully coalesced.
// ---------------------------------------------------------------------------
__global__ __launch_bounds__(256) void reduce_h(
    const bf16* __restrict__ gA, const bf16* __restrict__ gB,
    float* __restrict__ AOUT)
{
  const int idx = blockIdx.x * 256 + threadIdx.x;  // 1,048,576 total
  const int v4 = idx & 127;
  const int w  = (idx >> 7) & 1023;
  const int b  = idx >> 17;
  float s0 = 0.f, s1 = 0.f, s2 = 0.f, s3 = 0.f;
#pragma unroll
  for (int h = 0; h < 8; ++h) {
    const int z = b * 8 + h;
    const bf16* base = (z < 32) ? (gA + (long)z * 524288) : (gB + (long)(z - 32) * 524288);
    bf16x4 g = *(const bf16x4*)(base + (long)w * 512 + v4 * 4);
    s0 += (float)g[0]; s1 += (float)g[1]; s2 += (float)g[2]; s3 += (float)g[3];
  }
  *(float4*)(AOUT + (long)idx * 4) =
      make_float4(s0 * 0.125f, s1 * 0.125f, s2 * 0.125f, s3 * 0.125f);
}

// ---------------------------------------------------------------------------
// gemm_res: res[b,w,h*128+d] = G[z] (1024x512) @ CVt[z] (128x512)^T (m97).
// ---------------------------------------------------------------------------
__global__ __launch_bounds__(256) void gemm_res(
    const bf16* __restrict__ gA, const bf16* __restrict__ gB,
    const bf16* __restrict__ CVt, bf16* __restrict__ RES)
{
  __shared__ alignas(16) bf16 As[128 * 32];
  __shared__ alignas(16) bf16 Bs[128 * 32];
  const int tid  = threadIdx.x;
  const int wid  = tid >> 6;
  const int lane = tid & 63;
  const int l15  = lane & 15;
  const int quad = lane >> 4;
  const int z = blockIdx.z, b = z >> 3, h = z & 7;
  const bf16* A  = (z < 32) ? (gA + (long)z * 524288) : (gB + (long)(z - 32) * 524288);
  const bf16* Bt = CVt + (long)z * 65536;
  const int bm = blockIdx.x * 128;
  const int wm = (wid & 1) * 64, wn = (wid >> 1) * 64;

  f32x4 acc[4][4] = {};

  const int srow = tid >> 2;
  const int scol = (tid & 3) * 8;
  const bf16* ag0 = A  + (long)(bm + srow) * 512 + scol;
  const bf16* ag1 = ag0 + (long)64 * 512;
  const bf16* bg0 = Bt + (long)srow * 512 + scol;
  const bf16* bg1 = bg0 + (long)64 * 512;
  bf16* lA0 = As + wid * 512;
  bf16* lA1 = As + 2048 + wid * 512;
  bf16* lB0 = Bs + wid * 512;
  bf16* lB1 = Bs + 2048 + wid * 512;

  for (int k0 = 0; k0 < 512; k0 += 32) {
    gll16(ag0 + k0, lA0);
    gll16(ag1 + k0, lA1);
    gll16(bg0 + k0, lB0);
    gll16(bg1 + k0, lB1);
    __syncthreads();
    bf16x8 af[4], bfr[4];
#pragma unroll
    for (int i = 0; i < 4; ++i)
      af[i] = *(const bf16x8*)(As + (wm + i * 16 + l15) * 32 + quad * 8);
#pragma unroll
    for (int i = 0; i < 4; ++i)
      bfr[i] = *(const bf16x8*)(Bs + (wn + i * 16 + l15) * 32 + quad * 8);
#pragma unroll
    for (int mt = 0; mt < 4; ++mt)
#pragma unroll
      for (int nt = 0; nt < 4; ++nt)
        acc[mt][nt] = mfma16(af[mt], bfr[nt], acc[mt][nt]);
    __syncthreads();
  }

#pragma unroll
  for (int nt = 0; nt < 4; ++nt) {
    const int col = h * 128 + wn + nt * 16 + l15;
#pragma unroll
    for (int mt = 0; mt < 4; ++mt) {
      const int row0 = bm + wm + mt * 16 + quad * 4;
#pragma unroll
      for (int r = 0; r < 4; ++r)
        RES[((long)(b * 1024 + row0 + r)) * 1024 + col] = (bf16)acc[mt][nt][r];
    }
  }
}

// ---------------------------------------------------------------------------
// Batched transpose through LDS: T in {float,bf16} -> bf16 out.
// ---------------------------------------------------------------------------
template <typename T>
__global__ __launch_bounds__(256) void transpose_k(
    const T* __restrict__ in, bf16* __restrict__ out,
    int sIR, int sOR, long inStrideB, long inStrideH, long outStrideZ, int H)
{
  __shared__ bf16 t[32][33];
  const int z = blockIdx.z;
  const T* ib = in + (long)(z / H) * inStrideB + (long)(z % H) * inStrideH;
  bf16* ob = out + (long)z * outStrideZ;
  const int r0 = blockIdx.x * 32, c0 = blockIdx.y * 32;
  const int tx = threadIdx.x & 31, ty = threadIdx.x >> 5;
#pragma unroll
  for (int i = 0; i < 32; i += 8)
    t[ty + i][tx] = (bf16)(float)ib[(long)(r0 + ty + i) * sIR + (c0 + tx)];
  __syncthreads();
#pragma unroll
  for (int i = 0; i < 32; i += 8)
    ob[(long)(c0 + ty + i) * sOR + (r0 + tx)] = t[tx][ty + i];
}

// ---------------------------------------------------------------------------
// transpose_w9: z-batched fp32->bf16 transposes of all 9 weight matrices in
// one launch. z<7: 1024x1024. z=7: fw1 1024x2048. z=8: fw2 2048x1024.
// ---------------------------------------------------------------------------
struct TP9 { const float* in[9]; bf16* out[9]; };

__global__ __launch_bounds__(256) void transpose_w9(TP9 p)
{
  __shared__ bf16 t[32][33];
  const int z = blockIdx.z;
  int r0, c0, sIR, sOR;
  if (z < 7) {
    if (blockIdx.y >= 32) return;
    r0 = blockIdx.x * 32; c0 = blockIdx.y * 32; sIR = 1024; sOR = 1024;
  } else if (z == 7) {            // in 1024x2048 -> out 2048x1024
    r0 = blockIdx.x * 32; c0 = blockIdx.y * 32; sIR = 2048; sOR = 1024;
  } else {                        // in 2048x1024 -> out 1024x2048
    r0 = blockIdx.y * 32; c0 = blockIdx.x * 32; sIR = 1024; sOR = 2048;
  }
  const float* ib = p.in[z];
  bf16* ob = p.out[z];
  const int tx = threadIdx.x & 31, ty = threadIdx.x >> 5;
#pragma unroll
  for (int i = 0; i < 32; i += 8)
    t[ty + i][tx] = (bf16)ib[(long)(r0 + ty + i) * sIR + (c0 + tx)];
  __syncthreads();
#pragma unroll
  for (int i = 0; i < 32; i += 8)
    ob[(long)(c0 + ty + i) * sOR + (r0 + tx)] = t[tx][ty + i];
}

// ---------------------------------------------------------------------------
// LayerNorm over D=1024, 1 wave/row. Shared row body.
// ---------------------------------------------------------------------------
__device__ __forceinline__ void load16v(float* d, const bf16* p) {
  bf16x8 a = *(const bf16x8*)p, b2 = *(const bf16x8*)(p + 8);
#pragma unroll
  for (int j = 0; j < 8; ++j) { d[j] = (float)a[j]; d[j + 8] = (float)b2[j]; }
}
__device__ __forceinline__ void load16v(float* d, const float* p) {
#pragma unroll
  for (int j = 0; j < 4; ++j) {
    float4 v = ((const float4*)p)[j];
    d[4*j] = v.x; d[4*j+1] = v.y; d[4*j+2] = v.z; d[4*j+3] = v.w;
  }
}

template <typename TI>
__device__ __forceinline__ void ln_row_body(
    const TI* __restrict__ X, const float* __restrict__ G,
    const float* __restrict__ Bb, bf16* __restrict__ out, long row, int lane)
{
  const int c0 = lane * 16;
  const long base = row * 1024 + c0;
  float a[16];
  load16v(a, X + base);
  float s = 0.f, ss = 0.f;
#pragma unroll
  for (int j = 0; j < 16; ++j) { s += a[j]; ss += a[j] * a[j]; }
#pragma unroll
  for (int off = 32; off; off >>= 1) { s += __shfl_xor(s, off); ss += __shfl_xor(ss, off); }
  const float inv = 1.f / 1024.f;
  const float m = s * inv;
  const float rr = rsqrtf(fmaxf(ss * inv - m * m, 0.f) + 1e-5f);
  bf16x8 o0, o1;
#pragma unroll
  for (int j = 0; j < 16; ++j) {
    float v = (a[j] - m) * rr * G[c0 + j] + Bb[c0 + j];
    if (j < 8) o0[j] = (bf16)v; else o1[j - 8] = (bf16)v;
  }
  *(bf16x8*)(out + base) = o0;
  *(bf16x8*)(out + base + 8) = o1;
}

template <typename TI>
__global__ __launch_bounds__(256) void ln_k(
    const TI* __restrict__ X, const float* __restrict__ G1,
    const float* __restrict__ B1, bf16* __restrict__ out)
{
  const int wid = threadIdx.x >> 6, lane = threadIdx.x & 63;
  ln_row_body<TI>(X, G1, B1, out, (long)blockIdx.x * 4 + wid, lane);
}

// ln_pair: blocks [0,2048) LN 8192 bf16 rows; [2048,3072) LN 4096 f32 rows.
__global__ __launch_bounds__(256) void ln_pair(
    const bf16* __restrict__ Xa, const float* __restrict__ Ga,
    const float* __restrict__ Ba, bf16* __restrict__ outA,
    const float* __restrict__ Xb, const float* __restrict__ Gb,
    const float* __restrict__ Bb, bf16* __restrict__ outB)
{
  const int wid = threadIdx.x >> 6, lane = threadIdx.x & 63;
  const long row = (long)blockIdx.x * 4 + wid;
  if (blockIdx.x < 2048) ln_row_body<bf16>(Xa, Ga, Ba, outA, row, lane);
  else                   ln_row_body<float>(Xb, Gb, Bb, outB, row - 8192, lane);
}

// ln_fuse2: v = LN(X1;G1,B1)+LN(X2;G2,B2); outX = bf16(v); outH = LN(v;G3,B3).
__global__ __launch_bounds__(256) void ln_fuse2(
    const bf16* __restrict__ X1, const float* __restrict__ G1, const float* __restrict__ B1,
    const bf16* __restrict__ X2, const float* __restrict__ G2, const float* __restrict__ B2,
    const float* __restrict__ G3, const float* __restrict__ B3,
    bf16* __restrict__ outX, bf16* __restrict__ outH)
{
  const int wid = threadIdx.x >> 6, lane = threadIdx.x & 63;
  const long row = (long)blockIdx.x * 4 + wid;
  const int c0 = lane * 16;
  const long base = row * 1024 + c0;

  float a[16], b[16];
  load16v(a, X1 + base);
  load16v(b, X2 + base);
  float s1 = 0.f, ss1 = 0.f, s2 = 0.f, ss2 = 0.f;
#pragma unroll
  for (int j = 0; j < 16; ++j) {
    s1 += a[j]; ss1 += a[j] * a[j];
    s2 += b[j]; ss2 += b[j] * b[j];
  }
#pragma unroll
  for (int off = 32; off; off >>= 1) {
    s1 += __shfl_xor(s1, off); ss1 += __shfl_xor(ss1, off);
    s2 += __shfl_xor(s2, off); ss2 += __shfl_xor(ss2, off);
  }
  const float inv = 1.f / 1024.f;
  const float m1 = s1 * inv;
  const float r1 = rsqrtf(fmaxf(ss1 * inv - m1 * m1, 0.f) + 1e-5f);
  const float m2 = s2 * inv;
  const float r2 = rsqrtf(fmaxf(ss2 * inv - m2 * m2, 0.f) + 1e-5f);

  float v[16];
  float s3 = 0.f, ss3 = 0.f;
  bf16x8 o0, o1;
#pragma unroll
  for (int j = 0; j < 16; ++j) {
    v[j] = (a[j] - m1) * r1 * G1[c0 + j] + B1[c0 + j]
         + (b[j] - m2) * r2 * G2[c0 + j] + B2[c0 + j];
    s3 += v[j]; ss3 += v[j] * v[j];
    if (j < 8) o0[j] = (bf16)v[j]; else o1[j - 8] = (bf16)v[j];
  }
  *(bf16x8*)(outX + base) = o0;
  *(bf16x8*)(outX + base + 8) = o1;
#pragma unroll
  for (int off = 32; off; off >>= 1) {
    s3 += __shfl_xor(s3, off); ss3 += __shfl_xor(ss3, off);
  }
  const float m3 = s3 * inv;
  const float r3 = rsqrtf(fmaxf(ss3 * inv - m3 * m3, 0.f) + 1e-5f);
#pragma unroll
  for (int j = 0; j < 16; ++j) {
    float hh = (v[j] - m3) * r3 * G3[c0 + j] + B3[c0 + j];
    if (j < 8) o0[j] = (bf16)hh; else o1[j - 8] = (bf16)hh;
  }
  *(bf16x8*)(outH + base) = o0;
  *(bf16x8*)(outH + base + 8) = o1;
}

// ---------------------------------------------------------------------------
extern "C" void kernel_launch(void* const* d_in, const int* in_sizes, int n_in,
                              void* d_out, int out_size, void* d_ws, size_t ws_size,
                              hipStream_t stream) {
  (void)in_sizes; (void)n_in; (void)out_size; (void)ws_size;

  const float* x   = (const float*)d_in[0];
  const float* y   = (const float*)d_in[1];
  const float* r1g = (const float*)d_in[3];  const float* r1b = (const float*)d_in[4];
  const float* sa_wq = (const float*)d_in[5];  const float* sa_bq = (const float*)d_in[6];
  const float* sa_wk = (const float*)d_in[7];  const float* sa_bk = (const float*)d_in[8];
  const float* sa_wv = (const float*)d_in[9];  const float* sa_bv = (const float*)d_in[10];
  const float* sa_wo = (const float*)d_in[11]; const float* sa_bo = (const float*)d_in[12];
  const float* tn_g = (const float*)d_in[13];  const float* tn_b = (const float*)d_in[14];
  const float* an_g = (const float*)d_in[15];  const float* an_b = (const float*)d_in[16];
  const float* ca_wq = (const float*)d_in[17]; const float* ca_bq = (const float*)d_in[18];
  const float* ca_wk = (const float*)d_in[19]; const float* ca_bk = (const float*)d_in[20];
  const float* ca_wv = (const float*)d_in[21];
  const float* ca_bv = (const float*)d_in[22];
  const float* n1g = (const float*)d_in[23];   const float* n1b = (const float*)d_in[24];
  const float* n2g = (const float*)d_in[25];   const float* n2b = (const float*)d_in[26];
  const float* r2g = (const float*)d_in[27];   const float* r2b = (const float*)d_in[28];
  const float* fw1 = (const float*)d_in[29];   const float* fb1 = (const float*)d_in[30];
  const float* fw2 = (const float*)d_in[31];   const float* fb2 = (const float*)d_in[32];

  // ---- static 150MB lifetime-planned workspace ----
  char* wsb = (char*)d_ws;
  const size_t MBy = 1048576;
  bf16* fw1T = (bf16*)(wsb + 0 * MBy);
  bf16* fw2T = (bf16*)(wsb + 4 * MBy);
  bf16* wqT  = (bf16*)(wsb + 8 * MBy);    // wq|wk|wv contiguous (3x2MB)
  bf16* wkT  = (bf16*)(wsb + 10 * MBy);
  bf16* wvT  = (bf16*)(wsb + 12 * MBy);
  bf16* woT  = (bf16*)(wsb + 14 * MBy);
  bf16* cwqT = (bf16*)(wsb + 16 * MBy);
  bf16* cwkT = (bf16*)(wsb + 18 * MBy);   // cwk|cwv contiguous (2x2MB)
  bf16* cwvT = (bf16*)(wsb + 20 * MBy);
  bf16* h_bf = (bf16*)(wsb + 22 * MBy);
  bf16* t_bf = h_bf;  bf16* h2_bf = h_bf;
  bf16* q_bf = (bf16*)(wsb + 38 * MBy);
  bf16* av_bf = q_bf;
  bf16* gA = (bf16*)(wsb + 22 * MBy);           // z 0..31 (h/t/q/av dead)
  bf16* k_bf = (bf16*)(wsb + 54 * MBy);
  bf16* cq_bf = k_bf;  bf16* res_b = k_bf;
  bf16* v_bf = (bf16*)(wsb + 70 * MBy);
  bf16* ck_bf = v_bf;
  bf16* cv_bf = (bf16*)(wsb + 78 * MBy);
  bf16* x2_b  = v_bf;
  bf16* vT  = (bf16*)(wsb + 86 * MBy);
  bf16* cvT = vT;
  bf16* o_bf = (bf16*)(wsb + 102 * MBy);
  bf16* x1_b = o_bf;
  bf16* gB  = (bf16*)(wsb + 118 * MBy);          // z 32..63
  bf16* ffh = gB;

  float* out_x    = (float*)d_out;
  float* out_attn = out_x + 8 * 1024 * 1024;

  const dim3 blk(256);

  TP9 tp;
  tp.in[0] = sa_wq; tp.out[0] = wqT;
  tp.in[1] = sa_wk; tp.out[1] = wkT;
  tp.in[2] = sa_wv; tp.out[2] = wvT;
  tp.in[3] = sa_wo; tp.out[3] = woT;
  tp.in[4] = ca_wq; tp.out[4] = cwqT;
  tp.in[5] = ca_wk; tp.out[5] = cwkT;
  tp.in[6] = ca_wv; tp.out[6] = cwvT;
  tp.in[7] = fw1;   tp.out[7] = fw1T;
  tp.in[8] = fw2;   tp.out[8] = fw2T;
  transpose_w9<<<dim3(32, 64, 9), blk, 0, stream>>>(tp);

  ln_k<float><<<dim3(2048), blk, 0, stream>>>(x, r1g, r1b, h_bf);

  // fused QKV projection: packed weights wqT|wkT|wvT, split outputs
  Out3 oqkv = { q_bf, k_bf, v_bf, sa_bq, sa_bk, sa_bv };
  gemm_bt_split<<<dim3(24, 64), blk, 0, stream>>>(h_bf, wqT, oqkv, 8192, 3072, 1024);

  transpose_k<bf16><<<dim3(32, 4, 64), blk, 0, stream>>>(v_bf, vT, 1024, 1024,
      (long)1024 * 1024, 128, (long)128 * 1024, 8);

  attn_self<<<dim3(8, 64), dim3(512), 0, stream>>>(q_bf, k_bf, vT, o_bf);

  gemm_bt<<<dim3(8, 64), blk, 0, stream>>>(o_bf, woT, sa_bo, nullptr, x, x1_b, nullptr, 8192, 1024, 1024, 0);

  // t = LN(x1); av = LN(y) in one launch
  ln_pair<<<dim3(3072), blk, 0, stream>>>(x1_b, tn_g, tn_b, t_bf, y, an_g, an_b, av_bf);

  gemm_bt<<<dim3(8, 64), blk, 0, stream>>>(t_bf, cwqT, ca_bq, nullptr, nullptr, cq_bf, nullptr, 8192, 1024, 1024, 0);

  // fused CK/CV projection: packed weights cwkT|cwvT, split outputs
  Out3 ockv = { ck_bf, cv_bf, nullptr, ca_bk, ca_bv, nullptr };
  gemm_bt_split<<<dim3(16, 32), blk, 0, stream>>>(av_bf, cwkT, ockv, 4096, 2048, 1024);

  transpose_k<bf16><<<dim3(16, 4, 64), blk, 0, stream>>>(cv_bf, cvT, 1024, 512,
      (long)512 * 1024, 128, (long)128 * 512, 8);

  // gate (per-head blocks) -> G; then attn_out mean; then res GEMM
  gate2<<<dim3(32, 64), blk, 0, stream>>>(cq_bf, ck_bf, gA, gB);
  reduce_h<<<dim3(4096), blk, 0, stream>>>(gA, gB, out_attn);
  gemm_res<<<dim3(8, 1, 64), blk, 0, stream>>>(gA, gB, cvT, res_b);

  // x2 = LN(x1)+LN(res); h2 = LN(x2) in one launch
  ln_fuse2<<<dim3(2048), blk, 0, stream>>>(x1_b, n1g, n1b, res_b, n2g, n2b,
                                           r2g, r2b, x2_b, h2_bf);

  gemm_bt<<<dim3(16, 64), blk, 0, stream>>>(h2_bf, fw1T, fb1, nullptr, nullptr, ffh, nullptr, 8192, 2048, 1024, 1);
  gemm_bt<<<dim3(8, 64), blk, 0, stream>>>(ffh, fw2T, fb2, x2_b, nullptr, nullptr, out_x, 8192, 1024, 2048, 0);
}

// Round 7
// 666.054 us; speedup vs baseline: 1.4545x; 1.0500x over previous
//
#include <hip/hip_runtime.h>

// ---------------------------------------------------------------------------
// CrossDecoderLayer on MI355X (gfx950). External I/O fp32; internal bf16
// MFMA, fp32 accumulate. B=8, W=1024, V=512, D=1024, H=8, DK=128.
// R7 : XOR-swizzle attn/gate2 LDS (conflicts 15M->4M).
// R10: launch fusion (30->21): -78us. R11: 512-thr attn + fusion: -174us.
// R12: attn VGPR fix + T1 XCD swizzle on GEMMs (FETCH 72->59MB): -17us.
// R13: BK=64 GEMMs ([2][128][32] chunked LDS -> same read pattern, half the
//      barriers per MFMA); merge cq+ckcv into one gemm_bt_split; merge
//      reduce_h+gemm_res into one launch. 17 -> 15 dispatches.
// ---------------------------------------------------------------------------

typedef __bf16 bf16;
typedef bf16  bf16x4 __attribute__((ext_vector_type(4)));
typedef bf16  bf16x8 __attribute__((ext_vector_type(8)));
typedef float f32x4  __attribute__((ext_vector_type(4)));

#define SCALE 0.08838834764831845f  // 1/sqrt(128)

__device__ __forceinline__ f32x4 mfma16(bf16x8 a, bf16x8 b, f32x4 c) {
  return __builtin_amdgcn_mfma_f32_16x16x32_bf16(a, b, c, 0, 0, 0);
}

__device__ __forceinline__ void gll16(const bf16* g, bf16* l) {
  __builtin_amdgcn_global_load_lds(
      (__attribute__((address_space(1))) void*)(void*)g,
      (__attribute__((address_space(3))) void*)(void*)l, 16, 0, 0);
}

// XCD-aware bijective block swizzle (T1). Requires nwg % 8 == 0.
__device__ __forceinline__ void xcd_tile(int& bm, int& bn) {
  const int nx = gridDim.x;
  const int nwg = nx * gridDim.y;
  int bid = blockIdx.y * nx + blockIdx.x;
  const int cpx = nwg >> 3;
  bid = (bid & 7) * cpx + (bid >> 3);
  bn = (bid % nx) * 128;
  bm = (bid / nx) * 128;
}

// ---------------------------------------------------------------------------
// GEMM: C = epi(A[M,K] @ Bt[N,K]^T + bias [+residF]), 128x128 tile, BK=64
// (two 32-col LDS chunks), 4 waves x (64x64), global_load_lds staging.
// ---------------------------------------------------------------------------
__global__ __launch_bounds__(256) void gemm_bt(
    const bf16* __restrict__ A, const bf16* __restrict__ Bt,
    const float* __restrict__ bias,
    const bf16* __restrict__ residB, const float* __restrict__ residF,
    bf16* __restrict__ Cb, float* __restrict__ Cf,
    int M, int N, int K, int relu)
{
  __shared__ alignas(16) bf16 As[128 * 64];   // [2 chunks][128][32]
  __shared__ alignas(16) bf16 Bs[128 * 64];
  const int tid  = threadIdx.x;
  const int wid  = tid >> 6;
  const int lane = tid & 63;
  const int l15  = lane & 15;
  const int quad = lane >> 4;
  int bm, bn;
  xcd_tile(bm, bn);
  const int wm = (wid & 1) * 64,  wn = (wid >> 1) * 64;

  f32x4 acc[4][4] = {};

  const int srow = tid >> 2;
  const int scol = (tid & 3) * 8;
  const bf16* ag0 = A  + (long)(bm + srow) * K + scol;
  const bf16* ag1 = ag0 + (long)64 * K;
  const bf16* bg0 = Bt + (long)(bn + srow) * K + scol;
  const bf16* bg1 = bg0 + (long)64 * K;
  bf16* lA0 = As + wid * 512;
  bf16* lA1 = As + 2048 + wid * 512;
  bf16* lA2 = As + 4096 + wid * 512;
  bf16* lA3 = As + 6144 + wid * 512;
  bf16* lB0 = Bs + wid * 512;
  bf16* lB1 = Bs + 2048 + wid * 512;
  bf16* lB2 = Bs + 4096 + wid * 512;
  bf16* lB3 = Bs + 6144 + wid * 512;

  for (int k0 = 0; k0 < K; k0 += 64) {
    gll16(ag0 + k0, lA0);
    gll16(ag1 + k0, lA1);
    gll16(ag0 + k0 + 32, lA2);
    gll16(ag1 + k0 + 32, lA3);
    gll16(bg0 + k0, lB0);
    gll16(bg1 + k0, lB1);
    gll16(bg0 + k0 + 32, lB2);
    gll16(bg1 + k0 + 32, lB3);
    __syncthreads();
#pragma unroll
    for (int kk = 0; kk < 2; ++kk) {
      bf16x8 af[4], bfr[4];
#pragma unroll
      for (int i = 0; i < 4; ++i)
        af[i] = *(const bf16x8*)(As + kk * 4096 + (wm + i * 16 + l15) * 32 + quad * 8);
#pragma unroll
      for (int i = 0; i < 4; ++i)
        bfr[i] = *(const bf16x8*)(Bs + kk * 4096 + (wn + i * 16 + l15) * 32 + quad * 8);
#pragma unroll
      for (int mt = 0; mt < 4; ++mt)
#pragma unroll
        for (int nt = 0; nt < 4; ++nt)
          acc[mt][nt] = mfma16(af[mt], bfr[nt], acc[mt][nt]);
    }
    __syncthreads();
  }

#pragma unroll
  for (int nt = 0; nt < 4; ++nt) {
    const int col = bn + wn + nt * 16 + l15;
    const float bv = bias ? bias[col] : 0.f;
#pragma unroll
    for (int mt = 0; mt < 4; ++mt) {
      const int row0 = bm + wm + mt * 16 + quad * 4;
#pragma unroll
      for (int r = 0; r < 4; ++r) {
        const long idx = (long)(row0 + r) * N + col;
        float v = acc[mt][nt][r] + bv;
        if (relu) v = fmaxf(v, 0.f);
        if (residB) v += (float)residB[idx];
        if (residF) v += residF[idx];
        if (Cb) Cb[idx] = (bf16)v;
        if (Cf) Cf[idx] = v;
      }
    }
  }
}

// ---------------------------------------------------------------------------
// gemm_bt_split: m97 GEMM (BK=64) over a packed Bt of Ntot columns; epilogue
// splits output into per-1024-column buffers. A0 feeds chunk 0, A1 feeds
// chunks 1,2 (rows limited to m1lim; block-uniform early return).
// ---------------------------------------------------------------------------
struct Out3 {
  bf16* o0; bf16* o1; bf16* o2;
  const float* b0; const float* b1; const float* b2;
};

__global__ __launch_bounds__(256) void gemm_bt_split(
    const bf16* __restrict__ A0, const bf16* __restrict__ A1,
    const bf16* __restrict__ Bt, Out3 so, int m1lim, int K)
{
  __shared__ alignas(16) bf16 As[128 * 64];
  __shared__ alignas(16) bf16 Bs[128 * 64];
  const int tid  = threadIdx.x;
  const int wid  = tid >> 6;
  const int lane = tid & 63;
  const int l15  = lane & 15;
  const int quad = lane >> 4;
  int bm, bn;
  xcd_tile(bm, bn);
  const int wm = (wid & 1) * 64,  wn = (wid >> 1) * 64;

  const int ch = bn >> 10;
  if (ch > 0 && bm >= m1lim) return;
  const bf16* A = (ch == 0) ? A0 : A1;
  bf16* C = (ch == 0) ? so.o0 : (ch == 1 ? so.o1 : so.o2);
  const float* bp = (ch == 0) ? so.b0 : (ch == 1 ? so.b1 : so.b2);

  f32x4 acc[4][4] = {};

  const int srow = tid >> 2;
  const int scol = (tid & 3) * 8;
  const bf16* ag0 = A  + (long)(bm + srow) * K + scol;
  const bf16* ag1 = ag0 + (long)64 * K;
  const bf16* bg0 = Bt + (long)(bn + srow) * K + scol;
  const bf16* bg1 = bg0 + (long)64 * K;
  bf16* lA0 = As + wid * 512;
  bf16* lA1 = As + 2048 + wid * 512;
  bf16* lA2 = As + 4096 + wid * 512;
  bf16* lA3 = As + 6144 + wid * 512;
  bf16* lB0 = Bs + wid * 512;
  bf16* lB1 = Bs + 2048 + wid * 512;
  bf16* lB2 = Bs + 4096 + wid * 512;
  bf16* lB3 = Bs + 6144 + wid * 512;

  for (int k0 = 0; k0 < K; k0 += 64) {
    gll16(ag0 + k0, lA0);
    gll16(ag1 + k0, lA1);
    gll16(ag0 + k0 + 32, lA2);
    gll16(ag1 + k0 + 32, lA3);
    gll16(bg0 + k0, lB0);
    gll16(bg1 + k0, lB1);
    gll16(bg0 + k0 + 32, lB2);
    gll16(bg1 + k0 + 32, lB3);
    __syncthreads();
#pragma unroll
    for (int kk = 0; kk < 2; ++kk) {
      bf16x8 af[4], bfr[4];
#pragma unroll
      for (int i = 0; i < 4; ++i)
        af[i] = *(const bf16x8*)(As + kk * 4096 + (wm + i * 16 + l15) * 32 + quad * 8);
#pragma unroll
      for (int i = 0; i < 4; ++i)
        bfr[i] = *(const bf16x8*)(Bs + kk * 4096 + (wn + i * 16 + l15) * 32 + quad * 8);
#pragma unroll
      for (int mt = 0; mt < 4; ++mt)
#pragma unroll
        for (int nt = 0; nt < 4; ++nt)
          acc[mt][nt] = mfma16(af[mt], bfr[nt], acc[mt][nt]);
    }
    __syncthreads();
  }

#pragma unroll
  for (int nt = 0; nt < 4; ++nt) {
    const int col = bn + wn + nt * 16 + l15;
    const int cc  = col & 1023;
    const float bv = bp[cc];
#pragma unroll
    for (int mt = 0; mt < 4; ++mt) {
      const int row0 = bm + wm + mt * 16 + quad * 4;
#pragma unroll
      for (int r = 0; r < 4; ++r)
        C[(long)(row0 + r) * 1024 + cc] = (bf16)(acc[mt][nt][r] + bv);
    }
  }
}

// ---------------------------------------------------------------------------
// Flash-style self-attention (R11/R12: 512 thr, 128 q-rows, swizzled LDS).
// ---------------------------------------------------------------------------
__global__ __launch_bounds__(512) void attn_self(
    const bf16* __restrict__ Q, const bf16* __restrict__ Km,
    const bf16* __restrict__ Vt, bf16* __restrict__ O)
{
  __shared__ alignas(16) bf16 Ks[16384];
  __shared__ alignas(16) bf16 Vs[16384];
  __shared__ alignas(16) bf16 Ps[8192];      // 8 waves x (2 chunks x 512)
  const int tid  = threadIdx.x;
  const int wid  = tid >> 6;                  // 0..7
  const int lane = tid & 63;
  const int l15  = lane & 15;
  const int quad = lane >> 4;
  const int b = blockIdx.y >> 3, h = blockIdx.y & 7;
  const int q0 = blockIdx.x * 128;

  const int rdoff = l15 * 32 + (((quad ^ ((l15 >> 1) & 3))) << 3);

  const long qb = ((long)(b * 1024 + q0 + wid * 16 + l15)) * 1024 + h * 128 + quad * 8;
  bf16x8 qf[4];
#pragma unroll
  for (int ks = 0; ks < 4; ++ks) qf[ks] = *(const bf16x8*)(Q + qb + ks * 32);

  f32x4 oacc[8] = {};
  float mrow[4], lrow[4];
#pragma unroll
  for (int r = 0; r < 4; ++r) { mrow[r] = -3.0e38f; lrow[r] = 0.f; }

  const long kbase = (long)(b * 1024) * 1024 + h * 128;
  const long vbase = (long)(b * 8 + h) * 128 * 1024;

  const int srow = tid >> 3;        // 0..63
  const int sc8  = (tid & 7) * 8;

  bf16* pw = Ps + wid * 1024;

  for (int t = 0; t < 8; ++t) {
    const int kv0 = t * 128;
    __syncthreads();
#pragma unroll
    for (int dh = 0; dh < 2; ++dh)
#pragma unroll
      for (int kq = 0; kq < 2; ++kq) {
        const int kv = kq * 64 + srow;
        const int d  = dh * 64 + sc8;
        bf16x8 v = *(const bf16x8*)(Km + kbase + (long)(kv0 + kv) * 1024 + d);
        *(bf16x8*)(Ks + (d >> 5) * 4096 + kv * 32 +
                   (((((d & 31) >> 3) ^ ((kv >> 1) & 3))) << 3)) = v;
      }
#pragma unroll
    for (int kh = 0; kh < 2; ++kh)
#pragma unroll
      for (int dq = 0; dq < 2; ++dq) {
        const int d  = dq * 64 + srow;
        const int kv = kh * 64 + sc8;
        bf16x8 v = *(const bf16x8*)(Vt + vbase + (long)d * 1024 + kv0 + kv);
        *(bf16x8*)(Vs + (kv >> 5) * 4096 + d * 32 +
                   (((((kv & 31) >> 3) ^ ((d >> 1) & 3))) << 3)) = v;
      }
    __syncthreads();

    f32x4 sacc[8] = {};
#pragma unroll
    for (int nt = 0; nt < 8; ++nt)
#pragma unroll
      for (int ks = 0; ks < 4; ++ks)
        sacc[nt] = mfma16(qf[ks],
            *(const bf16x8*)(Ks + ks * 4096 + nt * 512 + rdoff),
            sacc[nt]);

    float tm[4];
#pragma unroll
    for (int r = 0; r < 4; ++r) {
      float m = -3.0e38f;
#pragma unroll
      for (int nt = 0; nt < 8; ++nt) m = fmaxf(m, sacc[nt][r]);
      tm[r] = m * SCALE;
    }
#pragma unroll
    for (int off = 8; off; off >>= 1)
#pragma unroll
      for (int r = 0; r < 4; ++r) tm[r] = fmaxf(tm[r], __shfl_xor(tm[r], off));
    float alpha[4], psum[4];
#pragma unroll
    for (int r = 0; r < 4; ++r) {
      const float mnew = fmaxf(mrow[r], tm[r]);
      alpha[r] = __expf(mrow[r] - mnew);
      mrow[r] = mnew;
      psum[r] = 0.f;
    }
#pragma unroll
    for (int nt = 0; nt < 8; ++nt)
#pragma unroll
      for (int r = 0; r < 4; ++r) oacc[nt][r] *= alpha[r];

    // two PV halves, reusing the 2-chunk per-wave P buffer
#pragma unroll
    for (int hs = 0; hs < 2; ++hs) {
#pragma unroll
      for (int n2 = 0; n2 < 4; ++n2) {
        const int nt = hs * 4 + n2;
#pragma unroll
        for (int r = 0; r < 4; ++r) {
          const float p = __expf(sacc[nt][r] * SCALE - mrow[r]);
          psum[r] += p;
          const int prow = quad * 4 + r;
          pw[((nt >> 1) & 1) * 512 + prow * 32 +
             (((((nt & 1) * 2 + (l15 >> 3)) ^ ((prow >> 1) & 3))) << 3) + (l15 & 7)] =
              (bf16)p;
        }
      }
#pragma unroll
      for (int ks2 = 0; ks2 < 2; ++ks2) {
        const bf16x8 pa = *(const bf16x8*)(pw + ks2 * 512 + rdoff);
        const int ksx = hs * 2 + ks2;
#pragma unroll
        for (int nt = 0; nt < 8; ++nt)
          oacc[nt] = mfma16(pa,
              *(const bf16x8*)(Vs + ksx * 4096 + nt * 512 + rdoff),
              oacc[nt]);
      }
    }

#pragma unroll
    for (int off = 8; off; off >>= 1)
#pragma unroll
      for (int r = 0; r < 4; ++r) psum[r] += __shfl_xor(psum[r], off);
#pragma unroll
    for (int r = 0; r < 4; ++r) lrow[r] = lrow[r] * alpha[r] + psum[r];
  }

  float linv[4];
#pragma unroll
  for (int r = 0; r < 4; ++r) linv[r] = 1.f / lrow[r];
#pragma unroll
  for (int nt = 0; nt < 8; ++nt)
#pragma unroll
    for (int r = 0; r < 4; ++r) {
      const int row = q0 + wid * 16 + quad * 4 + r;
      O[((long)(b * 1024 + row)) * 1024 + h * 128 + nt * 16 + l15] =
          (bf16)(oacc[nt][r] * linv[r]);
    }
}

// ---------------------------------------------------------------------------
// gate2: G[z=(b,h)][w][v] = sigmoid(SCALE * CQ.CK^T). Grid (32 wtiles, 64 z).
// ---------------------------------------------------------------------------
__global__ __launch_bounds__(256) void gate2(
    const bf16* __restrict__ CQ, const bf16* __restrict__ CK,
    bf16* __restrict__ gA, bf16* __restrict__ gB)
{
  __shared__ alignas(16) bf16 Ks[16384];      // 4 dchunks x 128 v x 32 d
  __shared__ alignas(16) bf16 Pt[4][1024];    // per-wave 16w x 64v transpose
  const int tid  = threadIdx.x;
  const int wid  = tid >> 6;
  const int lane = tid & 63;
  const int l15  = lane & 15;
  const int quad = lane >> 4;
  const int z = blockIdx.y, b = z >> 3, h = z & 7;
  const int w0 = blockIdx.x * 32;
  const int rsel = wid & 1, vsel = wid >> 1;

  const int rdoff = l15 * 32 + (((quad ^ ((l15 >> 1) & 3))) << 3);

  bf16* Gz = (z < 32) ? (gA + (long)z * 524288) : (gB + (long)(z - 32) * 524288);

  const long qb = ((long)(b * 1024 + w0 + rsel * 16 + l15)) * 1024 + h * 128 + quad * 8;
  bf16x8 qf[4];
#pragma unroll
  for (int ks = 0; ks < 4; ++ks) qf[ks] = *(const bf16x8*)(CQ + qb + ks * 32);

  const int srow = tid >> 3;        // 0..31
  const int sc8  = (tid & 7) * 8;   // 0..56

  for (int vt = 0; vt < 4; ++vt) {
    const int v0 = vt * 128;
    __syncthreads();
#pragma unroll
    for (int i = 0; i < 4; ++i) {
      const int v = i * 32 + srow;
#pragma unroll
      for (int dh = 0; dh < 2; ++dh) {
        const int d = dh * 64 + sc8;
        bf16x8 val = *(const bf16x8*)(CK + ((long)(b * 512 + v0 + v)) * 1024 + h * 128 + d);
        *(bf16x8*)(Ks + (d >> 5) * 4096 + v * 32 +
                   (((((d & 31) >> 3) ^ ((v >> 1) & 3))) << 3)) = val;
      }
    }
    __syncthreads();

    f32x4 sacc[4] = {};
#pragma unroll
    for (int nt = 0; nt < 4; ++nt)
#pragma unroll
      for (int ks = 0; ks < 4; ++ks)
        sacc[nt] = mfma16(qf[ks],
            *(const bf16x8*)(Ks + ks * 4096 + vsel * 2048 + nt * 512 + rdoff),
            sacc[nt]);

#pragma unroll
    for (int nt = 0; nt < 4; ++nt)
#pragma unroll
      for (int r = 0; r < 4; ++r) {
        const float g = 1.f / (1.f + __expf(-sacc[nt][r] * SCALE));
        const int prow = quad * 4 + r;
        const int g0 = nt * 2 + (l15 >> 3);
        Pt[wid][prow * 64 + ((g0 ^ ((prow >> 1) & 3)) << 3) + (l15 & 7)] = (bf16)g;
      }
#pragma unroll
    for (int pass = 0; pass < 2; ++pass) {
      const int f = pass * 512 + lane * 8;
      const int row = f >> 6, col = f & 63;
      const int gl = (lane & 7) ^ ((row >> 1) & 3);
      bf16x8 vv = *(const bf16x8*)(&Pt[wid][row * 64 + gl * 8]);
      *(bf16x8*)(Gz + (long)(w0 + rsel * 16 + row) * 512 + v0 + vsel * 64 + col) = vv;
    }
  }
}

// ---------------------------------------------------------------------------
// reduce_res: blocks [0,4096): attn_out mean over heads (reduce_h path).
// blocks [4096,4608): gemm_res (G[z] @ CVt[z]^T, BK=64). One launch — the
// two consumers of G are independent; mem-bound blocks overlap MFMA blocks.
// ---------------------------------------------------------------------------
__global__ __launch_bounds__(256) void reduce_res(
    const bf16* __restrict__ gA, const bf16* __restrict__ gB,
    const bf16* __restrict__ CVt, float* __restrict__ AOUT,
    bf16* __restrict__ RES)
{
  __shared__ alignas(16) bf16 As[128 * 64];
  __shared__ alignas(16) bf16 Bs[128 * 64];
  const int bid = blockIdx.x;
  const int tid = threadIdx.x;

  if (bid < 4096) {
    const int idx = bid * 256 + tid;  // 1,048,576 total
    const int v4 = idx & 127;
    const int w  = (idx >> 7) & 1023;
    const int b  = idx >> 17;
    float s0 = 0.f, s1 = 0.f, s2 = 0.f, s3 = 0.f;
#pragma unroll
    for (int h = 0; h < 8; ++h) {
      const int z = b * 8 + h;
      const bf16* base = (z < 32) ? (gA + (long)z * 524288) : (gB + (long)(z - 32) * 524288);
      bf16x4 g = *(const bf16x4*)(base + (long)w * 512 + v4 * 4);
      s0 += (float)g[0]; s1 += (float)g[1]; s2 += (float)g[2]; s3 += (float)g[3];
    }
    *(float4*)(AOUT + (long)idx * 4) =
        make_float4(s0 * 0.125f, s1 * 0.125f, s2 * 0.125f, s3 * 0.125f);
    return;
  }

  const int bid2 = bid - 4096;
  const int z = bid2 >> 3, b = z >> 3, h = z & 7;
  const int bm = (bid2 & 7) * 128;
  const int wid  = tid >> 6;
  const int lane = tid & 63;
  const int l15  = lane & 15;
  const int quad = lane >> 4;
  const bf16* A  = (z < 32) ? (gA + (long)z * 524288) : (gB + (long)(z - 32) * 524288);
  const bf16* Bt = CVt + (long)z * 65536;
  const int wm = (wid & 1) * 64, wn = (wid >> 1) * 64;

  f32x4 acc[4][4] = {};

  const int srow = tid >> 2;
  const int scol = (tid & 3) * 8;
  const bf16* ag0 = A  + (long)(bm + srow) * 512 + scol;
  const bf16* ag1 = ag0 + (long)64 * 512;
  const bf16* bg0 = Bt + (long)srow * 512 + scol;
  const bf16* bg1 = bg0 + (long)64 * 512;
  bf16* lA0 = As + wid * 512;
  bf16* lA1 = As + 2048 + wid * 512;
  bf16* lA2 = As + 4096 + wid * 512;
  bf16* lA3 = As + 6144 + wid * 512;
  bf16* lB0 = Bs + wid * 512;
  bf16* lB1 = Bs + 2048 + wid * 512;
  bf16* lB2 = Bs + 4096 + wid * 512;
  bf16* lB3 = Bs + 6144 + wid * 512;

  for (int k0 = 0; k0 < 512; k0 += 64) {
    gll16(ag0 + k0, lA0);
    gll16(ag1 + k0, lA1);
    gll16(ag0 + k0 + 32, lA2);
    gll16(ag1 + k0 + 32, lA3);
    gll16(bg0 + k0, lB0);
    gll16(bg1 + k0, lB1);
    gll16(bg0 + k0 + 32, lB2);
    gll16(bg1 + k0 + 32, lB3);
    __syncthreads();
#pragma unroll
    for (int kk = 0; kk < 2; ++kk) {
      bf16x8 af[4], bfr[4];
#pragma unroll
      for (int i = 0; i < 4; ++i)
        af[i] = *(const bf16x8*)(As + kk * 4096 + (wm + i * 16 + l15) * 32 + quad * 8);
#pragma unroll
      for (int i = 0; i < 4; ++i)
        bfr[i] = *(const bf16x8*)(Bs + kk * 4096 + (wn + i * 16 + l15) * 32 + quad * 8);
#pragma unroll
      for (int mt = 0; mt < 4; ++mt)
#pragma unroll
        for (int nt = 0; nt < 4; ++nt)
          acc[mt][nt] = mfma16(af[mt], bfr[nt], acc[mt][nt]);
    }
    __syncthreads();
  }

#pragma unroll
  for (int nt = 0; nt < 4; ++nt) {
    const int col = h * 128 + wn + nt * 16 + l15;
#pragma unroll
    for (int mt = 0; mt < 4; ++mt) {
      const int row0 = bm + wm + mt * 16 + quad * 4;
#pragma unroll
      for (int r = 0; r < 4; ++r)
        RES[((long)(b * 1024 + row0 + r)) * 1024 + col] = (bf16)acc[mt][nt][r];
    }
  }
}

// ---------------------------------------------------------------------------
// Batched transpose through LDS: T in {float,bf16} -> bf16 out.
// ---------------------------------------------------------------------------
template <typename T>
__global__ __launch_bounds__(256) void transpose_k(
    const T* __restrict__ in, bf16* __restrict__ out,
    int sIR, int sOR, long inStrideB, long inStrideH, long outStrideZ, int H)
{
  __shared__ bf16 t[32][33];
  const int z = blockIdx.z;
  const T* ib = in + (long)(z / H) * inStrideB + (long)(z % H) * inStrideH;
  bf16* ob = out + (long)z * outStrideZ;
  const int r0 = blockIdx.x * 32, c0 = blockIdx.y * 32;
  const int tx = threadIdx.x & 31, ty = threadIdx.x >> 5;
#pragma unroll
  for (int i = 0; i < 32; i += 8)
    t[ty + i][tx] = (bf16)(float)ib[(long)(r0 + ty + i) * sIR + (c0 + tx)];
  __syncthreads();
#pragma unroll
  for (int i = 0; i < 32; i += 8)
    ob[(long)(c0 + ty + i) * sOR + (r0 + tx)] = t[tx][ty + i];
}

// ---------------------------------------------------------------------------
// transpose_w9: z-batched fp32->bf16 transposes of all 9 weight matrices.
// ---------------------------------------------------------------------------
struct TP9 { const float* in[9]; bf16* out[9]; };

__global__ __launch_bounds__(256) void transpose_w9(TP9 p)
{
  __shared__ bf16 t[32][33];
  const int z = blockIdx.z;
  int r0, c0, sIR, sOR;
  if (z < 7) {
    if (blockIdx.y >= 32) return;
    r0 = blockIdx.x * 32; c0 = blockIdx.y * 32; sIR = 1024; sOR = 1024;
  } else if (z == 7) {            // in 1024x2048 -> out 2048x1024
    r0 = blockIdx.x * 32; c0 = blockIdx.y * 32; sIR = 2048; sOR = 1024;
  } else {                        // in 2048x1024 -> out 1024x2048
    r0 = blockIdx.y * 32; c0 = blockIdx.x * 32; sIR = 1024; sOR = 2048;
  }
  const float* ib = p.in[z];
  bf16* ob = p.out[z];
  const int tx = threadIdx.x & 31, ty = threadIdx.x >> 5;
#pragma unroll
  for (int i = 0; i < 32; i += 8)
    t[ty + i][tx] = (bf16)ib[(long)(r0 + ty + i) * sIR + (c0 + tx)];
  __syncthreads();
#pragma unroll
  for (int i = 0; i < 32; i += 8)
    ob[(long)(c0 + ty + i) * sOR + (r0 + tx)] = t[tx][ty + i];
}

// ---------------------------------------------------------------------------
// LayerNorm over D=1024, 1 wave/row. Shared row body.
// ---------------------------------------------------------------------------
__device__ __forceinline__ void load16v(float* d, const bf16* p) {
  bf16x8 a = *(const bf16x8*)p, b2 = *(const bf16x8*)(p + 8);
#pragma unroll
  for (int j = 0; j < 8; ++j) { d[j] = (float)a[j]; d[j + 8] = (float)b2[j]; }
}
__device__ __forceinline__ void load16v(float* d, const float* p) {
#pragma unroll
  for (int j = 0; j < 4; ++j) {
    float4 v = ((const float4*)p)[j];
    d[4*j] = v.x; d[4*j+1] = v.y; d[4*j+2] = v.z; d[4*j+3] = v.w;
  }
}

template <typename TI>
__device__ __forceinline__ void ln_row_body(
    const TI* __restrict__ X, const float* __restrict__ G,
    const float* __restrict__ Bb, bf16* __restrict__ out, long row, int lane)
{
  const int c0 = lane * 16;
  const long base = row * 1024 + c0;
  float a[16];
  load16v(a, X + base);
  float s = 0.f, ss = 0.f;
#pragma unroll
  for (int j = 0; j < 16; ++j) { s += a[j]; ss += a[j] * a[j]; }
#pragma unroll
  for (int off = 32; off; off >>= 1) { s += __shfl_xor(s, off); ss += __shfl_xor(ss, off); }
  const float inv = 1.f / 1024.f;
  const float m = s * inv;
  const float rr = rsqrtf(fmaxf(ss * inv - m * m, 0.f) + 1e-5f);
  bf16x8 o0, o1;
#pragma unroll
  for (int j = 0; j < 16; ++j) {
    float v = (a[j] - m) * rr * G[c0 + j] + Bb[c0 + j];
    if (j < 8) o0[j] = (bf16)v; else o1[j - 8] = (bf16)v;
  }
  *(bf16x8*)(out + base) = o0;
  *(bf16x8*)(out + base + 8) = o1;
}

template <typename TI>
__global__ __launch_bounds__(256) void ln_k(
    const TI* __restrict__ X, const float* __restrict__ G1,
    const float* __restrict__ B1, bf16* __restrict__ out)
{
  const int wid = threadIdx.x >> 6, lane = threadIdx.x & 63;
  ln_row_body<TI>(X, G1, B1, out, (long)blockIdx.x * 4 + wid, lane);
}

// ln_pair: blocks [0,2048) LN 8192 bf16 rows; [2048,3072) LN 4096 f32 rows.
__global__ __launch_bounds__(256) void ln_pair(
    const bf16* __restrict__ Xa, const float* __restrict__ Ga,
    const float* __restrict__ Ba, bf16* __restrict__ outA,
    const float* __restrict__ Xb, const float* __restrict__ Gb,
    const float* __restrict__ Bb, bf16* __restrict__ outB)
{
  const int wid = threadIdx.x >> 6, lane = threadIdx.x & 63;
  const long row = (long)blockIdx.x * 4 + wid;
  if (blockIdx.x < 2048) ln_row_body<bf16>(Xa, Ga, Ba, outA, row, lane);
  else                   ln_row_body<float>(Xb, Gb, Bb, outB, row - 8192, lane);
}

// ln_fuse2: v = LN(X1;G1,B1)+LN(X2;G2,B2); outX = bf16(v); outH = LN(v;G3,B3).
__global__ __launch_bounds__(256) void ln_fuse2(
    const bf16* __restrict__ X1, const float* __restrict__ G1, const float* __restrict__ B1,
    const bf16* __restrict__ X2, const float* __restrict__ G2, const float* __restrict__ B2,
    const float* __restrict__ G3, const float* __restrict__ B3,
    bf16* __restrict__ outX, bf16* __restrict__ outH)
{
  const int wid = threadIdx.x >> 6, lane = threadIdx.x & 63;
  const long row = (long)blockIdx.x * 4 + wid;
  const int c0 = lane * 16;
  const long base = row * 1024 + c0;

  float a[16], b[16];
  load16v(a, X1 + base);
  load16v(b, X2 + base);
  float s1 = 0.f, ss1 = 0.f, s2 = 0.f, ss2 = 0.f;
#pragma unroll
  for (int j = 0; j < 16; ++j) {
    s1 += a[j]; ss1 += a[j] * a[j];
    s2 += b[j]; ss2 += b[j] * b[j];
  }
#pragma unroll
  for (int off = 32; off; off >>= 1) {
    s1 += __shfl_xor(s1, off); ss1 += __shfl_xor(ss1, off);
    s2 += __shfl_xor(s2, off); ss2 += __shfl_xor(ss2, off);
  }
  const float inv = 1.f / 1024.f;
  const float m1 = s1 * inv;
  const float r1 = rsqrtf(fmaxf(ss1 * inv - m1 * m1, 0.f) + 1e-5f);
  const float m2 = s2 * inv;
  const float r2 = rsqrtf(fmaxf(ss2 * inv - m2 * m2, 0.f) + 1e-5f);

  float v[16];
  float s3 = 0.f, ss3 = 0.f;
  bf16x8 o0, o1;
#pragma unroll
  for (int j = 0; j < 16; ++j) {
    v[j] = (a[j] - m1) * r1 * G1[c0 + j] + B1[c0 + j]
         + (b[j] - m2) * r2 * G2[c0 + j] + B2[c0 + j];
    s3 += v[j]; ss3 += v[j] * v[j];
    if (j < 8) o0[j] = (bf16)v[j]; else o1[j - 8] = (bf16)v[j];
  }
  *(bf16x8*)(outX + base) = o0;
  *(bf16x8*)(outX + base + 8) = o1;
#pragma unroll
  for (int off = 32; off; off >>= 1) {
    s3 += __shfl_xor(s3, off); ss3 += __shfl_xor(ss3, off);
  }
  const float m3 = s3 * inv;
  const float r3 = rsqrtf(fmaxf(ss3 * inv - m3 * m3, 0.f) + 1e-5f);
#pragma unroll
  for (int j = 0; j < 16; ++j) {
    float hh = (v[j] - m3) * r3 * G3[c0 + j] + B3[c0 + j];
    if (j < 8) o0[j] = (bf16)hh; else o1[j - 8] = (bf16)hh;
  }
  *(bf16x8*)(outH + base) = o0;
  *(bf16x8*)(outH + base + 8) = o1;
}

// ---------------------------------------------------------------------------
extern "C" void kernel_launch(void* const* d_in, const int* in_sizes, int n_in,
                              void* d_out, int out_size, void* d_ws, size_t ws_size,
                              hipStream_t stream) {
  (void)in_sizes; (void)n_in; (void)out_size; (void)ws_size;

  const float* x   = (const float*)d_in[0];
  const float* y   = (const float*)d_in[1];
  const float* r1g = (const float*)d_in[3];  const float* r1b = (const float*)d_in[4];
  const float* sa_wq = (const float*)d_in[5];  const float* sa_bq = (const float*)d_in[6];
  const float* sa_wk = (const float*)d_in[7];  const float* sa_bk = (const float*)d_in[8];
  const float* sa_wv = (const float*)d_in[9];  const float* sa_bv = (const float*)d_in[10];
  const float* sa_wo = (const float*)d_in[11]; const float* sa_bo = (const float*)d_in[12];
  const float* tn_g = (const float*)d_in[13];  const float* tn_b = (const float*)d_in[14];
  const float* an_g = (const float*)d_in[15];  const float* an_b = (const float*)d_in[16];
  const float* ca_wq = (const float*)d_in[17]; const float* ca_bq = (const float*)d_in[18];
  const float* ca_wk = (const float*)d_in[19]; const float* ca_bk = (const float*)d_in[20];
  const float* ca_wv = (const float*)d_in[21];
  const float* ca_bv = (const float*)d_in[22];
  const float* n1g = (const float*)d_in[23];   const float* n1b = (const float*)d_in[24];
  const float* n2g = (const float*)d_in[25];   const float* n2b = (const float*)d_in[26];
  const float* r2g = (const float*)d_in[27];   const float* r2b = (const float*)d_in[28];
  const float* fw1 = (const float*)d_in[29];   const float* fb1 = (const float*)d_in[30];
  const float* fw2 = (const float*)d_in[31];   const float* fb2 = (const float*)d_in[32];

  // ---- static 150MB lifetime-planned workspace ----
  char* wsb = (char*)d_ws;
  const size_t MBy = 1048576;
  bf16* fw1T = (bf16*)(wsb + 0 * MBy);
  bf16* fw2T = (bf16*)(wsb + 4 * MBy);
  bf16* wqT  = (bf16*)(wsb + 8 * MBy);    // wq|wk|wv contiguous (3x2MB)
  bf16* wkT  = (bf16*)(wsb + 10 * MBy);
  bf16* wvT  = (bf16*)(wsb + 12 * MBy);
  bf16* woT  = (bf16*)(wsb + 14 * MBy);
  bf16* cwqT = (bf16*)(wsb + 16 * MBy);   // cwq|cwk|cwv contiguous (3x2MB)
  bf16* cwkT = (bf16*)(wsb + 18 * MBy);
  bf16* cwvT = (bf16*)(wsb + 20 * MBy);
  bf16* h_bf = (bf16*)(wsb + 22 * MBy);
  bf16* t_bf = h_bf;  bf16* h2_bf = h_bf;
  bf16* q_bf = (bf16*)(wsb + 38 * MBy);
  bf16* av_bf = q_bf;
  bf16* gA = (bf16*)(wsb + 22 * MBy);           // z 0..31 (h/t/q/av dead)
  bf16* k_bf = (bf16*)(wsb + 54 * MBy);
  bf16* cq_bf = k_bf;  bf16* res_b = k_bf;
  bf16* v_bf = (bf16*)(wsb + 70 * MBy);
  bf16* ck_bf = v_bf;
  bf16* cv_bf = (bf16*)(wsb + 78 * MBy);
  bf16* x2_b  = v_bf;
  bf16* vT  = (bf16*)(wsb + 86 * MBy);
  bf16* cvT = vT;
  bf16* o_bf = (bf16*)(wsb + 102 * MBy);
  bf16* x1_b = o_bf;
  bf16* gB  = (bf16*)(wsb + 118 * MBy);          // z 32..63
  bf16* ffh = gB;

  float* out_x    = (float*)d_out;
  float* out_attn = out_x + 8 * 1024 * 1024;

  const dim3 blk(256);

  TP9 tp;
  tp.in[0] = sa_wq; tp.out[0] = wqT;
  tp.in[1] = sa_wk; tp.out[1] = wkT;
  tp.in[2] = sa_wv; tp.out[2] = wvT;
  tp.in[3] = sa_wo; tp.out[3] = woT;
  tp.in[4] = ca_wq; tp.out[4] = cwqT;
  tp.in[5] = ca_wk; tp.out[5] = cwkT;
  tp.in[6] = ca_wv; tp.out[6] = cwvT;
  tp.in[7] = fw1;   tp.out[7] = fw1T;
  tp.in[8] = fw2;   tp.out[8] = fw2T;
  transpose_w9<<<dim3(32, 64, 9), blk, 0, stream>>>(tp);

  ln_k<float><<<dim3(2048), blk, 0, stream>>>(x, r1g, r1b, h_bf);

  // fused QKV projection: packed weights wqT|wkT|wvT, split outputs
  Out3 oqkv = { q_bf, k_bf, v_bf, sa_bq, sa_bk, sa_bv };
  gemm_bt_split<<<dim3(24, 64), blk, 0, stream>>>(h_bf, h_bf, wqT, oqkv, 8192, 1024);

  transpose_k<bf16><<<dim3(32, 4, 64), blk, 0, stream>>>(v_bf, vT, 1024, 1024,
      (long)1024 * 1024, 128, (long)128 * 1024, 8);

  attn_self<<<dim3(8, 64), dim3(512), 0, stream>>>(q_bf, k_bf, vT, o_bf);

  gemm_bt<<<dim3(8, 64), blk, 0, stream>>>(o_bf, woT, sa_bo, nullptr, x, x1_b, nullptr, 8192, 1024, 1024, 0);

  // t = LN(x1); av = LN(y) in one launch
  ln_pair<<<dim3(3072), blk, 0, stream>>>(x1_b, tn_g, tn_b, t_bf, y, an_g, an_b, av_bf);

  // fused CQ + CK + CV projection: packed weights cwqT|cwkT|cwvT; chunk0
  // uses A=t_bf (M=8192), chunks 1,2 use A=av_bf (M=4096, early return).
  Out3 ocq = { cq_bf, ck_bf, cv_bf, ca_bq, ca_bk, ca_bv };
  gemm_bt_split<<<dim3(24, 64), blk, 0, stream>>>(t_bf, av_bf, cwqT, ocq, 4096, 1024);

  transpose_k<bf16><<<dim3(16, 4, 64), blk, 0, stream>>>(cv_bf, cvT, 1024, 512,
      (long)512 * 1024, 128, (long)128 * 512, 8);

  // gate (per-head blocks) -> G; then attn_out mean + res GEMM in one launch
  gate2<<<dim3(32, 64), blk, 0, stream>>>(cq_bf, ck_bf, gA, gB);
  reduce_res<<<dim3(4608), blk, 0, stream>>>(gA, gB, cvT, out_attn, res_b);

  // x2 = LN(x1)+LN(res); h2 = LN(x2) in one launch
  ln_fuse2<<<dim3(2048), blk, 0, stream>>>(x1_b, n1g, n1b, res_b, n2g, n2b,
                                           r2g, r2b, x2_b, h2_bf);

  gemm_bt<<<dim3(16, 64), blk, 0, stream>>>(h2_bf, fw1T, fb1, nullptr, nullptr, ffh, nullptr, 8192, 2048, 1024, 1);
  gemm_bt<<<dim3(8, 64), blk, 0, stream>>>(ffh, fw2T, fb2, x2_b, nullptr, nullptr, out_x, 8192, 1024, 2048, 0);
}

// Round 9
// 655.323 us; speedup vs baseline: 1.4783x; 1.0164x over previous
//
#include <hip/hip_runtime.h>

// ---------------------------------------------------------------------------
// CrossDecoderLayer on MI355X (gfx950). External I/O fp32; internal bf16
// MFMA, fp32 accumulate. B=8, W=1024, V=512, D=1024, H=8, DK=128.
// R7 : XOR-swizzle attn/gate2 LDS. R10/R11: fusion + 512-thr attn.
// R12: T1 XCD swizzle GEMMs. R13: BK=64 GEMMs + merges (666us).
// R14: attn grid (64,8) -> all q-tiles of a (b,h) on one XCD (K/V L2-res);
//      K/V reg prefetch (32 VGPR on 80 base, fits 128 cap; R9's spill was
//      64-on-116); gate2 z-grouped + reduce_res z-remap (G same-XCD);
//      ln(x) folded into transpose launch (14 dispatches).
// (R15 = R14 resubmitted: previous round hit GPUAcquisitionTimeout, no data.)
// ---------------------------------------------------------------------------

typedef __bf16 bf16;
typedef bf16  bf16x4 __attribute__((ext_vector_type(4)));
typedef bf16  bf16x8 __attribute__((ext_vector_type(8)));
typedef float f32x4  __attribute__((ext_vector_type(4)));

#define SCALE 0.08838834764831845f  // 1/sqrt(128)

__device__ __forceinline__ f32x4 mfma16(bf16x8 a, bf16x8 b, f32x4 c) {
  return __builtin_amdgcn_mfma_f32_16x16x32_bf16(a, b, c, 0, 0, 0);
}

__device__ __forceinline__ void gll16(const bf16* g, bf16* l) {
  __builtin_amdgcn_global_load_lds(
      (__attribute__((address_space(1))) void*)(void*)g,
      (__attribute__((address_space(3))) void*)(void*)l, 16, 0, 0);
}

// XCD-aware bijective block swizzle (T1). Requires nwg % 8 == 0.
__device__ __forceinline__ void xcd_tile(int& bm, int& bn) {
  const int nx = gridDim.x;
  const int nwg = nx * gridDim.y;
  int bid = blockIdx.y * nx + blockIdx.x;
  const int cpx = nwg >> 3;
  bid = (bid & 7) * cpx + (bid >> 3);
  bn = (bid % nx) * 128;
  bm = (bid / nx) * 128;
}

// ---------------------------------------------------------------------------
// LayerNorm helpers (used by ln kernels and the merged transpose launch).
// ---------------------------------------------------------------------------
__device__ __forceinline__ void load16v(float* d, const bf16* p) {
  bf16x8 a = *(const bf16x8*)p, b2 = *(const bf16x8*)(p + 8);
#pragma unroll
  for (int j = 0; j < 8; ++j) { d[j] = (float)a[j]; d[j + 8] = (float)b2[j]; }
}
__device__ __forceinline__ void load16v(float* d, const float* p) {
#pragma unroll
  for (int j = 0; j < 4; ++j) {
    float4 v = ((const float4*)p)[j];
    d[4*j] = v.x; d[4*j+1] = v.y; d[4*j+2] = v.z; d[4*j+3] = v.w;
  }
}

template <typename TI>
__device__ __forceinline__ void ln_row_body(
    const TI* __restrict__ X, const float* __restrict__ G,
    const float* __restrict__ Bb, bf16* __restrict__ out, long row, int lane)
{
  const int c0 = lane * 16;
  const long base = row * 1024 + c0;
  float a[16];
  load16v(a, X + base);
  float s = 0.f, ss = 0.f;
#pragma unroll
  for (int j = 0; j < 16; ++j) { s += a[j]; ss += a[j] * a[j]; }
#pragma unroll
  for (int off = 32; off; off >>= 1) { s += __shfl_xor(s, off); ss += __shfl_xor(ss, off); }
  const float inv = 1.f / 1024.f;
  const float m = s * inv;
  const float rr = rsqrtf(fmaxf(ss * inv - m * m, 0.f) + 1e-5f);
  bf16x8 o0, o1;
#pragma unroll
  for (int j = 0; j < 16; ++j) {
    float v = (a[j] - m) * rr * G[c0 + j] + Bb[c0 + j];
    if (j < 8) o0[j] = (bf16)v; else o1[j - 8] = (bf16)v;
  }
  *(bf16x8*)(out + base) = o0;
  *(bf16x8*)(out + base + 8) = o1;
}

// ---------------------------------------------------------------------------
// GEMM: C = epi(A[M,K] @ Bt[N,K]^T + bias [+residF]), 128x128 tile, BK=64
// (two 32-col LDS chunks), 4 waves x (64x64), global_load_lds staging.
// ---------------------------------------------------------------------------
__global__ __launch_bounds__(256) void gemm_bt(
    const bf16* __restrict__ A, const bf16* __restrict__ Bt,
    const float* __restrict__ bias,
    const bf16* __restrict__ residB, const float* __restrict__ residF,
    bf16* __restrict__ Cb, float* __restrict__ Cf,
    int M, int N, int K, int relu)
{
  __shared__ alignas(16) bf16 As[128 * 64];   // [2 chunks][128][32]
  __shared__ alignas(16) bf16 Bs[128 * 64];
  const int tid  = threadIdx.x;
  const int wid  = tid >> 6;
  const int lane = tid & 63;
  const int l15  = lane & 15;
  const int quad = lane >> 4;
  int bm, bn;
  xcd_tile(bm, bn);
  const int wm = (wid & 1) * 64,  wn = (wid >> 1) * 64;

  f32x4 acc[4][4] = {};

  const int srow = tid >> 2;
  const int scol = (tid & 3) * 8;
  const bf16* ag0 = A  + (long)(bm + srow) * K + scol;
  const bf16* ag1 = ag0 + (long)64 * K;
  const bf16* bg0 = Bt + (long)(bn + srow) * K + scol;
  const bf16* bg1 = bg0 + (long)64 * K;
  bf16* lA0 = As + wid * 512;
  bf16* lA1 = As + 2048 + wid * 512;
  bf16* lA2 = As + 4096 + wid * 512;
  bf16* lA3 = As + 6144 + wid * 512;
  bf16* lB0 = Bs + wid * 512;
  bf16* lB1 = Bs + 2048 + wid * 512;
  bf16* lB2 = Bs + 4096 + wid * 512;
  bf16* lB3 = Bs + 6144 + wid * 512;

  for (int k0 = 0; k0 < K; k0 += 64) {
    gll16(ag0 + k0, lA0);
    gll16(ag1 + k0, lA1);
    gll16(ag0 + k0 + 32, lA2);
    gll16(ag1 + k0 + 32, lA3);
    gll16(bg0 + k0, lB0);
    gll16(bg1 + k0, lB1);
    gll16(bg0 + k0 + 32, lB2);
    gll16(bg1 + k0 + 32, lB3);
    __syncthreads();
#pragma unroll
    for (int kk = 0; kk < 2; ++kk) {
      bf16x8 af[4], bfr[4];
#pragma unroll
      for (int i = 0; i < 4; ++i)
        af[i] = *(const bf16x8*)(As + kk * 4096 + (wm + i * 16 + l15) * 32 + quad * 8);
#pragma unroll
      for (int i = 0; i < 4; ++i)
        bfr[i] = *(const bf16x8*)(Bs + kk * 4096 + (wn + i * 16 + l15) * 32 + quad * 8);
#pragma unroll
      for (int mt = 0; mt < 4; ++mt)
#pragma unroll
        for (int nt = 0; nt < 4; ++nt)
          acc[mt][nt] = mfma16(af[mt], bfr[nt], acc[mt][nt]);
    }
    __syncthreads();
  }

#pragma unroll
  for (int nt = 0; nt < 4; ++nt) {
    const int col = bn + wn + nt * 16 + l15;
    const float bv = bias ? bias[col] : 0.f;
#pragma unroll
    for (int mt = 0; mt < 4; ++mt) {
      const int row0 = bm + wm + mt * 16 + quad * 4;
#pragma unroll
      for (int r = 0; r < 4; ++r) {
        const long idx = (long)(row0 + r) * N + col;
        float v = acc[mt][nt][r] + bv;
        if (relu) v = fmaxf(v, 0.f);
        if (residB) v += (float)residB[idx];
        if (residF) v += residF[idx];
        if (Cb) Cb[idx] = (bf16)v;
        if (Cf) Cf[idx] = v;
      }
    }
  }
}

// ---------------------------------------------------------------------------
// gemm_bt_split: m97 GEMM (BK=64) over a packed Bt; epilogue splits output
// into per-1024-column buffers. A0 feeds chunk 0, A1 feeds chunks 1,2.
// ---------------------------------------------------------------------------
struct Out3 {
  bf16* o0; bf16* o1; bf16* o2;
  const float* b0; const float* b1; const float* b2;
};

__global__ __launch_bounds__(256) void gemm_bt_split(
    const bf16* __restrict__ A0, const bf16* __restrict__ A1,
    const bf16* __restrict__ Bt, Out3 so, int m1lim, int K)
{
  __shared__ alignas(16) bf16 As[128 * 64];
  __shared__ alignas(16) bf16 Bs[128 * 64];
  const int tid  = threadIdx.x;
  const int wid  = tid >> 6;
  const int lane = tid & 63;
  const int l15  = lane & 15;
  const int quad = lane >> 4;
  int bm, bn;
  xcd_tile(bm, bn);
  const int wm = (wid & 1) * 64,  wn = (wid >> 1) * 64;

  const int ch = bn >> 10;
  if (ch > 0 && bm >= m1lim) return;
  const bf16* A = (ch == 0) ? A0 : A1;
  bf16* C = (ch == 0) ? so.o0 : (ch == 1 ? so.o1 : so.o2);
  const float* bp = (ch == 0) ? so.b0 : (ch == 1 ? so.b1 : so.b2);

  f32x4 acc[4][4] = {};

  const int srow = tid >> 2;
  const int scol = (tid & 3) * 8;
  const bf16* ag0 = A  + (long)(bm + srow) * K + scol;
  const bf16* ag1 = ag0 + (long)64 * K;
  const bf16* bg0 = Bt + (long)(bn + srow) * K + scol;
  const bf16* bg1 = bg0 + (long)64 * K;
  bf16* lA0 = As + wid * 512;
  bf16* lA1 = As + 2048 + wid * 512;
  bf16* lA2 = As + 4096 + wid * 512;
  bf16* lA3 = As + 6144 + wid * 512;
  bf16* lB0 = Bs + wid * 512;
  bf16* lB1 = Bs + 2048 + wid * 512;
  bf16* lB2 = Bs + 4096 + wid * 512;
  bf16* lB3 = Bs + 6144 + wid * 512;

  for (int k0 = 0; k0 < K; k0 += 64) {
    gll16(ag0 + k0, lA0);
    gll16(ag1 + k0, lA1);
    gll16(ag0 + k0 + 32, lA2);
    gll16(ag1 + k0 + 32, lA3);
    gll16(bg0 + k0, lB0);
    gll16(bg1 + k0, lB1);
    gll16(bg0 + k0 + 32, lB2);
    gll16(bg1 + k0 + 32, lB3);
    __syncthreads();
#pragma unroll
    for (int kk = 0; kk < 2; ++kk) {
      bf16x8 af[4], bfr[4];
#pragma unroll
      for (int i = 0; i < 4; ++i)
        af[i] = *(const bf16x8*)(As + kk * 4096 + (wm + i * 16 + l15) * 32 + quad * 8);
#pragma unroll
      for (int i = 0; i < 4; ++i)
        bfr[i] = *(const bf16x8*)(Bs + kk * 4096 + (wn + i * 16 + l15) * 32 + quad * 8);
#pragma unroll
      for (int mt = 0; mt < 4; ++mt)
#pragma unroll
        for (int nt = 0; nt < 4; ++nt)
          acc[mt][nt] = mfma16(af[mt], bfr[nt], acc[mt][nt]);
    }
    __syncthreads();
  }

#pragma unroll
  for (int nt = 0; nt < 4; ++nt) {
    const int col = bn + wn + nt * 16 + l15;
    const int cc  = col & 1023;
    const float bv = bp[cc];
#pragma unroll
    for (int mt = 0; mt < 4; ++mt) {
      const int row0 = bm + wm + mt * 16 + quad * 4;
#pragma unroll
      for (int r = 0; r < 4; ++r)
        C[(long)(row0 + r) * 1024 + cc] = (bf16)(acc[mt][nt][r] + bv);
    }
  }
}

// ---------------------------------------------------------------------------
// Flash-style self-attention. R14: grid (64 z, 8 qt) -> linear id ≡ z mod 8,
// so all 8 q-tiles of one (b,h) share an XCD (K/V = 4MB = L2). K/V register
// prefetch (single 8x bf16x8 set = 32 VGPR on the 80-VGPR base): issue next
// tile's loads right after the post-stage barrier; they fly under compute.
// ---------------------------------------------------------------------------
__global__ __launch_bounds__(512) void attn_self(
    const bf16* __restrict__ Q, const bf16* __restrict__ Km,
    const bf16* __restrict__ Vt, bf16* __restrict__ O)
{
  __shared__ alignas(16) bf16 Ks[16384];
  __shared__ alignas(16) bf16 Vs[16384];
  __shared__ alignas(16) bf16 Ps[8192];      // 8 waves x (2 chunks x 512)
  const int tid  = threadIdx.x;
  const int wid  = tid >> 6;                  // 0..7
  const int lane = tid & 63;
  const int l15  = lane & 15;
  const int quad = lane >> 4;
  const int z = blockIdx.x;                   // (b,h) — XCD-grouped
  const int b = z >> 3, h = z & 7;
  const int q0 = blockIdx.y * 128;

  const int rdoff = l15 * 32 + (((quad ^ ((l15 >> 1) & 3))) << 3);

  const long qb = ((long)(b * 1024 + q0 + wid * 16 + l15)) * 1024 + h * 128 + quad * 8;
  bf16x8 qf[4];
#pragma unroll
  for (int ks = 0; ks < 4; ++ks) qf[ks] = *(const bf16x8*)(Q + qb + ks * 32);

  f32x4 oacc[8] = {};
  float mrow[4], lrow[4];
#pragma unroll
  for (int r = 0; r < 4; ++r) { mrow[r] = -3.0e38f; lrow[r] = 0.f; }

  const long kbase = (long)(b * 1024) * 1024 + h * 128;
  const long vbase = (long)(b * 8 + h) * 128 * 1024;

  const int srow = tid >> 3;        // 0..63
  const int sc8  = (tid & 7) * 8;

  bf16* pw = Ps + wid * 1024;

  // K/V prefetch registers (4 + 4 x bf16x8 = 32 VGPR)
  bf16x8 kr[4], vr[4];
#pragma unroll
  for (int dh = 0; dh < 2; ++dh)
#pragma unroll
    for (int kq = 0; kq < 2; ++kq)
      kr[dh * 2 + kq] = *(const bf16x8*)(
          Km + kbase + (long)(kq * 64 + srow) * 1024 + dh * 64 + sc8);
#pragma unroll
  for (int kh = 0; kh < 2; ++kh)
#pragma unroll
    for (int dq = 0; dq < 2; ++dq)
      vr[kh * 2 + dq] = *(const bf16x8*)(
          Vt + vbase + (long)(dq * 64 + srow) * 1024 + kh * 64 + sc8);

  for (int t = 0; t < 8; ++t) {
    __syncthreads();                // prev tile's Ks/Vs reads done
#pragma unroll
    for (int dh = 0; dh < 2; ++dh)
#pragma unroll
      for (int kq = 0; kq < 2; ++kq) {
        const int kv = kq * 64 + srow;
        const int d  = dh * 64 + sc8;
        *(bf16x8*)(Ks + (d >> 5) * 4096 + kv * 32 +
                   ((((d & 31) >> 3) ^ ((kv >> 1) & 3)) << 3)) = kr[dh * 2 + kq];
      }
#pragma unroll
    for (int kh = 0; kh < 2; ++kh)
#pragma unroll
      for (int dq = 0; dq < 2; ++dq) {
        const int d  = dq * 64 + srow;
        const int kv = kh * 64 + sc8;
        *(bf16x8*)(Vs + (kv >> 5) * 4096 + d * 32 +
                   ((((kv & 31) >> 3) ^ ((d >> 1) & 3)) << 3)) = vr[kh * 2 + dq];
      }
    __syncthreads();

    if (t < 7) {                    // issue next tile's loads under compute
      const int kn = (t + 1) * 128;
#pragma unroll
      for (int dh = 0; dh < 2; ++dh)
#pragma unroll
        for (int kq = 0; kq < 2; ++kq)
          kr[dh * 2 + kq] = *(const bf16x8*)(
              Km + kbase + (long)(kn + kq * 64 + srow) * 1024 + dh * 64 + sc8);
#pragma unroll
      for (int kh = 0; kh < 2; ++kh)
#pragma unroll
        for (int dq = 0; dq < 2; ++dq)
          vr[kh * 2 + dq] = *(const bf16x8*)(
              Vt + vbase + (long)(dq * 64 + srow) * 1024 + kn + kh * 64 + sc8);
    }

    f32x4 sacc[8] = {};
#pragma unroll
    for (int nt = 0; nt < 8; ++nt)
#pragma unroll
      for (int ks = 0; ks < 4; ++ks)
        sacc[nt] = mfma16(qf[ks],
            *(const bf16x8*)(Ks + ks * 4096 + nt * 512 + rdoff),
            sacc[nt]);

    float tm[4];
#pragma unroll
    for (int r = 0; r < 4; ++r) {
      float m = -3.0e38f;
#pragma unroll
      for (int nt = 0; nt < 8; ++nt) m = fmaxf(m, sacc[nt][r]);
      tm[r] = m * SCALE;
    }
#pragma unroll
    for (int off = 8; off; off >>= 1)
#pragma unroll
      for (int r = 0; r < 4; ++r) tm[r] = fmaxf(tm[r], __shfl_xor(tm[r], off));
    float alpha[4], psum[4];
#pragma unroll
    for (int r = 0; r < 4; ++r) {
      const float mnew = fmaxf(mrow[r], tm[r]);
      alpha[r] = __expf(mrow[r] - mnew);
      mrow[r] = mnew;
      psum[r] = 0.f;
    }
#pragma unroll
    for (int nt = 0; nt < 8; ++nt)
#pragma unroll
      for (int r = 0; r < 4; ++r) oacc[nt][r] *= alpha[r];

    // two PV halves, reusing the 2-chunk per-wave P buffer
#pragma unroll
    for (int hs = 0; hs < 2; ++hs) {
#pragma unroll
      for (int n2 = 0; n2 < 4; ++n2) {
        const int nt = hs * 4 + n2;
#pragma unroll
        for (int r = 0; r < 4; ++r) {
          const float p = __expf(sacc[nt][r] * SCALE - mrow[r]);
          psum[r] += p;
          const int prow = quad * 4 + r;
          pw[((nt >> 1) & 1) * 512 + prow * 32 +
             (((((nt & 1) * 2 + (l15 >> 3)) ^ ((prow >> 1) & 3))) << 3) + (l15 & 7)] =
              (bf16)p;
        }
      }
#pragma unroll
      for (int ks2 = 0; ks2 < 2; ++ks2) {
        const bf16x8 pa = *(const bf16x8*)(pw + ks2 * 512 + rdoff);
        const int ksx = hs * 2 + ks2;
#pragma unroll
        for (int nt = 0; nt < 8; ++nt)
          oacc[nt] = mfma16(pa,
              *(const bf16x8*)(Vs + ksx * 4096 + nt * 512 + rdoff),
              oacc[nt]);
      }
    }

#pragma unroll
    for (int off = 8; off; off >>= 1)
#pragma unroll
      for (int r = 0; r < 4; ++r) psum[r] += __shfl_xor(psum[r], off);
#pragma unroll
    for (int r = 0; r < 4; ++r) lrow[r] = lrow[r] * alpha[r] + psum[r];
  }

  float linv[4];
#pragma unroll
  for (int r = 0; r < 4; ++r) linv[r] = 1.f / lrow[r];
#pragma unroll
  for (int nt = 0; nt < 8; ++nt)
#pragma unroll
    for (int r = 0; r < 4; ++r) {
      const int row = q0 + wid * 16 + quad * 4 + r;
      O[((long)(b * 1024 + row)) * 1024 + h * 128 + nt * 16 + l15] =
          (bf16)(oacc[nt][r] * linv[r]);
    }
}

// ---------------------------------------------------------------------------
// gate2: G[z=(b,h)][w][v] = sigmoid(SCALE * CQ.CK^T). R14: grid (64 z,
// 32 wtiles) -> XCD = z%8, so CK[z] is fetched once per XCD and G[z] lands
// in that XCD's L2 for reduce_res.
// ---------------------------------------------------------------------------
__global__ __launch_bounds__(256) void gate2(
    const bf16* __restrict__ CQ, const bf16* __restrict__ CK,
    bf16* __restrict__ gA, bf16* __restrict__ gB)
{
  __shared__ alignas(16) bf16 Ks[16384];      // 4 dchunks x 128 v x 32 d
  __shared__ alignas(16) bf16 Pt[4][1024];    // per-wave 16w x 64v transpose
  const int tid  = threadIdx.x;
  const int wid  = tid >> 6;
  const int lane = tid & 63;
  const int l15  = lane & 15;
  const int quad = lane >> 4;
  const int z = blockIdx.x, b = z >> 3, h = z & 7;
  const int w0 = blockIdx.y * 32;
  const int rsel = wid & 1, vsel = wid >> 1;

  const int rdoff = l15 * 32 + (((quad ^ ((l15 >> 1) & 3))) << 3);

  bf16* Gz = (z < 32) ? (gA + (long)z * 524288) : (gB + (long)(z - 32) * 524288);

  const long qb = ((long)(b * 1024 + w0 + rsel * 16 + l15)) * 1024 + h * 128 + quad * 8;
  bf16x8 qf[4];
#pragma unroll
  for (int ks = 0; ks < 4; ++ks) qf[ks] = *(const bf16x8*)(CQ + qb + ks * 32);

  const int srow = tid >> 3;        // 0..31
  const int sc8  = (tid & 7) * 8;   // 0..56

  for (int vt = 0; vt < 4; ++vt) {
    const int v0 = vt * 128;
    __syncthreads();
#pragma unroll
    for (int i = 0; i < 4; ++i) {
      const int v = i * 32 + srow;
#pragma unroll
      for (int dh = 0; dh < 2; ++dh) {
        const int d = dh * 64 + sc8;
        bf16x8 val = *(const bf16x8*)(CK + ((long)(b * 512 + v0 + v)) * 1024 + h * 128 + d);
        *(bf16x8*)(Ks + (d >> 5) * 4096 + v * 32 +
                   (((((d & 31) >> 3) ^ ((v >> 1) & 3))) << 3)) = val;
      }
    }
    __syncthreads();

    f32x4 sacc[4] = {};
#pragma unroll
    for (int nt = 0; nt < 4; ++nt)
#pragma unroll
      for (int ks = 0; ks < 4; ++ks)
        sacc[nt] = mfma16(qf[ks],
            *(const bf16x8*)(Ks + ks * 4096 + vsel * 2048 + nt * 512 + rdoff),
            sacc[nt]);

#pragma unroll
    for (int nt = 0; nt < 4; ++nt)
#pragma unroll
      for (int r = 0; r < 4; ++r) {
        const float g = 1.f / (1.f + __expf(-sacc[nt][r] * SCALE));
        const int prow = quad * 4 + r;
        const int g0 = nt * 2 + (l15 >> 3);
        Pt[wid][prow * 64 + ((g0 ^ ((prow >> 1) & 3)) << 3) + (l15 & 7)] = (bf16)g;
      }
#pragma unroll
    for (int pass = 0; pass < 2; ++pass) {
      const int f = pass * 512 + lane * 8;
      const int row = f >> 6, col = f & 63;
      const int gl = (lane & 7) ^ ((row >> 1) & 3);
      bf16x8 vv = *(const bf16x8*)(&Pt[wid][row * 64 + gl * 8]);
      *(bf16x8*)(Gz + (long)(w0 + rsel * 16 + row) * 512 + v0 + vsel * 64 + col) = vv;
    }
  }
}

// ---------------------------------------------------------------------------
// reduce_res: blocks [0,4096): attn_out mean over heads.
// blocks [4096,4608): gemm_res; z = bid2 & 63 so XCD = z%8 matches gate2's
// G[z] placement (same-XCD L2 read).
// ---------------------------------------------------------------------------
__global__ __launch_bounds__(256) void reduce_res(
    const bf16* __restrict__ gA, const bf16* __restrict__ gB,
    const bf16* __restrict__ CVt, float* __restrict__ AOUT,
    bf16* __restrict__ RES)
{
  __shared__ alignas(16) bf16 As[128 * 64];
  __shared__ alignas(16) bf16 Bs[128 * 64];
  const int bid = blockIdx.x;
  const int tid = threadIdx.x;

  if (bid < 4096) {
    const int idx = bid * 256 + tid;  // 1,048,576 total
    const int v4 = idx & 127;
    const int w  = (idx >> 7) & 1023;
    const int b  = idx >> 17;
    float s0 = 0.f, s1 = 0.f, s2 = 0.f, s3 = 0.f;
#pragma unroll
    for (int h = 0; h < 8; ++h) {
      const int z = b * 8 + h;
      const bf16* base = (z < 32) ? (gA + (long)z * 524288) : (gB + (long)(z - 32) * 524288);
      bf16x4 g = *(const bf16x4*)(base + (long)w * 512 + v4 * 4);
      s0 += (float)g[0]; s1 += (float)g[1]; s2 += (float)g[2]; s3 += (float)g[3];
    }
    *(float4*)(AOUT + (long)idx * 4) =
        make_float4(s0 * 0.125f, s1 * 0.125f, s2 * 0.125f, s3 * 0.125f);
    return;
  }

  const int bid2 = bid - 4096;
  const int z = bid2 & 63, b = z >> 3, h = z & 7;   // XCD = bid2%8 = z%8
  const int bm = (bid2 >> 6) * 128;
  const int wid  = tid >> 6;
  const int lane = tid & 63;
  const int l15  = lane & 15;
  const int quad = lane >> 4;
  const bf16* A  = (z < 32) ? (gA + (long)z * 524288) : (gB + (long)(z - 32) * 524288);
  const bf16* Bt = CVt + (long)z * 65536;
  const int wm = (wid & 1) * 64, wn = (wid >> 1) * 64;

  f32x4 acc[4][4] = {};

  const int srow = tid >> 2;
  const int scol = (tid & 3) * 8;
  const bf16* ag0 = A  + (long)(bm + srow) * 512 + scol;
  const bf16* ag1 = ag0 + (long)64 * 512;
  const bf16* bg0 = Bt + (long)srow * 512 + scol;
  const bf16* bg1 = bg0 + (long)64 * 512;
  bf16* lA0 = As + wid * 512;
  bf16* lA1 = As + 2048 + wid * 512;
  bf16* lA2 = As + 4096 + wid * 512;
  bf16* lA3 = As + 6144 + wid * 512;
  bf16* lB0 = Bs + wid * 512;
  bf16* lB1 = Bs + 2048 + wid * 512;
  bf16* lB2 = Bs + 4096 + wid * 512;
  bf16* lB3 = Bs + 6144 + wid * 512;

  for (int k0 = 0; k0 < 512; k0 += 64) {
    gll16(ag0 + k0, lA0);
    gll16(ag1 + k0, lA1);
    gll16(ag0 + k0 + 32, lA2);
    gll16(ag1 + k0 + 32, lA3);
    gll16(bg0 + k0, lB0);
    gll16(bg1 + k0, lB1);
    gll16(bg0 + k0 + 32, lB2);
    gll16(bg1 + k0 + 32, lB3);
    __syncthreads();
#pragma unroll
    for (int kk = 0; kk < 2; ++kk) {
      bf16x8 af[4], bfr[4];
#pragma unroll
      for (int i = 0; i < 4; ++i)
        af[i] = *(const bf16x8*)(As + kk * 4096 + (wm + i * 16 + l15) * 32 + quad * 8);
#pragma unroll
      for (int i = 0; i < 4; ++i)
        bfr[i] = *(const bf16x8*)(Bs + kk * 4096 + (wn + i * 16 + l15) * 32 + quad * 8);
#pragma unroll
      for (int mt = 0; mt < 4; ++mt)
#pragma unroll
        for (int nt = 0; nt < 4; ++nt)
          acc[mt][nt] = mfma16(af[mt], bfr[nt], acc[mt][nt]);
    }
    __syncthreads();
  }

#pragma unroll
  for (int nt = 0; nt < 4; ++nt) {
    const int col = h * 128 + wn + nt * 16 + l15;
#pragma unroll
    for (int mt = 0; mt < 4; ++mt) {
      const int row0 = bm + wm + mt * 16 + quad * 4;
#pragma unroll
      for (int r = 0; r < 4; ++r)
        RES[((long)(b * 1024 + row0 + r)) * 1024 + col] = (bf16)acc[mt][nt][r];
    }
  }
}

// ---------------------------------------------------------------------------
// Batched transpose through LDS: T in {float,bf16} -> bf16 out.
// ---------------------------------------------------------------------------
template <typename T>
__global__ __launch_bounds__(256) void transpose_k(
    const T* __restrict__ in, bf16* __restrict__ out,
    int sIR, int sOR, long inStrideB, long inStrideH, long outStrideZ, int H)
{
  __shared__ bf16 t[32][33];
  const int z = blockIdx.z;
  const T* ib = in + (long)(z / H) * inStrideB + (long)(z % H) * inStrideH;
  bf16* ob = out + (long)z * outStrideZ;
  const int r0 = blockIdx.x * 32, c0 = blockIdx.y * 32;
  const int tx = threadIdx.x & 31, ty = threadIdx.x >> 5;
#pragma unroll
  for (int i = 0; i < 32; i += 8)
    t[ty + i][tx] = (bf16)(float)ib[(long)(r0 + ty + i) * sIR + (c0 + tx)];
  __syncthreads();
#pragma unroll
  for (int i = 0; i < 32; i += 8)
    ob[(long)(c0 + ty + i) * sOR + (r0 + tx)] = t[tx][ty + i];
}

// ---------------------------------------------------------------------------
// transpose_w10: z<9: weight transposes (as before). z==9: LN of x (2048
// row-groups mapped to the 32x64 grid slice).
// ---------------------------------------------------------------------------
struct TPLN {
  const float* in[9]; bf16* out[9];
  const float* lx; const float* lg; const float* lb; bf16* lout;
};

__global__ __launch_bounds__(256) void transpose_w10(TPLN p)
{
  __shared__ bf16 t[32][33];
  const int z = blockIdx.z;
  if (z == 9) {
    const int rid = blockIdx.y * 32 + blockIdx.x;   // 0..2047
    const int wid = threadIdx.x >> 6, lane = threadIdx.x & 63;
    ln_row_body<float>(p.lx, p.lg, p.lb, p.lout, (long)rid * 4 + wid, lane);
    return;
  }
  int r0, c0, sIR, sOR;
  if (z < 7) {
    if (blockIdx.y >= 32) return;
    r0 = blockIdx.x * 32; c0 = blockIdx.y * 32; sIR = 1024; sOR = 1024;
  } else if (z == 7) {            // in 1024x2048 -> out 2048x1024
    r0 = blockIdx.x * 32; c0 = blockIdx.y * 32; sIR = 2048; sOR = 1024;
  } else {                        // in 2048x1024 -> out 1024x2048
    r0 = blockIdx.y * 32; c0 = blockIdx.x * 32; sIR = 1024; sOR = 2048;
  }
  const float* ib = p.in[z];
  bf16* ob = p.out[z];
  const int tx = threadIdx.x & 31, ty = threadIdx.x >> 5;
#pragma unroll
  for (int i = 0; i < 32; i += 8)
    t[ty + i][tx] = (bf16)ib[(long)(r0 + ty + i) * sIR + (c0 + tx)];
  __syncthreads();
#pragma unroll
  for (int i = 0; i < 32; i += 8)
    ob[(long)(c0 + ty + i) * sOR + (r0 + tx)] = t[tx][ty + i];
}

// ln_pair: blocks [0,2048) LN 8192 bf16 rows; [2048,3072) LN 4096 f32 rows.
__global__ __launch_bounds__(256) void ln_pair(
    const bf16* __restrict__ Xa, const float* __restrict__ Ga,
    const float* __restrict__ Ba, bf16* __restrict__ outA,
    const float* __restrict__ Xb, const float* __restrict__ Gb,
    const float* __restrict__ Bb, bf16* __restrict__ outB)
{
  const int wid = threadIdx.x >> 6, lane = threadIdx.x & 63;
  const long row = (long)blockIdx.x * 4 + wid;
  if (blockIdx.x < 2048) ln_row_body<bf16>(Xa, Ga, Ba, outA, row, lane);
  else                   ln_row_body<float>(Xb, Gb, Bb, outB, row - 8192, lane);
}

// ln_fuse2: v = LN(X1;G1,B1)+LN(X2;G2,B2); outX = bf16(v); outH = LN(v;G3,B3).
__global__ __launch_bounds__(256) void ln_fuse2(
    const bf16* __restrict__ X1, const float* __restrict__ G1, const float* __restrict__ B1,
    const bf16* __restrict__ X2, const float* __restrict__ G2, const float* __restrict__ B2,
    const float* __restrict__ G3, const float* __restrict__ B3,
    bf16* __restrict__ outX, bf16* __restrict__ outH)
{
  const int wid = threadIdx.x >> 6, lane = threadIdx.x & 63;
  const long row = (long)blockIdx.x * 4 + wid;
  const int c0 = lane * 16;
  const long base = row * 1024 + c0;

  float a[16], b[16];
  load16v(a, X1 + base);
  load16v(b, X2 + base);
  float s1 = 0.f, ss1 = 0.f, s2 = 0.f, ss2 = 0.f;
#pragma unroll
  for (int j = 0; j < 16; ++j) {
    s1 += a[j]; ss1 += a[j] * a[j];
    s2 += b[j]; ss2 += b[j] * b[j];
  }
#pragma unroll
  for (int off = 32; off; off >>= 1) {
    s1 += __shfl_xor(s1, off); ss1 += __shfl_xor(ss1, off);
    s2 += __shfl_xor(s2, off); ss2 += __shfl_xor(ss2, off);
  }
  const float inv = 1.f / 1024.f;
  const float m1 = s1 * inv;
  const float r1 = rsqrtf(fmaxf(ss1 * inv - m1 * m1, 0.f) + 1e-5f);
  const float m2 = s2 * inv;
  const float r2 = rsqrtf(fmaxf(ss2 * inv - m2 * m2, 0.f) + 1e-5f);

  float v[16];
  float s3 = 0.f, ss3 = 0.f;
  bf16x8 o0, o1;
#pragma unroll
  for (int j = 0; j < 16; ++j) {
    v[j] = (a[j] - m1) * r1 * G1[c0 + j] + B1[c0 + j]
         + (b[j] - m2) * r2 * G2[c0 + j] + B2[c0 + j];
    s3 += v[j]; ss3 += v[j] * v[j];
    if (j < 8) o0[j] = (bf16)v[j]; else o1[j - 8] = (bf16)v[j];
  }
  *(bf16x8*)(outX + base) = o0;
  *(bf16x8*)(outX + base + 8) = o1;
#pragma unroll
  for (int off = 32; off; off >>= 1) {
    s3 += __shfl_xor(s3, off); ss3 += __shfl_xor(ss3, off);
  }
  const float m3 = s3 * inv;
  const float r3 = rsqrtf(fmaxf(ss3 * inv - m3 * m3, 0.f) + 1e-5f);
#pragma unroll
  for (int j = 0; j < 16; ++j) {
    float hh = (v[j] - m3) * r3 * G3[c0 + j] + B3[c0 + j];
    if (j < 8) o0[j] = (bf16)hh; else o1[j - 8] = (bf16)hh;
  }
  *(bf16x8*)(outH + base) = o0;
  *(bf16x8*)(outH + base + 8) = o1;
}

// ---------------------------------------------------------------------------
extern "C" void kernel_launch(void* const* d_in, const int* in_sizes, int n_in,
                              void* d_out, int out_size, void* d_ws, size_t ws_size,
                              hipStream_t stream) {
  (void)in_sizes; (void)n_in; (void)out_size; (void)ws_size;

  const float* x   = (const float*)d_in[0];
  const float* y   = (const float*)d_in[1];
  const float* r1g = (const float*)d_in[3];  const float* r1b = (const float*)d_in[4];
  const float* sa_wq = (const float*)d_in[5];  const float* sa_bq = (const float*)d_in[6];
  const float* sa_wk = (const float*)d_in[7];  const float* sa_bk = (const float*)d_in[8];
  const float* sa_wv = (const float*)d_in[9];  const float* sa_bv = (const float*)d_in[10];
  const float* sa_wo = (const float*)d_in[11]; const float* sa_bo = (const float*)d_in[12];
  const float* tn_g = (const float*)d_in[13];  const float* tn_b = (const float*)d_in[14];
  const float* an_g = (const float*)d_in[15];  const float* an_b = (const float*)d_in[16];
  const float* ca_wq = (const float*)d_in[17]; const float* ca_bq = (const float*)d_in[18];
  const float* ca_wk = (const float*)d_in[19]; const float* ca_bk = (const float*)d_in[20];
  const float* ca_wv = (const float*)d_in[21];
  const float* ca_bv = (const float*)d_in[22];
  const float* n1g = (const float*)d_in[23];   const float* n1b = (const float*)d_in[24];
  const float* n2g = (const float*)d_in[25];   const float* n2b = (const float*)d_in[26];
  const float* r2g = (const float*)d_in[27];   const float* r2b = (const float*)d_in[28];
  const float* fw1 = (const float*)d_in[29];   const float* fb1 = (const float*)d_in[30];
  const float* fw2 = (const float*)d_in[31];   const float* fb2 = (const float*)d_in[32];

  // ---- static 150MB lifetime-planned workspace ----
  char* wsb = (char*)d_ws;
  const size_t MBy = 1048576;
  bf16* fw1T = (bf16*)(wsb + 0 * MBy);
  bf16* fw2T = (bf16*)(wsb + 4 * MBy);
  bf16* wqT  = (bf16*)(wsb + 8 * MBy);    // wq|wk|wv contiguous (3x2MB)
  bf16* wkT  = (bf16*)(wsb + 10 * MBy);
  bf16* wvT  = (bf16*)(wsb + 12 * MBy);
  bf16* woT  = (bf16*)(wsb + 14 * MBy);
  bf16* cwqT = (bf16*)(wsb + 16 * MBy);   // cwq|cwk|cwv contiguous (3x2MB)
  bf16* cwkT = (bf16*)(wsb + 18 * MBy);
  bf16* cwvT = (bf16*)(wsb + 20 * MBy);
  bf16* h_bf = (bf16*)(wsb + 22 * MBy);
  bf16* t_bf = h_bf;  bf16* h2_bf = h_bf;
  bf16* q_bf = (bf16*)(wsb + 38 * MBy);
  bf16* av_bf = q_bf;
  bf16* gA = (bf16*)(wsb + 22 * MBy);           // z 0..31 (h/t/q/av dead)
  bf16* k_bf = (bf16*)(wsb + 54 * MBy);
  bf16* cq_bf = k_bf;  bf16* res_b = k_bf;
  bf16* v_bf = (bf16*)(wsb + 70 * MBy);
  bf16* ck_bf = v_bf;
  bf16* cv_bf = (bf16*)(wsb + 78 * MBy);
  bf16* x2_b  = v_bf;
  bf16* vT  = (bf16*)(wsb + 86 * MBy);
  bf16* cvT = vT;
  bf16* o_bf = (bf16*)(wsb + 102 * MBy);
  bf16* x1_b = o_bf;
  bf16* gB  = (bf16*)(wsb + 118 * MBy);          // z 32..63
  bf16* ffh = gB;

  float* out_x    = (float*)d_out;
  float* out_attn = out_x + 8 * 1024 * 1024;

  const dim3 blk(256);

  TPLN tp;
  tp.in[0] = sa_wq; tp.out[0] = wqT;
  tp.in[1] = sa_wk; tp.out[1] = wkT;
  tp.in[2] = sa_wv; tp.out[2] = wvT;
  tp.in[3] = sa_wo; tp.out[3] = woT;
  tp.in[4] = ca_wq; tp.out[4] = cwqT;
  tp.in[5] = ca_wk; tp.out[5] = cwkT;
  tp.in[6] = ca_wv; tp.out[6] = cwvT;
  tp.in[7] = fw1;   tp.out[7] = fw1T;
  tp.in[8] = fw2;   tp.out[8] = fw2T;
  tp.lx = x; tp.lg = r1g; tp.lb = r1b; tp.lout = h_bf;
  transpose_w10<<<dim3(32, 64, 10), blk, 0, stream>>>(tp);

  // fused QKV projection: packed weights wqT|wkT|wvT, split outputs
  Out3 oqkv = { q_bf, k_bf, v_bf, sa_bq, sa_bk, sa_bv };
  gemm_bt_split<<<dim3(24, 64), blk, 0, stream>>>(h_bf, h_bf, wqT, oqkv, 8192, 1024);

  transpose_k<bf16><<<dim3(32, 4, 64), blk, 0, stream>>>(v_bf, vT, 1024, 1024,
      (long)1024 * 1024, 128, (long)128 * 1024, 8);

  attn_self<<<dim3(64, 8), dim3(512), 0, stream>>>(q_bf, k_bf, vT, o_bf);

  gemm_bt<<<dim3(8, 64), blk, 0, stream>>>(o_bf, woT, sa_bo, nullptr, x, x1_b, nullptr, 8192, 1024, 1024, 0);

  // t = LN(x1); av = LN(y) in one launch
  ln_pair<<<dim3(3072), blk, 0, stream>>>(x1_b, tn_g, tn_b, t_bf, y, an_g, an_b, av_bf);

  // fused CQ + CK + CV projection: packed weights cwqT|cwkT|cwvT
  Out3 ocq = { cq_bf, ck_bf, cv_bf, ca_bq, ca_bk, ca_bv };
  gemm_bt_split<<<dim3(24, 64), blk, 0, stream>>>(t_bf, av_bf, cwqT, ocq, 4096, 1024);

  transpose_k<bf16><<<dim3(16, 4, 64), blk, 0, stream>>>(cv_bf, cvT, 1024, 512,
      (long)512 * 1024, 128, (long)128 * 512, 8);

  // gate (z-grouped) -> G; then attn_out mean + res GEMM in one launch
  gate2<<<dim3(64, 32), blk, 0, stream>>>(cq_bf, ck_bf, gA, gB);
  reduce_res<<<dim3(4608), blk, 0, stream>>>(gA, gB, cvT, out_attn, res_b);

  // x2 = LN(x1)+LN(res); h2 = LN(x2) in one launch
  ln_fuse2<<<dim3(2048), blk, 0, stream>>>(x1_b, n1g, n1b, res_b, n2g, n2b,
                                           r2g, r2b, x2_b, h2_bf);

  gemm_bt<<<dim3(16, 64), blk, 0, stream>>>(h2_bf, fw1T, fb1, nullptr, nullptr, ffh, nullptr, 8192, 2048, 1024, 1);
  gemm_bt<<<dim3(8, 64), blk, 0, stream>>>(ffh, fw2T, fb2, x2_b, nullptr, nullptr, out_x, 8192, 1024, 2048, 0);
}

// Round 10
// 640.443 us; speedup vs baseline: 1.5126x; 1.0232x over previous
//
#include <hip/hip_runtime.h>

// ---------------------------------------------------------------------------
// CrossDecoderLayer on MI355X (gfx950). External I/O fp32; internal bf16
// MFMA, fp32 accumulate. B=8, W=1024, V=512, D=1024, H=8, DK=128.
// R7 : XOR-swizzle attn/gate2 LDS. R10/R11: fusion + 512-thr attn.
// R12: T1 XCD swizzle GEMMs. R13: BK=64 GEMMs + merges (666us).
// R14: attn XCD-grouped grid + K/V reg prefetch (FETCH 139->41MB, 655us).
// R16: attn T5 setprio around QK^T/PV MFMA clusters (m191 attn +4-7%) +
//      T13 defer-max (skip rescale when __all(tm<=m+8); m214 +5%);
//      gate2 setprio. No GEMM structural change (attribution clean).
// ---------------------------------------------------------------------------

typedef __bf16 bf16;
typedef bf16  bf16x4 __attribute__((ext_vector_type(4)));
typedef bf16  bf16x8 __attribute__((ext_vector_type(8)));
typedef float f32x4  __attribute__((ext_vector_type(4)));

#define SCALE 0.08838834764831845f  // 1/sqrt(128)

__device__ __forceinline__ f32x4 mfma16(bf16x8 a, bf16x8 b, f32x4 c) {
  return __builtin_amdgcn_mfma_f32_16x16x32_bf16(a, b, c, 0, 0, 0);
}

__device__ __forceinline__ void gll16(const bf16* g, bf16* l) {
  __builtin_amdgcn_global_load_lds(
      (__attribute__((address_space(1))) void*)(void*)g,
      (__attribute__((address_space(3))) void*)(void*)l, 16, 0, 0);
}

// XCD-aware bijective block swizzle (T1). Requires nwg % 8 == 0.
__device__ __forceinline__ void xcd_tile(int& bm, int& bn) {
  const int nx = gridDim.x;
  const int nwg = nx * gridDim.y;
  int bid = blockIdx.y * nx + blockIdx.x;
  const int cpx = nwg >> 3;
  bid = (bid & 7) * cpx + (bid >> 3);
  bn = (bid % nx) * 128;
  bm = (bid / nx) * 128;
}

// ---------------------------------------------------------------------------
// LayerNorm helpers (used by ln kernels and the merged transpose launch).
// ---------------------------------------------------------------------------
__device__ __forceinline__ void load16v(float* d, const bf16* p) {
  bf16x8 a = *(const bf16x8*)p, b2 = *(const bf16x8*)(p + 8);
#pragma unroll
  for (int j = 0; j < 8; ++j) { d[j] = (float)a[j]; d[j + 8] = (float)b2[j]; }
}
__device__ __forceinline__ void load16v(float* d, const float* p) {
#pragma unroll
  for (int j = 0; j < 4; ++j) {
    float4 v = ((const float4*)p)[j];
    d[4*j] = v.x; d[4*j+1] = v.y; d[4*j+2] = v.z; d[4*j+3] = v.w;
  }
}

template <typename TI>
__device__ __forceinline__ void ln_row_body(
    const TI* __restrict__ X, const float* __restrict__ G,
    const float* __restrict__ Bb, bf16* __restrict__ out, long row, int lane)
{
  const int c0 = lane * 16;
  const long base = row * 1024 + c0;
  float a[16];
  load16v(a, X + base);
  float s = 0.f, ss = 0.f;
#pragma unroll
  for (int j = 0; j < 16; ++j) { s += a[j]; ss += a[j] * a[j]; }
#pragma unroll
  for (int off = 32; off; off >>= 1) { s += __shfl_xor(s, off); ss += __shfl_xor(ss, off); }
  const float inv = 1.f / 1024.f;
  const float m = s * inv;
  const float rr = rsqrtf(fmaxf(ss * inv - m * m, 0.f) + 1e-5f);
  bf16x8 o0, o1;
#pragma unroll
  for (int j = 0; j < 16; ++j) {
    float v = (a[j] - m) * rr * G[c0 + j] + Bb[c0 + j];
    if (j < 8) o0[j] = (bf16)v; else o1[j - 8] = (bf16)v;
  }
  *(bf16x8*)(out + base) = o0;
  *(bf16x8*)(out + base + 8) = o1;
}

// ---------------------------------------------------------------------------
// GEMM: C = epi(A[M,K] @ Bt[N,K]^T + bias [+residF]), 128x128 tile, BK=64
// (two 32-col LDS chunks), 4 waves x (64x64), global_load_lds staging.
// ---------------------------------------------------------------------------
__global__ __launch_bounds__(256) void gemm_bt(
    const bf16* __restrict__ A, const bf16* __restrict__ Bt,
    const float* __restrict__ bias,
    const bf16* __restrict__ residB, const float* __restrict__ residF,
    bf16* __restrict__ Cb, float* __restrict__ Cf,
    int M, int N, int K, int relu)
{
  __shared__ alignas(16) bf16 As[128 * 64];   // [2 chunks][128][32]
  __shared__ alignas(16) bf16 Bs[128 * 64];
  const int tid  = threadIdx.x;
  const int wid  = tid >> 6;
  const int lane = tid & 63;
  const int l15  = lane & 15;
  const int quad = lane >> 4;
  int bm, bn;
  xcd_tile(bm, bn);
  const int wm = (wid & 1) * 64,  wn = (wid >> 1) * 64;

  f32x4 acc[4][4] = {};

  const int srow = tid >> 2;
  const int scol = (tid & 3) * 8;
  const bf16* ag0 = A  + (long)(bm + srow) * K + scol;
  const bf16* ag1 = ag0 + (long)64 * K;
  const bf16* bg0 = Bt + (long)(bn + srow) * K + scol;
  const bf16* bg1 = bg0 + (long)64 * K;
  bf16* lA0 = As + wid * 512;
  bf16* lA1 = As + 2048 + wid * 512;
  bf16* lA2 = As + 4096 + wid * 512;
  bf16* lA3 = As + 6144 + wid * 512;
  bf16* lB0 = Bs + wid * 512;
  bf16* lB1 = Bs + 2048 + wid * 512;
  bf16* lB2 = Bs + 4096 + wid * 512;
  bf16* lB3 = Bs + 6144 + wid * 512;

  for (int k0 = 0; k0 < K; k0 += 64) {
    gll16(ag0 + k0, lA0);
    gll16(ag1 + k0, lA1);
    gll16(ag0 + k0 + 32, lA2);
    gll16(ag1 + k0 + 32, lA3);
    gll16(bg0 + k0, lB0);
    gll16(bg1 + k0, lB1);
    gll16(bg0 + k0 + 32, lB2);
    gll16(bg1 + k0 + 32, lB3);
    __syncthreads();
#pragma unroll
    for (int kk = 0; kk < 2; ++kk) {
      bf16x8 af[4], bfr[4];
#pragma unroll
      for (int i = 0; i < 4; ++i)
        af[i] = *(const bf16x8*)(As + kk * 4096 + (wm + i * 16 + l15) * 32 + quad * 8);
#pragma unroll
      for (int i = 0; i < 4; ++i)
        bfr[i] = *(const bf16x8*)(Bs + kk * 4096 + (wn + i * 16 + l15) * 32 + quad * 8);
#pragma unroll
      for (int mt = 0; mt < 4; ++mt)
#pragma unroll
        for (int nt = 0; nt < 4; ++nt)
          acc[mt][nt] = mfma16(af[mt], bfr[nt], acc[mt][nt]);
    }
    __syncthreads();
  }

#pragma unroll
  for (int nt = 0; nt < 4; ++nt) {
    const int col = bn + wn + nt * 16 + l15;
    const float bv = bias ? bias[col] : 0.f;
#pragma unroll
    for (int mt = 0; mt < 4; ++mt) {
      const int row0 = bm + wm + mt * 16 + quad * 4;
#pragma unroll
      for (int r = 0; r < 4; ++r) {
        const long idx = (long)(row0 + r) * N + col;
        float v = acc[mt][nt][r] + bv;
        if (relu) v = fmaxf(v, 0.f);
        if (residB) v += (float)residB[idx];
        if (residF) v += residF[idx];
        if (Cb) Cb[idx] = (bf16)v;
        if (Cf) Cf[idx] = v;
      }
    }
  }
}

// ---------------------------------------------------------------------------
// gemm_bt_split: m97 GEMM (BK=64) over a packed Bt; epilogue splits output
// into per-1024-column buffers. A0 feeds chunk 0, A1 feeds chunks 1,2.
// ---------------------------------------------------------------------------
struct Out3 {
  bf16* o0; bf16* o1; bf16* o2;
  const float* b0; const float* b1; const float* b2;
};

__global__ __launch_bounds__(256) void gemm_bt_split(
    const bf16* __restrict__ A0, const bf16* __restrict__ A1,
    const bf16* __restrict__ Bt, Out3 so, int m1lim, int K)
{
  __shared__ alignas(16) bf16 As[128 * 64];
  __shared__ alignas(16) bf16 Bs[128 * 64];
  const int tid  = threadIdx.x;
  const int wid  = tid >> 6;
  const int lane = tid & 63;
  const int l15  = lane & 15;
  const int quad = lane >> 4;
  int bm, bn;
  xcd_tile(bm, bn);
  const int wm = (wid & 1) * 64,  wn = (wid >> 1) * 64;

  const int ch = bn >> 10;
  if (ch > 0 && bm >= m1lim) return;
  const bf16* A = (ch == 0) ? A0 : A1;
  bf16* C = (ch == 0) ? so.o0 : (ch == 1 ? so.o1 : so.o2);
  const float* bp = (ch == 0) ? so.b0 : (ch == 1 ? so.b1 : so.b2);

  f32x4 acc[4][4] = {};

  const int srow = tid >> 2;
  const int scol = (tid & 3) * 8;
  const bf16* ag0 = A  + (long)(bm + srow) * K + scol;
  const bf16* ag1 = ag0 + (long)64 * K;
  const bf16* bg0 = Bt + (long)(bn + srow) * K + scol;
  const bf16* bg1 = bg0 + (long)64 * K;
  bf16* lA0 = As + wid * 512;
  bf16* lA1 = As + 2048 + wid * 512;
  bf16* lA2 = As + 4096 + wid * 512;
  bf16* lA3 = As + 6144 + wid * 512;
  bf16* lB0 = Bs + wid * 512;
  bf16* lB1 = Bs + 2048 + wid * 512;
  bf16* lB2 = Bs + 4096 + wid * 512;
  bf16* lB3 = Bs + 6144 + wid * 512;

  for (int k0 = 0; k0 < K; k0 += 64) {
    gll16(ag0 + k0, lA0);
    gll16(ag1 + k0, lA1);
    gll16(ag0 + k0 + 32, lA2);
    gll16(ag1 + k0 + 32, lA3);
    gll16(bg0 + k0, lB0);
    gll16(bg1 + k0, lB1);
    gll16(bg0 + k0 + 32, lB2);
    gll16(bg1 + k0 + 32, lB3);
    __syncthreads();
#pragma unroll
    for (int kk = 0; kk < 2; ++kk) {
      bf16x8 af[4], bfr[4];
#pragma unroll
      for (int i = 0; i < 4; ++i)
        af[i] = *(const bf16x8*)(As + kk * 4096 + (wm + i * 16 + l15) * 32 + quad * 8);
#pragma unroll
      for (int i = 0; i < 4; ++i)
        bfr[i] = *(const bf16x8*)(Bs + kk * 4096 + (wn + i * 16 + l15) * 32 + quad * 8);
#pragma unroll
      for (int mt = 0; mt < 4; ++mt)
#pragma unroll
        for (int nt = 0; nt < 4; ++nt)
          acc[mt][nt] = mfma16(af[mt], bfr[nt], acc[mt][nt]);
    }
    __syncthreads();
  }

#pragma unroll
  for (int nt = 0; nt < 4; ++nt) {
    const int col = bn + wn + nt * 16 + l15;
    const int cc  = col & 1023;
    const float bv = bp[cc];
#pragma unroll
    for (int mt = 0; mt < 4; ++mt) {
      const int row0 = bm + wm + mt * 16 + quad * 4;
#pragma unroll
      for (int r = 0; r < 4; ++r)
        C[(long)(row0 + r) * 1024 + cc] = (bf16)(acc[mt][nt][r] + bv);
    }
  }
}

// ---------------------------------------------------------------------------
// Flash-style self-attention. R14 structure + R16: setprio(1) around both
// MFMA clusters (T5) and defer-max (T13): skip O-rescale and keep stale m
// when the tile max grew by <= 8 (P bounded by e^8, bf16-safe).
// ---------------------------------------------------------------------------
__global__ __launch_bounds__(512) void attn_self(
    const bf16* __restrict__ Q, const bf16* __restrict__ Km,
    const bf16* __restrict__ Vt, bf16* __restrict__ O)
{
  __shared__ alignas(16) bf16 Ks[16384];
  __shared__ alignas(16) bf16 Vs[16384];
  __shared__ alignas(16) bf16 Ps[8192];      // 8 waves x (2 chunks x 512)
  const int tid  = threadIdx.x;
  const int wid  = tid >> 6;                  // 0..7
  const int lane = tid & 63;
  const int l15  = lane & 15;
  const int quad = lane >> 4;
  const int z = blockIdx.x;                   // (b,h) — XCD-grouped
  const int b = z >> 3, h = z & 7;
  const int q0 = blockIdx.y * 128;

  const int rdoff = l15 * 32 + (((quad ^ ((l15 >> 1) & 3))) << 3);

  const long qb = ((long)(b * 1024 + q0 + wid * 16 + l15)) * 1024 + h * 128 + quad * 8;
  bf16x8 qf[4];
#pragma unroll
  for (int ks = 0; ks < 4; ++ks) qf[ks] = *(const bf16x8*)(Q + qb + ks * 32);

  f32x4 oacc[8] = {};
  float mrow[4], lrow[4];
#pragma unroll
  for (int r = 0; r < 4; ++r) { mrow[r] = -3.0e38f; lrow[r] = 0.f; }

  const long kbase = (long)(b * 1024) * 1024 + h * 128;
  const long vbase = (long)(b * 8 + h) * 128 * 1024;

  const int srow = tid >> 3;        // 0..63
  const int sc8  = (tid & 7) * 8;

  bf16* pw = Ps + wid * 1024;

  // K/V prefetch registers (4 + 4 x bf16x8 = 32 VGPR)
  bf16x8 kr[4], vr[4];
#pragma unroll
  for (int dh = 0; dh < 2; ++dh)
#pragma unroll
    for (int kq = 0; kq < 2; ++kq)
      kr[dh * 2 + kq] = *(const bf16x8*)(
          Km + kbase + (long)(kq * 64 + srow) * 1024 + dh * 64 + sc8);
#pragma unroll
  for (int kh = 0; kh < 2; ++kh)
#pragma unroll
    for (int dq = 0; dq < 2; ++dq)
      vr[kh * 2 + dq] = *(const bf16x8*)(
          Vt + vbase + (long)(dq * 64 + srow) * 1024 + kh * 64 + sc8);

  for (int t = 0; t < 8; ++t) {
    __syncthreads();                // prev tile's Ks/Vs reads done
#pragma unroll
    for (int dh = 0; dh < 2; ++dh)
#pragma unroll
      for (int kq = 0; kq < 2; ++kq) {
        const int kv = kq * 64 + srow;
        const int d  = dh * 64 + sc8;
        *(bf16x8*)(Ks + (d >> 5) * 4096 + kv * 32 +
                   ((((d & 31) >> 3) ^ ((kv >> 1) & 3)) << 3)) = kr[dh * 2 + kq];
      }
#pragma unroll
    for (int kh = 0; kh < 2; ++kh)
#pragma unroll
      for (int dq = 0; dq < 2; ++dq) {
        const int d  = dq * 64 + srow;
        const int kv = kh * 64 + sc8;
        *(bf16x8*)(Vs + (kv >> 5) * 4096 + d * 32 +
                   ((((kv & 31) >> 3) ^ ((d >> 1) & 3)) << 3)) = vr[kh * 2 + dq];
      }
    __syncthreads();

    if (t < 7) {                    // issue next tile's loads under compute
      const int kn = (t + 1) * 128;
#pragma unroll
      for (int dh = 0; dh < 2; ++dh)
#pragma unroll
        for (int kq = 0; kq < 2; ++kq)
          kr[dh * 2 + kq] = *(const bf16x8*)(
              Km + kbase + (long)(kn + kq * 64 + srow) * 1024 + dh * 64 + sc8);
#pragma unroll
      for (int kh = 0; kh < 2; ++kh)
#pragma unroll
        for (int dq = 0; dq < 2; ++dq)
          vr[kh * 2 + dq] = *(const bf16x8*)(
              Vt + vbase + (long)(dq * 64 + srow) * 1024 + kn + kh * 64 + sc8);
    }

    f32x4 sacc[8] = {};
    __builtin_amdgcn_s_setprio(1);
#pragma unroll
    for (int nt = 0; nt < 8; ++nt)
#pragma unroll
      for (int ks = 0; ks < 4; ++ks)
        sacc[nt] = mfma16(qf[ks],
            *(const bf16x8*)(Ks + ks * 4096 + nt * 512 + rdoff),
            sacc[nt]);
    __builtin_amdgcn_s_setprio(0);

    float tm[4];
#pragma unroll
    for (int r = 0; r < 4; ++r) {
      float m = -3.0e38f;
#pragma unroll
      for (int nt = 0; nt < 8; ++nt) m = fmaxf(m, sacc[nt][r]);
      tm[r] = m * SCALE;
    }
#pragma unroll
    for (int off = 8; off; off >>= 1)
#pragma unroll
      for (int r = 0; r < 4; ++r) tm[r] = fmaxf(tm[r], __shfl_xor(tm[r], off));

    // T13 defer-max: if tile max grew by <= 8 for all rows (wave-wide),
    // keep the stale running max (P <= e^8, bf16-safe) and skip rescale.
    bool small = true;
#pragma unroll
    for (int r = 0; r < 4; ++r) small = small && (tm[r] <= mrow[r] + 8.f);
    const bool defer = __all(small);
    float psum[4];
#pragma unroll
    for (int r = 0; r < 4; ++r) psum[r] = 0.f;
    if (!defer) {
      float alpha[4];
#pragma unroll
      for (int r = 0; r < 4; ++r) {
        const float mnew = fmaxf(mrow[r], tm[r]);
        alpha[r] = __expf(mrow[r] - mnew);
        mrow[r] = mnew;
      }
#pragma unroll
      for (int nt = 0; nt < 8; ++nt)
#pragma unroll
        for (int r = 0; r < 4; ++r) oacc[nt][r] *= alpha[r];
#pragma unroll
      for (int r = 0; r < 4; ++r) lrow[r] *= alpha[r];
    }

    // two PV halves, reusing the 2-chunk per-wave P buffer
#pragma unroll
    for (int hs = 0; hs < 2; ++hs) {
#pragma unroll
      for (int n2 = 0; n2 < 4; ++n2) {
        const int nt = hs * 4 + n2;
#pragma unroll
        for (int r = 0; r < 4; ++r) {
          const float p = __expf(sacc[nt][r] * SCALE - mrow[r]);
          psum[r] += p;
          const int prow = quad * 4 + r;
          pw[((nt >> 1) & 1) * 512 + prow * 32 +
             (((((nt & 1) * 2 + (l15 >> 3)) ^ ((prow >> 1) & 3))) << 3) + (l15 & 7)] =
              (bf16)p;
        }
      }
      __builtin_amdgcn_s_setprio(1);
#pragma unroll
      for (int ks2 = 0; ks2 < 2; ++ks2) {
        const bf16x8 pa = *(const bf16x8*)(pw + ks2 * 512 + rdoff);
        const int ksx = hs * 2 + ks2;
#pragma unroll
        for (int nt = 0; nt < 8; ++nt)
          oacc[nt] = mfma16(pa,
              *(const bf16x8*)(Vs + ksx * 4096 + nt * 512 + rdoff),
              oacc[nt]);
      }
      __builtin_amdgcn_s_setprio(0);
    }

#pragma unroll
    for (int off = 8; off; off >>= 1)
#pragma unroll
      for (int r = 0; r < 4; ++r) psum[r] += __shfl_xor(psum[r], off);
#pragma unroll
    for (int r = 0; r < 4; ++r) lrow[r] += psum[r];
  }

  float linv[4];
#pragma unroll
  for (int r = 0; r < 4; ++r) linv[r] = 1.f / lrow[r];
#pragma unroll
  for (int nt = 0; nt < 8; ++nt)
#pragma unroll
    for (int r = 0; r < 4; ++r) {
      const int row = q0 + wid * 16 + quad * 4 + r;
      O[((long)(b * 1024 + row)) * 1024 + h * 128 + nt * 16 + l15] =
          (bf16)(oacc[nt][r] * linv[r]);
    }
}

// ---------------------------------------------------------------------------
// gate2: G[z=(b,h)][w][v] = sigmoid(SCALE * CQ.CK^T). z-grouped grid; R16:
// setprio around the MFMA cluster.
// ---------------------------------------------------------------------------
__global__ __launch_bounds__(256) void gate2(
    const bf16* __restrict__ CQ, const bf16* __restrict__ CK,
    bf16* __restrict__ gA, bf16* __restrict__ gB)
{
  __shared__ alignas(16) bf16 Ks[16384];      // 4 dchunks x 128 v x 32 d
  __shared__ alignas(16) bf16 Pt[4][1024];    // per-wave 16w x 64v transpose
  const int tid  = threadIdx.x;
  const int wid  = tid >> 6;
  const int lane = tid & 63;
  const int l15  = lane & 15;
  const int quad = lane >> 4;
  const int z = blockIdx.x, b = z >> 3, h = z & 7;
  const int w0 = blockIdx.y * 32;
  const int rsel = wid & 1, vsel = wid >> 1;

  const int rdoff = l15 * 32 + (((quad ^ ((l15 >> 1) & 3))) << 3);

  bf16* Gz = (z < 32) ? (gA + (long)z * 524288) : (gB + (long)(z - 32) * 524288);

  const long qb = ((long)(b * 1024 + w0 + rsel * 16 + l15)) * 1024 + h * 128 + quad * 8;
  bf16x8 qf[4];
#pragma unroll
  for (int ks = 0; ks < 4; ++ks) qf[ks] = *(const bf16x8*)(CQ + qb + ks * 32);

  const int srow = tid >> 3;        // 0..31
  const int sc8  = (tid & 7) * 8;   // 0..56

  for (int vt = 0; vt < 4; ++vt) {
    const int v0 = vt * 128;
    __syncthreads();
#pragma unroll
    for (int i = 0; i < 4; ++i) {
      const int v = i * 32 + srow;
#pragma unroll
      for (int dh = 0; dh < 2; ++dh) {
        const int d = dh * 64 + sc8;
        bf16x8 val = *(const bf16x8*)(CK + ((long)(b * 512 + v0 + v)) * 1024 + h * 128 + d);
        *(bf16x8*)(Ks + (d >> 5) * 4096 + v * 32 +
                   (((((d & 31) >> 3) ^ ((v >> 1) & 3))) << 3)) = val;
      }
    }
    __syncthreads();

    f32x4 sacc[4] = {};
    __builtin_amdgcn_s_setprio(1);
#pragma unroll
    for (int nt = 0; nt < 4; ++nt)
#pragma unroll
      for (int ks = 0; ks < 4; ++ks)
        sacc[nt] = mfma16(qf[ks],
            *(const bf16x8*)(Ks + ks * 4096 + vsel * 2048 + nt * 512 + rdoff),
            sacc[nt]);
    __builtin_amdgcn_s_setprio(0);

#pragma unroll
    for (int nt = 0; nt < 4; ++nt)
#pragma unroll
      for (int r = 0; r < 4; ++r) {
        const float g = 1.f / (1.f + __expf(-sacc[nt][r] * SCALE));
        const int prow = quad * 4 + r;
        const int g0 = nt * 2 + (l15 >> 3);
        Pt[wid][prow * 64 + ((g0 ^ ((prow >> 1) & 3)) << 3) + (l15 & 7)] = (bf16)g;
      }
#pragma unroll
    for (int pass = 0; pass < 2; ++pass) {
      const int f = pass * 512 + lane * 8;
      const int row = f >> 6, col = f & 63;
      const int gl = (lane & 7) ^ ((row >> 1) & 3);
      bf16x8 vv = *(const bf16x8*)(&Pt[wid][row * 64 + gl * 8]);
      *(bf16x8*)(Gz + (long)(w0 + rsel * 16 + row) * 512 + v0 + vsel * 64 + col) = vv;
    }
  }
}

// ---------------------------------------------------------------------------
// reduce_res: blocks [0,4096): attn_out mean over heads.
// blocks [4096,4608): gemm_res; z = bid2 & 63 so XCD = z%8 matches gate2's
// G[z] placement (same-XCD L2 read).
// ---------------------------------------------------------------------------
__global__ __launch_bounds__(256) void reduce_res(
    const bf16* __restrict__ gA, const bf16* __restrict__ gB,
    const bf16* __restrict__ CVt, float* __restrict__ AOUT,
    bf16* __restrict__ RES)
{
  __shared__ alignas(16) bf16 As[128 * 64];
  __shared__ alignas(16) bf16 Bs[128 * 64];
  const int bid = blockIdx.x;
  const int tid = threadIdx.x;

  if (bid < 4096) {
    const int idx = bid * 256 + tid;  // 1,048,576 total
    const int v4 = idx & 127;
    const int w  = (idx >> 7) & 1023;
    const int b  = idx >> 17;
    float s0 = 0.f, s1 = 0.f, s2 = 0.f, s3 = 0.f;
#pragma unroll
    for (int h = 0; h < 8; ++h) {
      const int z = b * 8 + h;
      const bf16* base = (z < 32) ? (gA + (long)z * 524288) : (gB + (long)(z - 32) * 524288);
      bf16x4 g = *(const bf16x4*)(base + (long)w * 512 + v4 * 4);
      s0 += (float)g[0]; s1 += (float)g[1]; s2 += (float)g[2]; s3 += (float)g[3];
    }
    *(float4*)(AOUT + (long)idx * 4) =
        make_float4(s0 * 0.125f, s1 * 0.125f, s2 * 0.125f, s3 * 0.125f);
    return;
  }

  const int bid2 = bid - 4096;
  const int z = bid2 & 63, b = z >> 3, h = z & 7;   // XCD = bid2%8 = z%8
  const int bm = (bid2 >> 6) * 128;
  const int wid  = tid >> 6;
  const int lane = tid & 63;
  const int l15  = lane & 15;
  const int quad = lane >> 4;
  const bf16* A  = (z < 32) ? (gA + (long)z * 524288) : (gB + (long)(z - 32) * 524288);
  const bf16* Bt = CVt + (long)z * 65536;
  const int wm = (wid & 1) * 64, wn = (wid >> 1) * 64;

  f32x4 acc[4][4] = {};

  const int srow = tid >> 2;
  const int scol = (tid & 3) * 8;
  const bf16* ag0 = A  + (long)(bm + srow) * 512 + scol;
  const bf16* ag1 = ag0 + (long)64 * 512;
  const bf16* bg0 = Bt + (long)srow * 512 + scol;
  const bf16* bg1 = bg0 + (long)64 * 512;
  bf16* lA0 = As + wid * 512;
  bf16* lA1 = As + 2048 + wid * 512;
  bf16* lA2 = As + 4096 + wid * 512;
  bf16* lA3 = As + 6144 + wid * 512;
  bf16* lB0 = Bs + wid * 512;
  bf16* lB1 = Bs + 2048 + wid * 512;
  bf16* lB2 = Bs + 4096 + wid * 512;
  bf16* lB3 = Bs + 6144 + wid * 512;

  for (int k0 = 0; k0 < 512; k0 += 64) {
    gll16(ag0 + k0, lA0);
    gll16(ag1 + k0, lA1);
    gll16(ag0 + k0 + 32, lA2);
    gll16(ag1 + k0 + 32, lA3);
    gll16(bg0 + k0, lB0);
    gll16(bg1 + k0, lB1);
    gll16(bg0 + k0 + 32, lB2);
    gll16(bg1 + k0 + 32, lB3);
    __syncthreads();
#pragma unroll
    for (int kk = 0; kk < 2; ++kk) {
      bf16x8 af[4], bfr[4];
#pragma unroll
      for (int i = 0; i < 4; ++i)
        af[i] = *(const bf16x8*)(As + kk * 4096 + (wm + i * 16 + l15) * 32 + quad * 8);
#pragma unroll
      for (int i = 0; i < 4; ++i)
        bfr[i] = *(const bf16x8*)(Bs + kk * 4096 + (wn + i * 16 + l15) * 32 + quad * 8);
#pragma unroll
      for (int mt = 0; mt < 4; ++mt)
#pragma unroll
        for (int nt = 0; nt < 4; ++nt)
          acc[mt][nt] = mfma16(af[mt], bfr[nt], acc[mt][nt]);
    }
    __syncthreads();
  }

#pragma unroll
  for (int nt = 0; nt < 4; ++nt) {
    const int col = h * 128 + wn + nt * 16 + l15;
#pragma unroll
    for (int mt = 0; mt < 4; ++mt) {
      const int row0 = bm + wm + mt * 16 + quad * 4;
#pragma unroll
      for (int r = 0; r < 4; ++r)
        RES[((long)(b * 1024 + row0 + r)) * 1024 + col] = (bf16)acc[mt][nt][r];
    }
  }
}

// ---------------------------------------------------------------------------
// Batched transpose through LDS: T in {float,bf16} -> bf16 out.
// ---------------------------------------------------------------------------
template <typename T>
__global__ __launch_bounds__(256) void transpose_k(
    const T* __restrict__ in, bf16* __restrict__ out,
    int sIR, int sOR, long inStrideB, long inStrideH, long outStrideZ, int H)
{
  __shared__ bf16 t[32][33];
  const int z = blockIdx.z;
  const T* ib = in + (long)(z / H) * inStrideB + (long)(z % H) * inStrideH;
  bf16* ob = out + (long)z * outStrideZ;
  const int r0 = blockIdx.x * 32, c0 = blockIdx.y * 32;
  const int tx = threadIdx.x & 31, ty = threadIdx.x >> 5;
#pragma unroll
  for (int i = 0; i < 32; i += 8)
    t[ty + i][tx] = (bf16)(float)ib[(long)(r0 + ty + i) * sIR + (c0 + tx)];
  __syncthreads();
#pragma unroll
  for (int i = 0; i < 32; i += 8)
    ob[(long)(c0 + ty + i) * sOR + (r0 + tx)] = t[tx][ty + i];
}

// ---------------------------------------------------------------------------
// transpose_w10: z<9: weight transposes. z==9: LN of x.
// ---------------------------------------------------------------------------
struct TPLN {
  const float* in[9]; bf16* out[9];
  const float* lx; const float* lg; const float* lb; bf16* lout;
};

__global__ __launch_bounds__(256) void transpose_w10(TPLN p)
{
  __shared__ bf16 t[32][33];
  const int z = blockIdx.z;
  if (z == 9) {
    const int rid = blockIdx.y * 32 + blockIdx.x;   // 0..2047
    const int wid = threadIdx.x >> 6, lane = threadIdx.x & 63;
    ln_row_body<float>(p.lx, p.lg, p.lb, p.lout, (long)rid * 4 + wid, lane);
    return;
  }
  int r0, c0, sIR, sOR;
  if (z < 7) {
    if (blockIdx.y >= 32) return;
    r0 = blockIdx.x * 32; c0 = blockIdx.y * 32; sIR = 1024; sOR = 1024;
  } else if (z == 7) {            // in 1024x2048 -> out 2048x1024
    r0 = blockIdx.x * 32; c0 = blockIdx.y * 32; sIR = 2048; sOR = 1024;
  } else {                        // in 2048x1024 -> out 1024x2048
    r0 = blockIdx.y * 32; c0 = blockIdx.x * 32; sIR = 1024; sOR = 2048;
  }
  const float* ib = p.in[z];
  bf16* ob = p.out[z];
  const int tx = threadIdx.x & 31, ty = threadIdx.x >> 5;
#pragma unroll
  for (int i = 0; i < 32; i += 8)
    t[ty + i][tx] = (bf16)ib[(long)(r0 + ty + i) * sIR + (c0 + tx)];
  __syncthreads();
#pragma unroll
  for (int i = 0; i < 32; i += 8)
    ob[(long)(c0 + ty + i) * sOR + (r0 + tx)] = t[tx][ty + i];
}

// ln_pair: blocks [0,2048) LN 8192 bf16 rows; [2048,3072) LN 4096 f32 rows.
__global__ __launch_bounds__(256) void ln_pair(
    const bf16* __restrict__ Xa, const float* __restrict__ Ga,
    const float* __restrict__ Ba, bf16* __restrict__ outA,
    const float* __restrict__ Xb, const float* __restrict__ Gb,
    const float* __restrict__ Bb, bf16* __restrict__ outB)
{
  const int wid = threadIdx.x >> 6, lane = threadIdx.x & 63;
  const long row = (long)blockIdx.x * 4 + wid;
  if (blockIdx.x < 2048) ln_row_body<bf16>(Xa, Ga, Ba, outA, row, lane);
  else                   ln_row_body<float>(Xb, Gb, Bb, outB, row - 8192, lane);
}

// ln_fuse2: v = LN(X1;G1,B1)+LN(X2;G2,B2); outX = bf16(v); outH = LN(v;G3,B3).
__global__ __launch_bounds__(256) void ln_fuse2(
    const bf16* __restrict__ X1, const float* __restrict__ G1, const float* __restrict__ B1,
    const bf16* __restrict__ X2, const float* __restrict__ G2, const float* __restrict__ B2,
    const float* __restrict__ G3, const float* __restrict__ B3,
    bf16* __restrict__ outX, bf16* __restrict__ outH)
{
  const int wid = threadIdx.x >> 6, lane = threadIdx.x & 63;
  const long row = (long)blockIdx.x * 4 + wid;
  const int c0 = lane * 16;
  const long base = row * 1024 + c0;

  float a[16], b[16];
  load16v(a, X1 + base);
  load16v(b, X2 + base);
  float s1 = 0.f, ss1 = 0.f, s2 = 0.f, ss2 = 0.f;
#pragma unroll
  for (int j = 0; j < 16; ++j) {
    s1 += a[j]; ss1 += a[j] * a[j];
    s2 += b[j]; ss2 += b[j] * b[j];
  }
#pragma unroll
  for (int off = 32; off; off >>= 1) {
    s1 += __shfl_xor(s1, off); ss1 += __shfl_xor(ss1, off);
    s2 += __shfl_xor(s2, off); ss2 += __shfl_xor(ss2, off);
  }
  const float inv = 1.f / 1024.f;
  const float m1 = s1 * inv;
  const float r1 = rsqrtf(fmaxf(ss1 * inv - m1 * m1, 0.f) + 1e-5f);
  const float m2 = s2 * inv;
  const float r2 = rsqrtf(fmaxf(ss2 * inv - m2 * m2, 0.f) + 1e-5f);

  float v[16];
  float s3 = 0.f, ss3 = 0.f;
  bf16x8 o0, o1;
#pragma unroll
  for (int j = 0; j < 16; ++j) {
    v[j] = (a[j] - m1) * r1 * G1[c0 + j] + B1[c0 + j]
         + (b[j] - m2) * r2 * G2[c0 + j] + B2[c0 + j];
    s3 += v[j]; ss3 += v[j] * v[j];
    if (j < 8) o0[j] = (bf16)v[j]; else o1[j - 8] = (bf16)v[j];
  }
  *(bf16x8*)(outX + base) = o0;
  *(bf16x8*)(outX + base + 8) = o1;
#pragma unroll
  for (int off = 32; off; off >>= 1) {
    s3 += __shfl_xor(s3, off); ss3 += __shfl_xor(ss3, off);
  }
  const float m3 = s3 * inv;
  const float r3 = rsqrtf(fmaxf(ss3 * inv - m3 * m3, 0.f) + 1e-5f);
#pragma unroll
  for (int j = 0; j < 16; ++j) {
    float hh = (v[j] - m3) * r3 * G3[c0 + j] + B3[c0 + j];
    if (j < 8) o0[j] = (bf16)hh; else o1[j - 8] = (bf16)hh;
  }
  *(bf16x8*)(outH + base) = o0;
  *(bf16x8*)(outH + base + 8) = o1;
}

// ---------------------------------------------------------------------------
extern "C" void kernel_launch(void* const* d_in, const int* in_sizes, int n_in,
                              void* d_out, int out_size, void* d_ws, size_t ws_size,
                              hipStream_t stream) {
  (void)in_sizes; (void)n_in; (void)out_size; (void)ws_size;

  const float* x   = (const float*)d_in[0];
  const float* y   = (const float*)d_in[1];
  const float* r1g = (const float*)d_in[3];  const float* r1b = (const float*)d_in[4];
  const float* sa_wq = (const float*)d_in[5];  const float* sa_bq = (const float*)d_in[6];
  const float* sa_wk = (const float*)d_in[7];  const float* sa_bk = (const float*)d_in[8];
  const float* sa_wv = (const float*)d_in[9];  const float* sa_bv = (const float*)d_in[10];
  const float* sa_wo = (const float*)d_in[11]; const float* sa_bo = (const float*)d_in[12];
  const float* tn_g = (const float*)d_in[13];  const float* tn_b = (const float*)d_in[14];
  const float* an_g = (const float*)d_in[15];  const float* an_b = (const float*)d_in[16];
  const float* ca_wq = (const float*)d_in[17]; const float* ca_bq = (const float*)d_in[18];
  const float* ca_wk = (const float*)d_in[19]; const float* ca_bk = (const float*)d_in[20];
  const float* ca_wv = (const float*)d_in[21];
  const float* ca_bv = (const float*)d_in[22];
  const float* n1g = (const float*)d_in[23];   const float* n1b = (const float*)d_in[24];
  const float* n2g = (const float*)d_in[25];   const float* n2b = (const float*)d_in[26];
  const float* r2g = (const float*)d_in[27];   const float* r2b = (const float*)d_in[28];
  const float* fw1 = (const float*)d_in[29];   const float* fb1 = (const float*)d_in[30];
  const float* fw2 = (const float*)d_in[31];   const float* fb2 = (const float*)d_in[32];

  // ---- static 150MB lifetime-planned workspace ----
  char* wsb = (char*)d_ws;
  const size_t MBy = 1048576;
  bf16* fw1T = (bf16*)(wsb + 0 * MBy);
  bf16* fw2T = (bf16*)(wsb + 4 * MBy);
  bf16* wqT  = (bf16*)(wsb + 8 * MBy);    // wq|wk|wv contiguous (3x2MB)
  bf16* wkT  = (bf16*)(wsb + 10 * MBy);
  bf16* wvT  = (bf16*)(wsb + 12 * MBy);
  bf16* woT  = (bf16*)(wsb + 14 * MBy);
  bf16* cwqT = (bf16*)(wsb + 16 * MBy);   // cwq|cwk|cwv contiguous (3x2MB)
  bf16* cwkT = (bf16*)(wsb + 18 * MBy);
  bf16* cwvT = (bf16*)(wsb + 20 * MBy);
  bf16* h_bf = (bf16*)(wsb + 22 * MBy);
  bf16* t_bf = h_bf;  bf16* h2_bf = h_bf;
  bf16* q_bf = (bf16*)(wsb + 38 * MBy);
  bf16* av_bf = q_bf;
  bf16* gA = (bf16*)(wsb + 22 * MBy);           // z 0..31 (h/t/q/av dead)
  bf16* k_bf = (bf16*)(wsb + 54 * MBy);
  bf16* cq_bf = k_bf;  bf16* res_b = k_bf;
  bf16* v_bf = (bf16*)(wsb + 70 * MBy);
  bf16* ck_bf = v_bf;
  bf16* cv_bf = (bf16*)(wsb + 78 * MBy);
  bf16* x2_b  = v_bf;
  bf16* vT  = (bf16*)(wsb + 86 * MBy);
  bf16* cvT = vT;
  bf16* o_bf = (bf16*)(wsb + 102 * MBy);
  bf16* x1_b = o_bf;
  bf16* gB  = (bf16*)(wsb + 118 * MBy);          // z 32..63
  bf16* ffh = gB;

  float* out_x    = (float*)d_out;
  float* out_attn = out_x + 8 * 1024 * 1024;

  const dim3 blk(256);

  TPLN tp;
  tp.in[0] = sa_wq; tp.out[0] = wqT;
  tp.in[1] = sa_wk; tp.out[1] = wkT;
  tp.in[2] = sa_wv; tp.out[2] = wvT;
  tp.in[3] = sa_wo; tp.out[3] = woT;
  tp.in[4] = ca_wq; tp.out[4] = cwqT;
  tp.in[5] = ca_wk; tp.out[5] = cwkT;
  tp.in[6] = ca_wv; tp.out[6] = cwvT;
  tp.in[7] = fw1;   tp.out[7] = fw1T;
  tp.in[8] = fw2;   tp.out[8] = fw2T;
  tp.lx = x; tp.lg = r1g; tp.lb = r1b; tp.lout = h_bf;
  transpose_w10<<<dim3(32, 64, 10), blk, 0, stream>>>(tp);

  // fused QKV projection: packed weights wqT|wkT|wvT, split outputs
  Out3 oqkv = { q_bf, k_bf, v_bf, sa_bq, sa_bk, sa_bv };
  gemm_bt_split<<<dim3(24, 64), blk, 0, stream>>>(h_bf, h_bf, wqT, oqkv, 8192, 1024);

  transpose_k<bf16><<<dim3(32, 4, 64), blk, 0, stream>>>(v_bf, vT, 1024, 1024,
      (long)1024 * 1024, 128, (long)128 * 1024, 8);

  attn_self<<<dim3(64, 8), dim3(512), 0, stream>>>(q_bf, k_bf, vT, o_bf);

  gemm_bt<<<dim3(8, 64), blk, 0, stream>>>(o_bf, woT, sa_bo, nullptr, x, x1_b, nullptr, 8192, 1024, 1024, 0);

  // t = LN(x1); av = LN(y) in one launch
  ln_pair<<<dim3(3072), blk, 0, stream>>>(x1_b, tn_g, tn_b, t_bf, y, an_g, an_b, av_bf);

  // fused CQ + CK + CV projection: packed weights cwqT|cwkT|cwvT
  Out3 ocq = { cq_bf, ck_bf, cv_bf, ca_bq, ca_bk, ca_bv };
  gemm_bt_split<<<dim3(24, 64), blk, 0, stream>>>(t_bf, av_bf, cwqT, ocq, 4096, 1024);

  transpose_k<bf16><<<dim3(16, 4, 64), blk, 0, stream>>>(cv_bf, cvT, 1024, 512,
      (long)512 * 1024, 128, (long)128 * 512, 8);

  // gate (z-grouped) -> G; then attn_out mean + res GEMM in one launch
  gate2<<<dim3(64, 32), blk, 0, stream>>>(cq_bf, ck_bf, gA, gB);
  reduce_res<<<dim3(4608), blk, 0, stream>>>(gA, gB, cvT, out_attn, res_b);

  // x2 = LN(x1)+LN(res); h2 = LN(x2) in one launch
  ln_fuse2<<<dim3(2048), blk, 0, stream>>>(x1_b, n1g, n1b, res_b, n2g, n2b,
                                           r2g, r2b, x2_b, h2_bf);

  gemm_bt<<<dim3(16, 64), blk, 0, stream>>>(h2_bf, fw1T, fb1, nullptr, nullptr, ffh, nullptr, 8192, 2048, 1024, 1);
  gemm_bt<<<dim3(8, 64), blk, 0, stream>>>(ffh, fw2T, fb2, x2_b, nullptr, nullptr, out_x, 8192, 1024, 2048, 0);
}